// Round 5
// baseline (1875.692 us; speedup 1.0000x reference)
//
#include <hip/hip_runtime.h>
#include <hip/hip_bf16.h>
#include <math.h>

#define B_ 16
#define N_ 500
#define T_ 12
#define K_ 10
#define NROWS (B_*N_)   // 8000

// ---------------- threefry / gumbel (jax.random.key(42)) ----------------
__device__ __forceinline__ unsigned rotl32(unsigned v, int r){ return (v<<r)|(v>>(32-r)); }

__device__ __forceinline__ void threefry2x32(unsigned k0, unsigned k1,
                                             unsigned c0, unsigned c1,
                                             unsigned &o0, unsigned &o1){
  unsigned ks2 = k0 ^ k1 ^ 0x1BD11BDAu;
  unsigned x0 = c0 + k0, x1 = c1 + k1;
#define TF_R(r) { x0 += x1; x1 = rotl32(x1,(r)); x1 ^= x0; }
  TF_R(13) TF_R(15) TF_R(26) TF_R(6)
  x0 += k1;  x1 += ks2 + 1u;
  TF_R(17) TF_R(29) TF_R(16) TF_R(24)
  x0 += ks2; x1 += k0 + 2u;
  TF_R(13) TF_R(15) TF_R(26) TF_R(6)
  x0 += k0;  x1 += k1 + 3u;
  TF_R(17) TF_R(29) TF_R(16) TF_R(24)
  x0 += k1;  x1 += ks2 + 4u;
  TF_R(13) TF_R(15) TF_R(26) TF_R(6)
  x0 += ks2; x1 += k0 + 5u;
#undef TF_R
  o0 = x0; o1 = x1;
}

// Partitionable threefry (JAX >= 0.4.30 default), bit_width=32:
//   bits[i] = x0 ^ x1 of threefry(key, (hi32(i), lo32(i)))     [jax/_src/prng.py]
// Legacy fallback (flip if node-sized errors persist):
//   i<2500: x0 of (i, i+2500); else x1 of (i-2500, i).
__device__ __forceinline__ float gumbel_at(unsigned idx){
  unsigned b0, b1;
  threefry2x32(0u, 42u, 0u, idx, b0, b1);
  unsigned bits = b0 ^ b1;
  float u = __uint_as_float((bits >> 9) | 0x3f800000u) - 1.0f;  // [0,1)
  u = fmaxf(u, 1.17549435e-38f);                                // minval=tiny
  return -logf(-logf(u));
}

// ---------------- matq = nodes_cb @ w_q ----------------
__global__ __launch_bounds__(256) void k_matq(const float* __restrict__ nodes_cb,
                                              const float* __restrict__ w_q,
                                              float* __restrict__ matq){
  int idx = blockIdx.x*256 + threadIdx.x;
  if (idx >= N_*64) return;
  int n = idx >> 6, d = idx & 63;
  float a = 0.f;
  for (int c = 0; c < 64; ++c) a += nodes_cb[n*64+c] * w_q[c*64+d];
  matq[idx] = a;
}

// ---------------- routing: argmax_k(logits + gumbel), grouped node lists ----------------
__global__ __launch_bounds__(256) void k_route(const float* __restrict__ env_cb,
                                               const float* __restrict__ w_v,
                                               const float* __restrict__ w_k,
                                               const float* __restrict__ matq,
                                               int* __restrict__ node_list,
                                               int* __restrict__ off){
  __shared__ float smk[K_*64];
  __shared__ float smv[K_*K_];
  __shared__ int sroute[N_];
  int tid = threadIdx.x;
  for (int idx = tid; idx < K_*64; idx += 256){
    int kk = idx >> 6, d = idx & 63;
    float a = 0.f;
    for (int c = 0; c < 64; ++c) a += env_cb[kk*64+c] * w_k[c*64+d];
    smk[idx] = a;
  }
  for (int idx = tid; idx < K_*K_; idx += 256){
    int kk = idx / K_, j = idx % K_;
    float a = 0.f;
    for (int c = 0; c < 64; ++c) a += env_cb[kk*64+c] * w_v[c*K_+j];
    smv[idx] = a;
  }
  __syncthreads();
  for (int n = tid; n < N_; n += 256){
    float s[K_];
    float mx = -1e30f;
    for (int j = 0; j < K_; ++j){
      float a = 0.f;
      for (int d = 0; d < 64; ++d) a += matq[n*64+d]*smk[j*64+d];
      s[j] = a * 0.125f;           // scale = 1/sqrt(64)
      mx = fmaxf(mx, s[j]);
    }
    float sum = 0.f;
    for (int j = 0; j < K_; ++j){ s[j] = expf(s[j]-mx); sum += s[j]; }
    float inv = 1.f/sum;
    int best = 0; float bestv = -1e30f;
    for (int j2 = 0; j2 < K_; ++j2){
      float lg = 0.f;
      for (int j = 0; j < K_; ++j) lg += s[j]*inv*smv[j*K_+j2];
      float tot = lg + gumbel_at((unsigned)(n*K_+j2));
      if (tot > bestv){ bestv = tot; best = j2; }   // strict > == first-max (jax argmax)
    }
    sroute[n] = best;
  }
  __syncthreads();
  if (tid == 0){
    int cnt[K_]; for (int j=0;j<K_;++j) cnt[j]=0;
    for (int n=0;n<N_;++n) cnt[sroute[n]]++;
    int acc=0;
    for (int j=0;j<K_;++j){ off[j]=acc; acc+=cnt[j]; }
    off[K_]=acc;
    int pos[K_]; for (int j=0;j<K_;++j) pos[j]=off[j];
    for (int n=0;n<N_;++n) node_list[pos[sroute[n]]++] = n;
  }
}

// ---------------- t_emb ----------------
__global__ void k_temb(const int* __restrict__ t_pos, float* __restrict__ temb){
  int tid = threadIdx.x;
  if (tid >= B_*T_) return;
  int b = tid / T_, t = tid % T_;
  int p0 = t_pos[(b*T_+t)*2+0], p1 = t_pos[(b*T_+t)*2+1];
  float tp = (float)((p0 <= 4) ? p1 : 23 + p1);   // NH-1 = 23
  float c0 = -logf(10000.f)/32.f;
  for (int j = 0; j < 32; ++j){
    float a = tp * expf(c0 * (float)j);
    temb[(b*T_+t)*64 + j]      = cosf(a);
    temb[(b*T_+t)*64 + 32 + j] = sinf(a);
  }
}

// ---------------- core[b] = reshape(t_emb[:,11] @ core_W + core_b, (64,64)) ----------------
__global__ __launch_bounds__(256) void k_core(const float* __restrict__ temb,
                                              const float* __restrict__ core_W,
                                              const float* __restrict__ core_b,
                                              float* __restrict__ core_f){
  int idx = blockIdx.x*256 + threadIdx.x;
  if (idx >= B_*4096) return;
  int b = idx >> 12, c = idx & 4095;
  const float* te = temb + (b*T_ + 11)*64;
  float a = core_b[c];
  for (int h = 0; h < 64; ++h) a += te[h] * core_W[h*4096 + c];
  core_f[idx] = a;
}

// ---------------- tmp1[b] = sum_i te[b,i] * nv_pk[i], te = nv_p1[ind_p[:,1]] ----------------
__global__ __launch_bounds__(256) void k_tmp1(const int* __restrict__ ind,
                                              const float* __restrict__ nv_p1,
                                              const float* __restrict__ nv_pk,
                                              float* __restrict__ tmp1){
  int idx = blockIdx.x*256 + threadIdx.x;
  if (idx >= B_*4096) return;
  int b = idx >> 12, c = idx & 4095;
  int i0 = ind[(b*T_+1)*2+0], i1 = ind[(b*T_+1)*2+1];  // ind_p[:, -(T-1)] == column 1
  int row = (i0 <= 4) ? i1 : 23 + i1;
  const float* te = nv_p1 + row*64;
  float a = 0.f;
  for (int h = 0; h < 64; ++h) a += te[h] * nv_pk[h*4096 + c];
  tmp1[idx] = a;
}

// ---------------- fused per-expert TCN (both paths), 8 rows/block ----------------
__global__ __launch_bounds__(256) void k_tcn(
    const float* __restrict__ x,
    const float* __restrict__ fcx_W, const float* __restrict__ fcx_b,
    const float* __restrict__ temb,
    const int* __restrict__ node_list, const int* __restrict__ off,
    const float* __restrict__ WinN, const float* __restrict__ binN,
    const float* __restrict__ WfN,  const float* __restrict__ bfN,
    const float* __restrict__ WgN,  const float* __restrict__ bgN,
    const float* __restrict__ WoutN,const float* __restrict__ boutN,
    const float* __restrict__ WinP, const float* __restrict__ binP,
    const float* __restrict__ WfP,  const float* __restrict__ bfP,
    const float* __restrict__ WgP,  const float* __restrict__ bgP,
    const float* __restrict__ WoutP,const float* __restrict__ boutP,
    float* __restrict__ out_unb, float* __restrict__ out_hpr)
{
  int k = blockIdx.y;
  int path = blockIdx.z;           // 0 = N (t0=1 -> unbias), 1 = P (t0=0 -> h_prev)
  int cnt = off[k+1] - off[k];
  int rows = cnt * 16;             // B per node
  int r0 = blockIdx.x * 8;
  if (r0 >= rows) return;

  const float* Win  = (path ? WinP  : WinN)  + k*16384;
  const float* bin  = (path ? binP  : binN)  + k*128;
  const float* Wf   = (path ? WfP   : WfN)   + k*4*16384;
  const float* bf_  = (path ? bfP   : bfN)   + k*2*128;
  const float* Wg   = (path ? WgP   : WgN)   + k*4*16384;
  const float* bg_  = (path ? bgP   : bgN)   + k*2*128;
  const float* Wout = (path ? WoutP : WoutN) + k*8192;
  const float* bout = (path ? boutP : boutN) + k*64;
  float* outb = path ? out_hpr : out_unb;
  int t0 = path ? 0 : 1;

  __shared__ __align__(16) float sIn[4096];
  __shared__ __align__(16) float sH0[4096];
  __shared__ __align__(16) float sH1[2048];
  __shared__ int rowBN[8];
  __shared__ int rowB[8];

  int tid = threadIdx.x;
  if (tid < 8){
    int r = r0 + tid;
    if (r < rows){
      int node = node_list[off[k] + (r >> 4)];
      int b = r & 15;
      rowBN[tid] = b*N_ + node;
      rowB[tid]  = b;
    } else { rowBN[tid] = -1; rowB[tid] = 0; }
  }
  __syncthreads();

  // Stage 0: build input tile in LDS directly from x/fcx/temb
  for (int i = 0; i < 8; ++i){
    int rb = rowBN[i], b = rowB[i];
    for (int c2 = tid; c2 < 512; c2 += 256){
      int t = (c2 >> 7) + t0, c = c2 & 127;
      float v = 0.f;
      if (rb >= 0){
        if (c < 64){
          const float* xp = x + (rb*T_ + t)*2;
          v = xp[0]*fcx_W[c] + xp[1]*fcx_W[64+c] + fcx_b[c];
        } else {
          v = temb[(b*T_ + t)*64 + (c-64)];
        }
      }
      sIn[i*512 + c2] = v;
    }
  }
  __syncthreads();

  int o = tid & 127;
  int half = tid >> 7;

  // Stage 1: h0 = xin @ Win + bin
  {
    float acc[16];
    #pragma unroll
    for (int j=0;j<16;++j) acc[j]=0.f;
    for (int c = 0; c < 128; c += 4){
      float w0 = Win[(c+0)*128+o];
      float w1 = Win[(c+1)*128+o];
      float w2 = Win[(c+2)*128+o];
      float w3 = Win[(c+3)*128+o];
      #pragma unroll
      for (int j=0;j<16;++j){
        float4 xv = *(const float4*)&sIn[(half*16+j)*128 + c];
        acc[j] += xv.x*w0 + xv.y*w1 + xv.z*w2 + xv.w*w3;
      }
    }
    float bb = bin[o];
    #pragma unroll
    for (int j=0;j<16;++j) sH0[(half*16+j)*128 + o] = acc[j] + bb;
  }
  __syncthreads();

  // Stage 2: block0 (d=1) at t in {0,2}: half=0 -> f, half=1 -> g
  {
    const float* W  = half ? Wg : Wf;
    const float* bb = half ? bg_ : bf_;
    float acc[16];
    #pragma unroll
    for (int j=0;j<16;++j) acc[j]=0.f;
    for (int c = 0; c < 128; c += 4){
      float a0=W[(c+0)*128+o], a1=W[(c+1)*128+o],
            a2=W[(c+2)*128+o], a3=W[(c+3)*128+o];
      float e0=W[16384+(c+0)*128+o], e1=W[16384+(c+1)*128+o],
            e2=W[16384+(c+2)*128+o], e3=W[16384+(c+3)*128+o];
      #pragma unroll
      for (int i=0;i<8;++i){
        #pragma unroll
        for (int ti=0;ti<2;++ti){
          int t = ti*2;
          float4 xa = *(const float4*)&sH0[(i*4+t  )*128 + c];
          float4 xb = *(const float4*)&sH0[(i*4+t+1)*128 + c];
          acc[i*2+ti] += xa.x*a0 + xa.y*a1 + xa.z*a2 + xa.w*a3
                       + xb.x*e0 + xb.y*e1 + xb.z*e2 + xb.w*e3;
        }
      }
    }
    float bv = bb[o];
    #pragma unroll
    for (int j=0;j<16;++j) sIn[half*2048 + j*128 + o] = acc[j] + bv;
  }
  __syncthreads();
  for (int idx = tid; idx < 2048; idx += 256){
    int j = idx >> 7, oo = idx & 127;
    int i = j >> 1, ti = j & 1;
    float f = tanhf(sIn[j*128+oo]);
    float g = 1.f/(1.f + expf(-sIn[2048 + j*128 + oo]));
    sH1[j*128+oo] = f*g + sH0[(i*4 + ti*2 + 1)*128 + oo];
  }
  __syncthreads();

  // Stage 3: block1 (d=2): taps h1[0], h1[2]
  {
    const float* W  = (half ? Wg : Wf) + 2*16384;
    const float* bb = (half ? bg_ : bf_) + 128;
    float acc[8];
    #pragma unroll
    for (int i=0;i<8;++i) acc[i]=0.f;
    for (int c = 0; c < 128; c += 4){
      float a0=W[(c+0)*128+o], a1=W[(c+1)*128+o],
            a2=W[(c+2)*128+o], a3=W[(c+3)*128+o];
      float e0=W[16384+(c+0)*128+o], e1=W[16384+(c+1)*128+o],
            e2=W[16384+(c+2)*128+o], e3=W[16384+(c+3)*128+o];
      #pragma unroll
      for (int i=0;i<8;++i){
        float4 xa = *(const float4*)&sH1[(i*2+0)*128 + c];
        float4 xb = *(const float4*)&sH1[(i*2+1)*128 + c];
        acc[i] += xa.x*a0 + xa.y*a1 + xa.z*a2 + xa.w*a3
                + xb.x*e0 + xb.y*e1 + xb.z*e2 + xb.w*e3;
      }
    }
    float bv = bb[o];
    #pragma unroll
    for (int i=0;i<8;++i) sIn[half*1024 + i*128 + o] = acc[i] + bv;
  }
  __syncthreads();
  for (int idx = tid; idx < 1024; idx += 256){
    int i = idx >> 7, oo = idx & 127;
    float f = tanhf(sIn[i*128+oo]);
    float g = 1.f/(1.f + expf(-sIn[1024 + i*128 + oo]));
    sH0[i*128+oo] = f*g + sH1[(i*2+1)*128 + oo];
  }
  __syncthreads();

  // Stage 4: out = h2 @ Wout + bout (128 -> 64)
  {
    int o6 = tid & 63, grp = tid >> 6;
    #pragma unroll
    for (int ii=0; ii<2; ++ii){
      int i = grp*2 + ii;
      float acc = 0.f;
      for (int c = 0; c < 128; c += 4){
        float w0=Wout[(c+0)*64+o6], w1=Wout[(c+1)*64+o6],
              w2=Wout[(c+2)*64+o6], w3=Wout[(c+3)*64+o6];
        float4 xv = *(const float4*)&sH0[i*128 + c];
        acc += xv.x*w0 + xv.y*w1 + xv.z*w2 + xv.w*w3;
      }
      if (rowBN[i] >= 0) outb[rowBN[i]*64 + o6] = acc + bout[o6];
    }
  }
}

// ---------------- batchnorm over (B,N) ----------------
__global__ __launch_bounds__(256) void k_bnstats(const float* __restrict__ unb,
                                                 const float* __restrict__ hpr,
                                                 float* __restrict__ stats){
  int bid = blockIdx.x;            // 0..127
  int tensor = bid >> 6, c = bid & 63;
  const float* buf = tensor ? hpr : unb;
  float s1 = 0.f, s2 = 0.f;
  for (int r = threadIdx.x; r < NROWS; r += 256){
    float v = buf[r*64 + c];
    s1 += v; s2 += v*v;
  }
  __shared__ float r1[256], r2[256];
  r1[threadIdx.x]=s1; r2[threadIdx.x]=s2;
  __syncthreads();
  for (int s=128; s>0; s>>=1){
    if (threadIdx.x < s){ r1[threadIdx.x]+=r1[threadIdx.x+s]; r2[threadIdx.x]+=r2[threadIdx.x+s]; }
    __syncthreads();
  }
  if (threadIdx.x==0){
    float mean = r1[0]/(float)NROWS;
    float var  = r2[0]/(float)NROWS - mean*mean;
    stats[tensor*128 + c]      = mean;
    stats[tensor*128 + 64 + c] = rsqrtf(var + 1e-5f);
  }
}

__global__ __launch_bounds__(256) void k_bnapply(float* __restrict__ unb, float* __restrict__ hpr,
                                                 const float* __restrict__ stats,
                                                 const float* __restrict__ g1, const float* __restrict__ be1,
                                                 const float* __restrict__ gP, const float* __restrict__ beP){
  int idx = blockIdx.x*256 + threadIdx.x;
  if (idx >= 2*NROWS*64) return;
  int tensor = idx >= NROWS*64;
  int local = idx - tensor*NROWS*64;
  int c = local & 63;
  float* buf = tensor ? hpr : unb;
  float mean = stats[tensor*128+c], rstd = stats[tensor*128+64+c];
  float g = tensor ? gP[c] : g1[c];
  float bb = tensor ? beP[c] : be1[c];
  buf[local] = g * (buf[local]-mean) * rstd + bb;
}

// ---------------- fused adjacency build + apply (+ optional GCN epilogue) ----------------
// amode 0: A = geo (pre-normalized, shared over b)
// amode 1: A = softmax_m( (Qf[b]@M[b]) . Keysf[b]^T )            (causal)
// amode 2: A = softmax_m( relu( (Qb@M[b]) . Keysb^T ) )          (adaptive)
// Y_tile = A_tile @ X[b]   (16 rows x 64)
// final=0: write Y.  final=1: cur (+)= (X0+Z1+Y) @ Wg + bg.
__global__ __launch_bounds__(256) void k_attn(
    int amode, int relu, int final_, int add,
    const float* __restrict__ geo,
    const float* __restrict__ Qf, const float* __restrict__ Qb,
    const float* __restrict__ M,
    const float* __restrict__ Keysf, const float* __restrict__ Keysb,
    const float* __restrict__ X,
    const float* __restrict__ X0, const float* __restrict__ Z1,
    const float* __restrict__ Wg, const float* __restrict__ bg,
    float* __restrict__ cur, float* __restrict__ Y)
{
  __shared__ float vbuf[16][65];
  __shared__ float mb[64][65];
  __shared__ float sbuf[16][513];
  __shared__ float red[16][17];
  __shared__ float rowm[16], rowinv[16];

  int b = blockIdx.y, n0 = blockIdx.x*16;
  int tid = threadIdx.x;
  int nl = tid >> 4, ml = tid & 15;      // 16 x 16 thread layout
  int n = n0 + nl;

  if (amode == 0){
    // load A rows directly (zero-pad cols >= N_)
    for (int idx = tid; idx < 16*512; idx += 256){
      int r = idx >> 9, m = idx & 511;
      int nn = n0 + r;
      sbuf[r][m] = (nn < N_ && m < N_) ? geo[nn*N_+m] : 0.f;
    }
    __syncthreads();
  } else {
    // raw Q tile
    for (int idx = tid; idx < 1024; idx += 256){
      int r = idx >> 6, kk = idx & 63;
      int nn = n0 + r;
      float q = 0.f;
      if (nn < N_) q = (amode == 1) ? Qf[(b*N_+nn)*64+kk] : Qb[nn*64+kk];
      vbuf[r][kk] = q;
    }
    // M[b] (64x64)
    for (int idx = tid; idx < 4096; idx += 256){
      int kk = idx >> 6, c = idx & 63;
      mb[kk][c] = M[b*4096 + idx];
    }
    __syncthreads();
    // V = Q @ M : thread (nl, ml) computes V[nl][ml*4 .. ml*4+3]
    float v4[4] = {0.f,0.f,0.f,0.f};
    for (int kk = 0; kk < 64; ++kk){
      float q = vbuf[nl][kk];
      #pragma unroll
      for (int c = 0; c < 4; ++c) v4[c] += q * mb[kk][ml*4+c];
    }
    __syncthreads();
    #pragma unroll
    for (int c = 0; c < 4; ++c) vbuf[nl][ml*4+c] = v4[c];
    __syncthreads();
    // scores: stream keys in 64-row chunks
    for (int m0 = 0; m0 < 512; m0 += 64){
      for (int idx = tid; idx < 4096; idx += 256){
        int mm = idx >> 6, kk = idx & 63;
        int m = m0 + mm;
        float v = 0.f;
        if (m < N_) v = (amode == 1) ? Keysf[(b*N_+m)*64+kk] : Keysb[m*64+kk];
        mb[mm][kk] = v;
      }
      __syncthreads();
      #pragma unroll
      for (int mi = 0; mi < 4; ++mi){
        int mloc = ml + 16*mi;
        float a = 0.f;
        for (int kk = 0; kk < 64; ++kk) a += vbuf[nl][kk]*mb[mloc][kk];
        sbuf[nl][m0+mloc] = a;
      }
      __syncthreads();
    }
    // row softmax (optional relu), write probs in place, zero-pad cols >= N_
    float lmax = -1e30f;
    for (int m = ml; m < N_; m += 16){
      float v = sbuf[nl][m];
      if (relu) v = fmaxf(v, 0.f);
      lmax = fmaxf(lmax, v);
    }
    red[nl][ml] = lmax;
    __syncthreads();
    if (ml == 0){
      float mx = red[nl][0];
      for (int j=1;j<16;++j) mx = fmaxf(mx, red[nl][j]);
      rowm[nl] = mx;
    }
    __syncthreads();
    float mx = rowm[nl];
    float lsum = 0.f;
    for (int m = ml; m < N_; m += 16){
      float v = sbuf[nl][m];
      if (relu) v = fmaxf(v, 0.f);
      lsum += expf(v - mx);
    }
    red[nl][ml] = lsum;
    __syncthreads();
    if (ml == 0){
      float s = 0.f;
      for (int j=0;j<16;++j) s += red[nl][j];
      rowinv[nl] = 1.f/s;
    }
    __syncthreads();
    float inv = rowinv[nl];
    for (int m = ml; m < 512; m += 16){
      float p = 0.f;
      if (m < N_){
        float v = sbuf[nl][m];
        if (relu) v = fmaxf(v, 0.f);
        p = expf(v - mx)*inv;
      }
      sbuf[nl][m] = p;
    }
    __syncthreads();
  }

  // apply: Y_tile = A_tile @ X[b], thread (nl, ml) accumulates cols ml*4..+3
  float acc4[4] = {0.f,0.f,0.f,0.f};
  for (int m0 = 0; m0 < 512; m0 += 64){
    for (int idx = tid; idx < 4096; idx += 256){
      int mm = idx >> 6, kk = idx & 63;
      int m = m0 + mm;
      mb[mm][kk] = (m < N_) ? X[(b*N_+m)*64+kk] : 0.f;
    }
    __syncthreads();
    for (int mm = 0; mm < 64; ++mm){
      float p = sbuf[nl][m0+mm];
      #pragma unroll
      for (int c = 0; c < 4; ++c) acc4[c] += p * mb[mm][ml*4+c];
    }
    __syncthreads();
  }

  if (!final_){
    if (n < N_){
      #pragma unroll
      for (int c = 0; c < 4; ++c) Y[(b*N_+n)*64 + ml*4+c] = acc4[c];
    }
    return;
  }

  // epilogue: cur (+)= (X0 + Z1 + Y) @ Wg + bg
  {
    int row = b*N_ + n;
    #pragma unroll
    for (int c = 0; c < 4; ++c){
      float s = 0.f;
      if (n < N_) s = acc4[c] + X0[row*64 + ml*4+c] + Z1[row*64 + ml*4+c];
      vbuf[nl][ml*4+c] = s;
    }
    for (int idx = tid; idx < 4096; idx += 256){
      int kk = idx >> 6, c = idx & 63;
      mb[kk][c] = Wg[idx];
    }
    __syncthreads();
    float o4[4] = {0.f,0.f,0.f,0.f};
    for (int kk = 0; kk < 64; ++kk){
      float s = vbuf[nl][kk];
      #pragma unroll
      for (int c = 0; c < 4; ++c) o4[c] += s * mb[kk][ml*4+c];
    }
    if (n < N_){
      #pragma unroll
      for (int c = 0; c < 4; ++c){
        float val = o4[c] + bg[ml*4+c];
        if (add) cur[row*64 + ml*4+c] += val;
        else     cur[row*64 + ml*4+c]  = val;
      }
    }
  }
}

// ---------------- output head: elu(cur @ W1[t] + b1) @ W2[t] + b2 ----------------
__global__ __launch_bounds__(128) void k_out(const float* __restrict__ cur,
                                             const float* __restrict__ W1, const float* __restrict__ bb1,
                                             const float* __restrict__ W2, const float* __restrict__ bb2,
                                             float* __restrict__ out){
  __shared__ float ch[64];
  __shared__ float red0[128], red1[128];
  int row = blockIdx.x;
  int tid = threadIdx.x;
  if (tid < 64) ch[tid] = cur[row*64 + tid];
  __syncthreads();
  for (int t = 0; t < 12; ++t){
    float hv = 0.f;
    if (tid < 100){
      float a = bb1[t*100 + tid];
      for (int h = 0; h < 64; ++h) a += ch[h] * W1[(t*64+h)*100 + tid];
      hv = (a > 0.f) ? a : expm1f(a);   // elu
    }
    red0[tid] = (tid < 100) ? hv * W2[(t*100+tid)*2+0] : 0.f;
    red1[tid] = (tid < 100) ? hv * W2[(t*100+tid)*2+1] : 0.f;
    __syncthreads();
    for (int s=64; s>0; s>>=1){
      if (tid < s){ red0[tid]+=red0[tid+s]; red1[tid]+=red1[tid+s]; }
      __syncthreads();
    }
    if (tid == 0){
      out[(row*12+t)*2+0] = red0[0] + bb2[t*2+0];
      out[(row*12+t)*2+1] = red1[0] + bb2[t*2+1];
    }
    __syncthreads();
  }
}

// ---------------- launch ----------------
extern "C" void kernel_launch(void* const* d_in, const int* in_sizes, int n_in,
                              void* d_out, int out_size, void* d_ws, size_t ws_size,
                              hipStream_t stream)
{
  const float* x        = (const float*)d_in[0];
  const float* geo      = (const float*)d_in[2];
  const float* fcx_W    = (const float*)d_in[3];
  const float* fcx_b    = (const float*)d_in[4];
  const float* env_cb   = (const float*)d_in[5];
  const float* nodes_cb = (const float*)d_in[6];
  const float* w_v      = (const float*)d_in[7];
  const float* w_k      = (const float*)d_in[8];
  const float* w_q      = (const float*)d_in[9];
  const float* core_W   = (const float*)d_in[10];
  const float* core_b   = (const float*)d_in[11];
  const float* tN_Win   = (const float*)d_in[12];
  const float* tN_bin   = (const float*)d_in[13];
  const float* tN_Wf    = (const float*)d_in[14];
  const float* tN_bf    = (const float*)d_in[15];
  const float* tN_Wg    = (const float*)d_in[16];
  const float* tN_bg    = (const float*)d_in[17];
  const float* tN_Wout  = (const float*)d_in[18];
  const float* tN_bout  = (const float*)d_in[19];
  const float* tP_Win   = (const float*)d_in[20];
  const float* tP_bin   = (const float*)d_in[21];
  const float* tP_Wf    = (const float*)d_in[22];
  const float* tP_bf    = (const float*)d_in[23];
  const float* tP_Wg    = (const float*)d_in[24];
  const float* tP_bg    = (const float*)d_in[25];
  const float* tP_Wout  = (const float*)d_in[26];
  const float* tP_bout  = (const float*)d_in[27];
  const float* bn1_g    = (const float*)d_in[28];
  const float* bn1_b    = (const float*)d_in[29];
  const float* bnP_g    = (const float*)d_in[30];
  const float* bnP_b    = (const float*)d_in[31];
  const float* gcn1_W   = (const float*)d_in[32];
  const float* gcn1_b   = (const float*)d_in[33];
  const float* gcn2_W   = (const float*)d_in[34];
  const float* gcn2_b   = (const float*)d_in[35];
  const float* gcnp_W   = (const float*)d_in[36];
  const float* gcnp_b   = (const float*)d_in[37];
  const float* nv_p1    = (const float*)d_in[38];
  const float* nv_p2    = (const float*)d_in[39];
  const float* nv_p3    = (const float*)d_in[40];
  const float* nv_pk    = (const float*)d_in[41];
  const float* out_W1   = (const float*)d_in[42];
  const float* out_b1   = (const float*)d_in[43];
  const float* out_W2   = (const float*)d_in[44];
  const float* out_b2   = (const float*)d_in[45];
  const int*   t_pos    = (const int*)d_in[46];
  const int*   ind      = (const int*)d_in[47];

  // Workspace: 4096 B header + 2,223,616 floats = 8,898,560 B (~8.49 MiB)
  int* node_list = (int*)d_ws;          // 512 ints
  int* off       = node_list + 512;     // 16 ints
  float* F = (float*)((char*)d_ws + 4096);
  float* temb   = F + 0;         // 12,288
  float* core_f = F + 12288;     // 65,536
  float* tmp1   = F + 77824;     // 65,536
  float* stats  = F + 143360;    // 256
  float* matq   = F + 143616;    // 32,000
  float* unb    = F + 175616;    // 512,000
  float* hpr    = F + 687616;    // 512,000
  float* cur    = F + 1199616;   // 512,000
  float* zt1    = F + 1711616;   // 512,000

  k_matq <<<dim3(125), dim3(256), 0, stream>>>(nodes_cb, w_q, matq);
  k_route<<<dim3(1),   dim3(256), 0, stream>>>(env_cb, w_v, w_k, matq, node_list, off);
  k_temb <<<dim3(1),   dim3(192), 0, stream>>>(t_pos, temb);
  k_core <<<dim3(256), dim3(256), 0, stream>>>(temb, core_W, core_b, core_f);
  k_tcn  <<<dim3(1000,10,2), dim3(256), 0, stream>>>(x, fcx_W, fcx_b, temb, node_list, off,
      tN_Win, tN_bin, tN_Wf, tN_bf, tN_Wg, tN_bg, tN_Wout, tN_bout,
      tP_Win, tP_bin, tP_Wf, tP_bf, tP_Wg, tP_bg, tP_Wout, tP_bout,
      unb, hpr);
  k_bnstats<<<dim3(128), dim3(256), 0, stream>>>(unb, hpr, stats);
  k_bnapply<<<dim3(4000),dim3(256), 0, stream>>>(unb, hpr, stats, bn1_g, bn1_b, bnP_g, bnP_b);

  dim3 ag(32, 16);
  // gcn1: geo adjacency on h_prev
  k_attn<<<ag, 256, 0, stream>>>(0,0,0,0, geo, nullptr,nullptr,nullptr, nullptr,nullptr,
                                 hpr, nullptr,nullptr, nullptr,nullptr, nullptr, zt1);
  k_attn<<<ag, 256, 0, stream>>>(0,0,1,0, geo, nullptr,nullptr,nullptr, nullptr,nullptr,
                                 zt1, hpr, zt1, gcn1_W, gcn1_b, cur, nullptr);
  // gcn2: causal adjacency softmax(unb @ core[b] @ hpr^T) on unbias
  k_attn<<<ag, 256, 0, stream>>>(1,0,0,0, nullptr, unb,nullptr, core_f, hpr,nullptr,
                                 unb, nullptr,nullptr, nullptr,nullptr, nullptr, zt1);
  k_attn<<<ag, 256, 0, stream>>>(1,0,1,1, nullptr, unb,nullptr, core_f, hpr,nullptr,
                                 zt1, unb, zt1, gcn2_W, gcn2_b, cur, nullptr);
  // gcnp: adaptive adjacency softmax(relu(nv_p3 @ (nv_p2 @ (te @ nv_pk)))) on unbias
  k_tmp1<<<dim3(256), dim3(256), 0, stream>>>(ind, nv_p1, nv_pk, tmp1);
  k_attn<<<ag, 256, 0, stream>>>(2,1,0,0, nullptr, nullptr,nv_p2, tmp1, nullptr,nv_p3,
                                 unb, nullptr,nullptr, nullptr,nullptr, nullptr, zt1);
  k_attn<<<ag, 256, 0, stream>>>(2,1,1,1, nullptr, nullptr,nv_p2, tmp1, nullptr,nv_p3,
                                 zt1, unb, zt1, gcnp_W, gcnp_b, cur, nullptr);
  // head
  k_out<<<dim3(8000), dim3(128), 0, stream>>>(cur, out_W1, out_b1, out_W2, out_b2, (float*)d_out);
}

// Round 7
// 1857.077 us; speedup vs baseline: 1.0100x; 1.0100x over previous
//
#include <hip/hip_runtime.h>
#include <hip/hip_bf16.h>
#include <math.h>

#define B_ 16
#define N_ 500
#define T_ 12
#define K_ 10
#define NROWS (B_*N_)   // 8000

// ---------------- threefry / gumbel (jax.random.key(42)) ----------------
__device__ __forceinline__ unsigned rotl32(unsigned v, int r){ return (v<<r)|(v>>(32-r)); }

__device__ __forceinline__ void threefry2x32(unsigned k0, unsigned k1,
                                             unsigned c0, unsigned c1,
                                             unsigned &o0, unsigned &o1){
  unsigned ks2 = k0 ^ k1 ^ 0x1BD11BDAu;
  unsigned x0 = c0 + k0, x1 = c1 + k1;
#define TF_R(r) { x0 += x1; x1 = rotl32(x1,(r)); x1 ^= x0; }
  TF_R(13) TF_R(15) TF_R(26) TF_R(6)
  x0 += k1;  x1 += ks2 + 1u;
  TF_R(17) TF_R(29) TF_R(16) TF_R(24)
  x0 += ks2; x1 += k0 + 2u;
  TF_R(13) TF_R(15) TF_R(26) TF_R(6)
  x0 += k0;  x1 += k1 + 3u;
  TF_R(17) TF_R(29) TF_R(16) TF_R(24)
  x0 += k1;  x1 += ks2 + 4u;
  TF_R(13) TF_R(15) TF_R(26) TF_R(6)
  x0 += ks2; x1 += k0 + 5u;
#undef TF_R
  o0 = x0; o1 = x1;
}

// Partitionable threefry (JAX >= 0.4.30): bits[i] = x0 ^ x1 of threefry(key,(0,i)).
// VERIFIED bit-exact vs harness (round 5 pass).
__device__ __forceinline__ float gumbel_at(unsigned idx){
  unsigned b0, b1;
  threefry2x32(0u, 42u, 0u, idx, b0, b1);
  unsigned bits = b0 ^ b1;
  float u = __uint_as_float((bits >> 9) | 0x3f800000u) - 1.0f;  // [0,1)
  u = fmaxf(u, 1.17549435e-38f);
  return -logf(-logf(u));
}

// ---------------- matq = nodes_cb @ w_q ----------------
__global__ __launch_bounds__(256) void k_matq(const float* __restrict__ nodes_cb,
                                              const float* __restrict__ w_q,
                                              float* __restrict__ matq){
  int idx = blockIdx.x*256 + threadIdx.x;
  if (idx >= N_*64) return;
  int n = idx >> 6, d = idx & 63;
  float a = 0.f;
  for (int c = 0; c < 64; ++c) a += nodes_cb[n*64+c] * w_q[c*64+d];
  matq[idx] = a;
}

// ---------------- routing ----------------
__global__ __launch_bounds__(256) void k_route(const float* __restrict__ env_cb,
                                               const float* __restrict__ w_v,
                                               const float* __restrict__ w_k,
                                               const float* __restrict__ matq,
                                               int* __restrict__ node_list,
                                               int* __restrict__ off){
  __shared__ float smk[K_*64];
  __shared__ float smv[K_*K_];
  __shared__ int sroute[N_];
  int tid = threadIdx.x;
  for (int idx = tid; idx < K_*64; idx += 256){
    int kk = idx >> 6, d = idx & 63;
    float a = 0.f;
    for (int c = 0; c < 64; ++c) a += env_cb[kk*64+c] * w_k[c*64+d];
    smk[idx] = a;
  }
  for (int idx = tid; idx < K_*K_; idx += 256){
    int kk = idx / K_, j = idx % K_;
    float a = 0.f;
    for (int c = 0; c < 64; ++c) a += env_cb[kk*64+c] * w_v[c*K_+j];
    smv[idx] = a;
  }
  __syncthreads();
  for (int n = tid; n < N_; n += 256){
    float s[K_];
    float mx = -1e30f;
    for (int j = 0; j < K_; ++j){
      float a = 0.f;
      for (int d = 0; d < 64; ++d) a += matq[n*64+d]*smk[j*64+d];
      s[j] = a * 0.125f;
      mx = fmaxf(mx, s[j]);
    }
    float sum = 0.f;
    for (int j = 0; j < K_; ++j){ s[j] = expf(s[j]-mx); sum += s[j]; }
    float inv = 1.f/sum;
    int best = 0; float bestv = -1e30f;
    for (int j2 = 0; j2 < K_; ++j2){
      float lg = 0.f;
      for (int j = 0; j < K_; ++j) lg += s[j]*inv*smv[j*K_+j2];
      float tot = lg + gumbel_at((unsigned)(n*K_+j2));
      if (tot > bestv){ bestv = tot; best = j2; }
    }
    sroute[n] = best;
  }
  __syncthreads();
  if (tid == 0){
    int cnt[K_]; for (int j=0;j<K_;++j) cnt[j]=0;
    for (int n=0;n<N_;++n) cnt[sroute[n]]++;
    int acc=0;
    for (int j=0;j<K_;++j){ off[j]=acc; acc+=cnt[j]; }
    off[K_]=acc;
    int pos[K_]; for (int j=0;j<K_;++j) pos[j]=off[j];
    for (int n=0;n<N_;++n) node_list[pos[sroute[n]]++] = n;
  }
}

// ---------------- t_emb ----------------
__global__ void k_temb(const int* __restrict__ t_pos, float* __restrict__ temb){
  int tid = threadIdx.x;
  if (tid >= B_*T_) return;
  int b = tid / T_, t = tid % T_;
  int p0 = t_pos[(b*T_+t)*2+0], p1 = t_pos[(b*T_+t)*2+1];
  float tp = (float)((p0 <= 4) ? p1 : 23 + p1);
  float c0 = -logf(10000.f)/32.f;
  for (int j = 0; j < 32; ++j){
    float a = tp * expf(c0 * (float)j);
    temb[(b*T_+t)*64 + j]      = cosf(a);
    temb[(b*T_+t)*64 + 32 + j] = sinf(a);
  }
}

// ---------------- core[b] ----------------
__global__ __launch_bounds__(256) void k_core(const float* __restrict__ temb,
                                              const float* __restrict__ core_W,
                                              const float* __restrict__ core_b,
                                              float* __restrict__ core_f){
  int idx = blockIdx.x*256 + threadIdx.x;
  if (idx >= B_*4096) return;
  int b = idx >> 12, c = idx & 4095;
  const float* te = temb + (b*T_ + 11)*64;
  float a = core_b[c];
  for (int h = 0; h < 64; ++h) a += te[h] * core_W[h*4096 + c];
  core_f[idx] = a;
}

// ---------------- tmp1[b] ----------------
__global__ __launch_bounds__(256) void k_tmp1(const int* __restrict__ ind,
                                              const float* __restrict__ nv_p1,
                                              const float* __restrict__ nv_pk,
                                              float* __restrict__ tmp1){
  int idx = blockIdx.x*256 + threadIdx.x;
  if (idx >= B_*4096) return;
  int b = idx >> 12, c = idx & 4095;
  int i0 = ind[(b*T_+1)*2+0], i1 = ind[(b*T_+1)*2+1];
  int row = (i0 <= 4) ? i1 : 23 + i1;
  const float* te = nv_p1 + row*64;
  float a = 0.f;
  for (int h = 0; h < 64; ++h) a += te[h] * nv_pk[h*4096 + c];
  tmp1[idx] = a;
}

// ---------------- fused per-expert TCN, 8 rows/block ----------------
// Fused f+g gates (round-6 win) but ZERO LDS aliasing (round-5 discipline):
// sIn -> sH0 -> sH1 -> sH2, one barrier per stage boundary. 45 KB LDS, 3 blk/CU.
__global__ __launch_bounds__(256) void k_tcn(
    const float* __restrict__ x,
    const float* __restrict__ fcx_W, const float* __restrict__ fcx_b,
    const float* __restrict__ temb,
    const int* __restrict__ node_list, const int* __restrict__ off,
    const float* __restrict__ WinN, const float* __restrict__ binN,
    const float* __restrict__ WfN,  const float* __restrict__ bfN,
    const float* __restrict__ WgN,  const float* __restrict__ bgN,
    const float* __restrict__ WoutN,const float* __restrict__ boutN,
    const float* __restrict__ WinP, const float* __restrict__ binP,
    const float* __restrict__ WfP,  const float* __restrict__ bfP,
    const float* __restrict__ WgP,  const float* __restrict__ bgP,
    const float* __restrict__ WoutP,const float* __restrict__ boutP,
    float* __restrict__ out_unb, float* __restrict__ out_hpr)
{
  int k = blockIdx.y;
  int path = blockIdx.z;           // 0 = N (t0=1 -> unbias), 1 = P (t0=0 -> h_prev)
  int cnt = off[k+1] - off[k];
  int rows = cnt * 16;
  int r0 = blockIdx.x * 8;
  if (r0 >= rows) return;

  const float* Win  = (path ? WinP  : WinN)  + k*16384;
  const float* bin  = (path ? binP  : binN)  + k*128;
  const float* Wf   = (path ? WfP   : WfN)   + k*4*16384;
  const float* bf_  = (path ? bfP   : bfN)   + k*2*128;
  const float* Wg   = (path ? WgP   : WgN)   + k*4*16384;
  const float* bg_  = (path ? bgP   : bgN)   + k*2*128;
  const float* Wout = (path ? WoutP : WoutN) + k*8192;
  const float* bout = (path ? boutP : boutN) + k*64;
  float* outb = path ? out_hpr : out_unb;
  int t0 = path ? 0 : 1;

  __shared__ __align__(16) float sIn[4096];   // input only
  __shared__ __align__(16) float sH0[4096];   // h0 only
  __shared__ __align__(16) float sH1[2048];   // h1 only
  __shared__ __align__(16) float sH2[1024];   // h2 only
  __shared__ int rowBN[8];
  __shared__ int rowB[8];

  int tid = threadIdx.x;
  if (tid < 8){
    int r = r0 + tid;
    if (r < rows){
      int node = node_list[off[k] + (r >> 4)];
      int b = r & 15;
      rowBN[tid] = b*N_ + node;
      rowB[tid]  = b;
    } else { rowBN[tid] = -1; rowB[tid] = 0; }
  }
  __syncthreads();

  // Stage 0: build input tile
  for (int i = 0; i < 8; ++i){
    int rb = rowBN[i], b = rowB[i];
    for (int c2 = tid; c2 < 512; c2 += 256){
      int t = (c2 >> 7) + t0, c = c2 & 127;
      float v = 0.f;
      if (rb >= 0){
        if (c < 64){
          const float* xp = x + (rb*T_ + t)*2;
          v = xp[0]*fcx_W[c] + xp[1]*fcx_W[64+c] + fcx_b[c];
        } else {
          v = temb[(b*T_ + t)*64 + (c-64)];
        }
      }
      sIn[i*512 + c2] = v;
    }
  }
  __syncthreads();

  // Stage 1: h0 = xin @ Win + bin. 2 cols x 8 rt rows per thread.
  {
    int oc = (tid & 63)*2;
    int jg = (tid >> 6)*8;
    float a0[8], a1[8];
    #pragma unroll
    for (int j=0;j<8;++j){ a0[j]=0.f; a1[j]=0.f; }
    for (int c = 0; c < 128; c += 4){
      float2 w0 = *(const float2*)(Win + (c+0)*128 + oc);
      float2 w1 = *(const float2*)(Win + (c+1)*128 + oc);
      float2 w2 = *(const float2*)(Win + (c+2)*128 + oc);
      float2 w3 = *(const float2*)(Win + (c+3)*128 + oc);
      #pragma unroll
      for (int j=0;j<8;++j){
        float4 xv = *(const float4*)&sIn[(jg+j)*128 + c];
        a0[j] += xv.x*w0.x + xv.y*w1.x + xv.z*w2.x + xv.w*w3.x;
        a1[j] += xv.x*w0.y + xv.y*w1.y + xv.z*w2.y + xv.w*w3.y;
      }
    }
    float b0v = bin[oc], b1v = bin[oc+1];
    #pragma unroll
    for (int j=0;j<8;++j){
      sH0[(jg+j)*128 + oc]   = a0[j] + b0v;
      sH0[(jg+j)*128 + oc+1] = a1[j] + b1v;
    }
  }
  __syncthreads();

  // Stage 2: block0 (d=1), fused f+g, reads sH0, writes sH1.
  {
    int o = tid & 127;
    int jg = (tid >> 7)*8;
    float af[8], ag[8];
    #pragma unroll
    for (int j=0;j<8;++j){ af[j]=0.f; ag[j]=0.f; }
    for (int c = 0; c < 128; c += 4){
      float f00=Wf[(c+0)*128+o], f01=Wf[(c+1)*128+o], f02=Wf[(c+2)*128+o], f03=Wf[(c+3)*128+o];
      float f10=Wf[16384+(c+0)*128+o], f11=Wf[16384+(c+1)*128+o], f12=Wf[16384+(c+2)*128+o], f13=Wf[16384+(c+3)*128+o];
      float g00=Wg[(c+0)*128+o], g01=Wg[(c+1)*128+o], g02=Wg[(c+2)*128+o], g03=Wg[(c+3)*128+o];
      float g10=Wg[16384+(c+0)*128+o], g11=Wg[16384+(c+1)*128+o], g12=Wg[16384+(c+2)*128+o], g13=Wg[16384+(c+3)*128+o];
      #pragma unroll
      for (int jj=0;jj<8;++jj){
        int j = jg + jj;
        int i = j >> 1, ti = j & 1;
        float4 xa = *(const float4*)&sH0[(i*4+ti*2  )*128 + c];
        float4 xb = *(const float4*)&sH0[(i*4+ti*2+1)*128 + c];
        af[jj] += xa.x*f00 + xa.y*f01 + xa.z*f02 + xa.w*f03
                + xb.x*f10 + xb.y*f11 + xb.z*f12 + xb.w*f13;
        ag[jj] += xa.x*g00 + xa.y*g01 + xa.z*g02 + xa.w*g03
                + xb.x*g10 + xb.y*g11 + xb.z*g12 + xb.w*g13;
      }
    }
    float bfv = bf_[o], bgv = bg_[o];
    #pragma unroll
    for (int jj=0;jj<8;++jj){
      int j = jg + jj;
      int i = j >> 1, ti = j & 1;
      float f = tanhf(af[jj] + bfv);
      float g = 1.f/(1.f + expf(-(ag[jj] + bgv)));
      sH1[j*128 + o] = f*g + sH0[(i*4 + ti*2 + 1)*128 + o];
    }
  }
  __syncthreads();

  // Stage 3: block1 (d=2), fused f+g, reads sH1, writes sH2.
  {
    int o = tid & 127;
    int ig = (tid >> 7)*4;
    const float* Wf1 = Wf + 2*16384;
    const float* Wg1 = Wg + 2*16384;
    float af[4], ag[4];
    #pragma unroll
    for (int i=0;i<4;++i){ af[i]=0.f; ag[i]=0.f; }
    for (int c = 0; c < 128; c += 4){
      float f00=Wf1[(c+0)*128+o], f01=Wf1[(c+1)*128+o], f02=Wf1[(c+2)*128+o], f03=Wf1[(c+3)*128+o];
      float f10=Wf1[16384+(c+0)*128+o], f11=Wf1[16384+(c+1)*128+o], f12=Wf1[16384+(c+2)*128+o], f13=Wf1[16384+(c+3)*128+o];
      float g00=Wg1[(c+0)*128+o], g01=Wg1[(c+1)*128+o], g02=Wg1[(c+2)*128+o], g03=Wg1[(c+3)*128+o];
      float g10=Wg1[16384+(c+0)*128+o], g11=Wg1[16384+(c+1)*128+o], g12=Wg1[16384+(c+2)*128+o], g13=Wg1[16384+(c+3)*128+o];
      #pragma unroll
      for (int ii=0;ii<4;++ii){
        int i = ig + ii;
        float4 xa = *(const float4*)&sH1[(i*2+0)*128 + c];
        float4 xb = *(const float4*)&sH1[(i*2+1)*128 + c];
        af[ii] += xa.x*f00 + xa.y*f01 + xa.z*f02 + xa.w*f03
                + xb.x*f10 + xb.y*f11 + xb.z*f12 + xb.w*f13;
        ag[ii] += xa.x*g00 + xa.y*g01 + xa.z*g02 + xa.w*g03
                + xb.x*g10 + xb.y*g11 + xb.z*g12 + xb.w*g13;
      }
    }
    float bfv = bf_[128+o], bgv = bg_[128+o];
    #pragma unroll
    for (int ii=0;ii<4;++ii){
      int i = ig + ii;
      float f = tanhf(af[ii] + bfv);
      float g = 1.f/(1.f + expf(-(ag[ii] + bgv)));
      sH2[i*128 + o] = f*g + sH1[(i*2+1)*128 + o];
    }
  }
  __syncthreads();

  // Stage 4: out = h2 @ Wout + bout (128 -> 64)
  {
    int o6 = tid & 63, grp = tid >> 6;
    #pragma unroll
    for (int ii=0; ii<2; ++ii){
      int i = grp*2 + ii;
      float acc = 0.f;
      for (int c = 0; c < 128; c += 4){
        float w0=Wout[(c+0)*64+o6], w1=Wout[(c+1)*64+o6],
              w2=Wout[(c+2)*64+o6], w3=Wout[(c+3)*64+o6];
        float4 xv = *(const float4*)&sH2[i*128 + c];
        acc += xv.x*w0 + xv.y*w1 + xv.z*w2 + xv.w*w3;
      }
      if (rowBN[i] >= 0) outb[rowBN[i]*64 + o6] = acc + bout[o6];
    }
  }
}

// ---------------- batchnorm ----------------
__global__ __launch_bounds__(256) void k_bnstats(const float* __restrict__ unb,
                                                 const float* __restrict__ hpr,
                                                 float* __restrict__ stats){
  int bid = blockIdx.x;
  int tensor = bid >> 6, c = bid & 63;
  const float* buf = tensor ? hpr : unb;
  float s1 = 0.f, s2 = 0.f;
  for (int r = threadIdx.x; r < NROWS; r += 256){
    float v = buf[r*64 + c];
    s1 += v; s2 += v*v;
  }
  __shared__ float r1[256], r2[256];
  r1[threadIdx.x]=s1; r2[threadIdx.x]=s2;
  __syncthreads();
  for (int s=128; s>0; s>>=1){
    if (threadIdx.x < s){ r1[threadIdx.x]+=r1[threadIdx.x+s]; r2[threadIdx.x]+=r2[threadIdx.x+s]; }
    __syncthreads();
  }
  if (threadIdx.x==0){
    float mean = r1[0]/(float)NROWS;
    float var  = r2[0]/(float)NROWS - mean*mean;
    stats[tensor*128 + c]      = mean;
    stats[tensor*128 + 64 + c] = rsqrtf(var + 1e-5f);
  }
}

__global__ __launch_bounds__(256) void k_bnapply(float* __restrict__ unb, float* __restrict__ hpr,
                                                 const float* __restrict__ stats,
                                                 const float* __restrict__ g1, const float* __restrict__ be1,
                                                 const float* __restrict__ gP, const float* __restrict__ beP){
  int idx = blockIdx.x*256 + threadIdx.x;
  if (idx >= 2*NROWS*64) return;
  int tensor = idx >= NROWS*64;
  int local = idx - tensor*NROWS*64;
  int c = local & 63;
  float* buf = tensor ? hpr : unb;
  float mean = stats[tensor*128+c], rstd = stats[tensor*128+64+c];
  float g = tensor ? gP[c] : g1[c];
  float bb = tensor ? beP[c] : be1[c];
  buf[local] = g * (buf[local]-mean) * rstd + bb;
}

// ---------------- fused adjacency build + apply (round-5 proven version) ----------------
__global__ __launch_bounds__(256) void k_attn(
    int amode, int relu, int final_, int add,
    const float* __restrict__ geo,
    const float* __restrict__ Qf, const float* __restrict__ Qb,
    const float* __restrict__ M,
    const float* __restrict__ Keysf, const float* __restrict__ Keysb,
    const float* __restrict__ X,
    const float* __restrict__ X0, const float* __restrict__ Z1,
    const float* __restrict__ Wg, const float* __restrict__ bg,
    float* __restrict__ cur, float* __restrict__ Y)
{
  __shared__ float vbuf[16][65];
  __shared__ float mb[64][65];
  __shared__ float sbuf[16][513];
  __shared__ float red[16][17];
  __shared__ float rowm[16], rowinv[16];

  int b = blockIdx.y, n0 = blockIdx.x*16;
  int tid = threadIdx.x;
  int nl = tid >> 4, ml = tid & 15;
  int n = n0 + nl;

  if (amode == 0){
    for (int idx = tid; idx < 16*512; idx += 256){
      int r = idx >> 9, m = idx & 511;
      int nn = n0 + r;
      sbuf[r][m] = (nn < N_ && m < N_) ? geo[nn*N_+m] : 0.f;
    }
    __syncthreads();
  } else {
    for (int idx = tid; idx < 1024; idx += 256){
      int r = idx >> 6, kk = idx & 63;
      int nn = n0 + r;
      float q = 0.f;
      if (nn < N_) q = (amode == 1) ? Qf[(b*N_+nn)*64+kk] : Qb[nn*64+kk];
      vbuf[r][kk] = q;
    }
    for (int idx = tid; idx < 4096; idx += 256){
      int kk = idx >> 6, c = idx & 63;
      mb[kk][c] = M[b*4096 + idx];
    }
    __syncthreads();
    float v4[4] = {0.f,0.f,0.f,0.f};
    for (int kk = 0; kk < 64; ++kk){
      float q = vbuf[nl][kk];
      #pragma unroll
      for (int c = 0; c < 4; ++c) v4[c] += q * mb[kk][ml*4+c];
    }
    __syncthreads();
    #pragma unroll
    for (int c = 0; c < 4; ++c) vbuf[nl][ml*4+c] = v4[c];
    __syncthreads();
    for (int m0 = 0; m0 < 512; m0 += 64){
      for (int idx = tid; idx < 4096; idx += 256){
        int mm = idx >> 6, kk = idx & 63;
        int m = m0 + mm;
        float v = 0.f;
        if (m < N_) v = (amode == 1) ? Keysf[(b*N_+m)*64+kk] : Keysb[m*64+kk];
        mb[mm][kk] = v;
      }
      __syncthreads();
      #pragma unroll
      for (int mi = 0; mi < 4; ++mi){
        int mloc = ml + 16*mi;
        float a = 0.f;
        for (int kk = 0; kk < 64; ++kk) a += vbuf[nl][kk]*mb[mloc][kk];
        sbuf[nl][m0+mloc] = a;
      }
      __syncthreads();
    }
    float lmax = -1e30f;
    for (int m = ml; m < N_; m += 16){
      float v = sbuf[nl][m];
      if (relu) v = fmaxf(v, 0.f);
      lmax = fmaxf(lmax, v);
    }
    red[nl][ml] = lmax;
    __syncthreads();
    if (ml == 0){
      float mx = red[nl][0];
      for (int j=1;j<16;++j) mx = fmaxf(mx, red[nl][j]);
      rowm[nl] = mx;
    }
    __syncthreads();
    float mx = rowm[nl];
    float lsum = 0.f;
    for (int m = ml; m < N_; m += 16){
      float v = sbuf[nl][m];
      if (relu) v = fmaxf(v, 0.f);
      lsum += expf(v - mx);
    }
    red[nl][ml] = lsum;
    __syncthreads();
    if (ml == 0){
      float s = 0.f;
      for (int j=0;j<16;++j) s += red[nl][j];
      rowinv[nl] = 1.f/s;
    }
    __syncthreads();
    float inv = rowinv[nl];
    for (int m = ml; m < 512; m += 16){
      float p = 0.f;
      if (m < N_){
        float v = sbuf[nl][m];
        if (relu) v = fmaxf(v, 0.f);
        p = expf(v - mx)*inv;
      }
      sbuf[nl][m] = p;
    }
    __syncthreads();
  }

  float acc4[4] = {0.f,0.f,0.f,0.f};
  for (int m0 = 0; m0 < 512; m0 += 64){
    for (int idx = tid; idx < 4096; idx += 256){
      int mm = idx >> 6, kk = idx & 63;
      int m = m0 + mm;
      mb[mm][kk] = (m < N_) ? X[(b*N_+m)*64+kk] : 0.f;
    }
    __syncthreads();
    for (int mm = 0; mm < 64; ++mm){
      float p = sbuf[nl][m0+mm];
      #pragma unroll
      for (int c = 0; c < 4; ++c) acc4[c] += p * mb[mm][ml*4+c];
    }
    __syncthreads();
  }

  if (!final_){
    if (n < N_){
      #pragma unroll
      for (int c = 0; c < 4; ++c) Y[(b*N_+n)*64 + ml*4+c] = acc4[c];
    }
    return;
  }

  {
    int row = b*N_ + n;
    #pragma unroll
    for (int c = 0; c < 4; ++c){
      float s = 0.f;
      if (n < N_) s = acc4[c] + X0[row*64 + ml*4+c] + Z1[row*64 + ml*4+c];
      vbuf[nl][ml*4+c] = s;
    }
    for (int idx = tid; idx < 4096; idx += 256){
      int kk = idx >> 6, c = idx & 63;
      mb[kk][c] = Wg[idx];
    }
    __syncthreads();
    float o4[4] = {0.f,0.f,0.f,0.f};
    for (int kk = 0; kk < 64; ++kk){
      float s = vbuf[nl][kk];
      #pragma unroll
      for (int c = 0; c < 4; ++c) o4[c] += s * mb[kk][ml*4+c];
    }
    if (n < N_){
      #pragma unroll
      for (int c = 0; c < 4; ++c){
        float val = o4[c] + bg[ml*4+c];
        if (add) cur[row*64 + ml*4+c] += val;
        else     cur[row*64 + ml*4+c]  = val;
      }
    }
  }
}

// ---------------- output head: 4 rows/block, 2 barriers ----------------
__global__ __launch_bounds__(128) void k_out(const float* __restrict__ cur,
                                             const float* __restrict__ W1, const float* __restrict__ bb1,
                                             const float* __restrict__ W2, const float* __restrict__ bb2,
                                             float* __restrict__ out){
  __shared__ float ch[4][64];
  __shared__ float hid[4*1200];   // [r][t][f]
  int tid = threadIdx.x;
  int rbase = blockIdx.x*4;
  for (int idx = tid; idx < 256; idx += 128){
    int r = idx >> 6, h = idx & 63;
    ch[r][h] = cur[(rbase+r)*64 + h];
  }
  __syncthreads();
  for (int job = tid; job < 1200; job += 128){
    int t = job / 100, f = job - t*100;
    float a0 = bb1[t*100+f], a1 = a0, a2 = a0, a3 = a0;
    for (int h = 0; h < 64; ++h){
      float w = W1[(t*64+h)*100 + f];
      a0 += ch[0][h]*w; a1 += ch[1][h]*w; a2 += ch[2][h]*w; a3 += ch[3][h]*w;
    }
    hid[0*1200+job] = (a0 > 0.f) ? a0 : expm1f(a0);
    hid[1*1200+job] = (a1 > 0.f) ? a1 : expm1f(a1);
    hid[2*1200+job] = (a2 > 0.f) ? a2 : expm1f(a2);
    hid[3*1200+job] = (a3 > 0.f) ? a3 : expm1f(a3);
  }
  __syncthreads();
  if (tid < 96){
    int r = tid / 24, rem = tid % 24;
    int t = rem >> 1, o = rem & 1;
    float a = bb2[t*2+o];
    const float* hp = hid + r*1200 + t*100;
    for (int f = 0; f < 100; ++f) a += hp[f] * W2[(t*100+f)*2+o];
    out[(rbase+r)*24 + t*2+o] = a;
  }
}

// ---------------- launch ----------------
extern "C" void kernel_launch(void* const* d_in, const int* in_sizes, int n_in,
                              void* d_out, int out_size, void* d_ws, size_t ws_size,
                              hipStream_t stream)
{
  const float* x        = (const float*)d_in[0];
  const float* geo      = (const float*)d_in[2];
  const float* fcx_W    = (const float*)d_in[3];
  const float* fcx_b    = (const float*)d_in[4];
  const float* env_cb   = (const float*)d_in[5];
  const float* nodes_cb = (const float*)d_in[6];
  const float* w_v      = (const float*)d_in[7];
  const float* w_k      = (const float*)d_in[8];
  const float* w_q      = (const float*)d_in[9];
  const float* core_W   = (const float*)d_in[10];
  const float* core_b   = (const float*)d_in[11];
  const float* tN_Win   = (const float*)d_in[12];
  const float* tN_bin   = (const float*)d_in[13];
  const float* tN_Wf    = (const float*)d_in[14];
  const float* tN_bf    = (const float*)d_in[15];
  const float* tN_Wg    = (const float*)d_in[16];
  const float* tN_bg    = (const float*)d_in[17];
  const float* tN_Wout  = (const float*)d_in[18];
  const float* tN_bout  = (const float*)d_in[19];
  const float* tP_Win   = (const float*)d_in[20];
  const float* tP_bin   = (const float*)d_in[21];
  const float* tP_Wf    = (const float*)d_in[22];
  const float* tP_bf    = (const float*)d_in[23];
  const float* tP_Wg    = (const float*)d_in[24];
  const float* tP_bg    = (const float*)d_in[25];
  const float* tP_Wout  = (const float*)d_in[26];
  const float* tP_bout  = (const float*)d_in[27];
  const float* bn1_g    = (const float*)d_in[28];
  const float* bn1_b    = (const float*)d_in[29];
  const float* bnP_g    = (const float*)d_in[30];
  const float* bnP_b    = (const float*)d_in[31];
  const float* gcn1_W   = (const float*)d_in[32];
  const float* gcn1_b   = (const float*)d_in[33];
  const float* gcn2_W   = (const float*)d_in[34];
  const float* gcn2_b   = (const float*)d_in[35];
  const float* gcnp_W   = (const float*)d_in[36];
  const float* gcnp_b   = (const float*)d_in[37];
  const float* nv_p1    = (const float*)d_in[38];
  const float* nv_p2    = (const float*)d_in[39];
  const float* nv_p3    = (const float*)d_in[40];
  const float* nv_pk    = (const float*)d_in[41];
  const float* out_W1   = (const float*)d_in[42];
  const float* out_b1   = (const float*)d_in[43];
  const float* out_W2   = (const float*)d_in[44];
  const float* out_b2   = (const float*)d_in[45];
  const int*   t_pos    = (const int*)d_in[46];
  const int*   ind      = (const int*)d_in[47];

  // Workspace: 4096 B header + 2,223,616 floats = 8,898,560 B (~8.49 MiB)
  int* node_list = (int*)d_ws;
  int* off       = node_list + 512;
  float* F = (float*)((char*)d_ws + 4096);
  float* temb   = F + 0;
  float* core_f = F + 12288;
  float* tmp1   = F + 77824;
  float* stats  = F + 143360;
  float* matq   = F + 143616;
  float* unb    = F + 175616;
  float* hpr    = F + 687616;
  float* cur    = F + 1199616;
  float* zt1    = F + 1711616;

  k_matq <<<dim3(125), dim3(256), 0, stream>>>(nodes_cb, w_q, matq);
  k_route<<<dim3(1),   dim3(256), 0, stream>>>(env_cb, w_v, w_k, matq, node_list, off);
  k_temb <<<dim3(1),   dim3(192), 0, stream>>>(t_pos, temb);
  k_core <<<dim3(256), dim3(256), 0, stream>>>(temb, core_W, core_b, core_f);
  k_tcn  <<<dim3(1000,10,2), dim3(256), 0, stream>>>(x, fcx_W, fcx_b, temb, node_list, off,
      tN_Win, tN_bin, tN_Wf, tN_bf, tN_Wg, tN_bg, tN_Wout, tN_bout,
      tP_Win, tP_bin, tP_Wf, tP_bf, tP_Wg, tP_bg, tP_Wout, tP_bout,
      unb, hpr);
  k_bnstats<<<dim3(128), dim3(256), 0, stream>>>(unb, hpr, stats);
  k_bnapply<<<dim3(4000),dim3(256), 0, stream>>>(unb, hpr, stats, bn1_g, bn1_b, bnP_g, bnP_b);

  dim3 ag(32, 16);
  // gcn1: geo adjacency on h_prev
  k_attn<<<ag, 256, 0, stream>>>(0,0,0,0, geo, nullptr,nullptr,nullptr, nullptr,nullptr,
                                 hpr, nullptr,nullptr, nullptr,nullptr, nullptr, zt1);
  k_attn<<<ag, 256, 0, stream>>>(0,0,1,0, geo, nullptr,nullptr,nullptr, nullptr,nullptr,
                                 zt1, hpr, zt1, gcn1_W, gcn1_b, cur, nullptr);
  // gcn2: causal adjacency softmax(unb @ core[b] @ hpr^T) on unbias
  k_attn<<<ag, 256, 0, stream>>>(1,0,0,0, nullptr, unb,nullptr, core_f, hpr,nullptr,
                                 unb, nullptr,nullptr, nullptr,nullptr, nullptr, zt1);
  k_attn<<<ag, 256, 0, stream>>>(1,0,1,1, nullptr, unb,nullptr, core_f, hpr,nullptr,
                                 zt1, unb, zt1, gcn2_W, gcn2_b, cur, nullptr);
  // gcnp: adaptive adjacency softmax(relu(nv_p3 @ (nv_p2 @ (te @ nv_pk)))) on unbias
  k_tmp1<<<dim3(256), dim3(256), 0, stream>>>(ind, nv_p1, nv_pk, tmp1);
  k_attn<<<ag, 256, 0, stream>>>(2,1,0,0, nullptr, nullptr,nv_p2, tmp1, nullptr,nv_p3,
                                 unb, nullptr,nullptr, nullptr,nullptr, nullptr, zt1);
  k_attn<<<ag, 256, 0, stream>>>(2,1,1,1, nullptr, nullptr,nv_p2, tmp1, nullptr,nv_p3,
                                 zt1, unb, zt1, gcnp_W, gcnp_b, cur, nullptr);
  // head
  k_out<<<dim3(2000), dim3(128), 0, stream>>>(cur, out_W1, out_b1, out_W2, out_b2, (float*)d_out);
}

// Round 8
// 1777.362 us; speedup vs baseline: 1.0553x; 1.0449x over previous
//
#include <hip/hip_runtime.h>
#include <hip/hip_bf16.h>
#include <math.h>

#define B_ 16
#define N_ 500
#define T_ 12
#define K_ 10
#define NROWS (B_*N_)   // 8000

// ---------------- threefry / gumbel (jax.random.key(42)) ----------------
__device__ __forceinline__ unsigned rotl32(unsigned v, int r){ return (v<<r)|(v>>(32-r)); }

__device__ __forceinline__ void threefry2x32(unsigned k0, unsigned k1,
                                             unsigned c0, unsigned c1,
                                             unsigned &o0, unsigned &o1){
  unsigned ks2 = k0 ^ k1 ^ 0x1BD11BDAu;
  unsigned x0 = c0 + k0, x1 = c1 + k1;
#define TF_R(r) { x0 += x1; x1 = rotl32(x1,(r)); x1 ^= x0; }
  TF_R(13) TF_R(15) TF_R(26) TF_R(6)
  x0 += k1;  x1 += ks2 + 1u;
  TF_R(17) TF_R(29) TF_R(16) TF_R(24)
  x0 += ks2; x1 += k0 + 2u;
  TF_R(13) TF_R(15) TF_R(26) TF_R(6)
  x0 += k0;  x1 += k1 + 3u;
  TF_R(17) TF_R(29) TF_R(16) TF_R(24)
  x0 += k1;  x1 += ks2 + 4u;
  TF_R(13) TF_R(15) TF_R(26) TF_R(6)
  x0 += ks2; x1 += k0 + 5u;
#undef TF_R
  o0 = x0; o1 = x1;
}

// Partitionable threefry (JAX >= 0.4.30): bits[i] = x0 ^ x1 of threefry(key,(0,i)).
// VERIFIED bit-exact vs harness (round 5 pass).
__device__ __forceinline__ float gumbel_at(unsigned idx){
  unsigned b0, b1;
  threefry2x32(0u, 42u, 0u, idx, b0, b1);
  unsigned bits = b0 ^ b1;
  float u = __uint_as_float((bits >> 9) | 0x3f800000u) - 1.0f;  // [0,1)
  u = fmaxf(u, 1.17549435e-38f);
  return -logf(-logf(u));
}

// ---------------- matq = nodes_cb @ w_q ----------------
__global__ __launch_bounds__(256) void k_matq(const float* __restrict__ nodes_cb,
                                              const float* __restrict__ w_q,
                                              float* __restrict__ matq){
  int idx = blockIdx.x*256 + threadIdx.x;
  if (idx >= N_*64) return;
  int n = idx >> 6, d = idx & 63;
  float a = 0.f;
  for (int c = 0; c < 64; ++c) a += nodes_cb[n*64+c] * w_q[c*64+d];
  matq[idx] = a;
}

// ---------------- routing ----------------
__global__ __launch_bounds__(256) void k_route(const float* __restrict__ env_cb,
                                               const float* __restrict__ w_v,
                                               const float* __restrict__ w_k,
                                               const float* __restrict__ matq,
                                               int* __restrict__ node_list,
                                               int* __restrict__ off){
  __shared__ float smk[K_*64];
  __shared__ float smv[K_*K_];
  __shared__ int sroute[N_];
  int tid = threadIdx.x;
  for (int idx = tid; idx < K_*64; idx += 256){
    int kk = idx >> 6, d = idx & 63;
    float a = 0.f;
    for (int c = 0; c < 64; ++c) a += env_cb[kk*64+c] * w_k[c*64+d];
    smk[idx] = a;
  }
  for (int idx = tid; idx < K_*K_; idx += 256){
    int kk = idx / K_, j = idx % K_;
    float a = 0.f;
    for (int c = 0; c < 64; ++c) a += env_cb[kk*64+c] * w_v[c*K_+j];
    smv[idx] = a;
  }
  __syncthreads();
  for (int n = tid; n < N_; n += 256){
    float s[K_];
    float mx = -1e30f;
    for (int j = 0; j < K_; ++j){
      float a = 0.f;
      for (int d = 0; d < 64; ++d) a += matq[n*64+d]*smk[j*64+d];
      s[j] = a * 0.125f;
      mx = fmaxf(mx, s[j]);
    }
    float sum = 0.f;
    for (int j = 0; j < K_; ++j){ s[j] = expf(s[j]-mx); sum += s[j]; }
    float inv = 1.f/sum;
    int best = 0; float bestv = -1e30f;
    for (int j2 = 0; j2 < K_; ++j2){
      float lg = 0.f;
      for (int j = 0; j < K_; ++j) lg += s[j]*inv*smv[j*K_+j2];
      float tot = lg + gumbel_at((unsigned)(n*K_+j2));
      if (tot > bestv){ bestv = tot; best = j2; }
    }
    sroute[n] = best;
  }
  __syncthreads();
  if (tid == 0){
    int cnt[K_]; for (int j=0;j<K_;++j) cnt[j]=0;
    for (int n=0;n<N_;++n) cnt[sroute[n]]++;
    int acc=0;
    for (int j=0;j<K_;++j){ off[j]=acc; acc+=cnt[j]; }
    off[K_]=acc;
    int pos[K_]; for (int j=0;j<K_;++j) pos[j]=off[j];
    for (int n=0;n<N_;++n) node_list[pos[sroute[n]]++] = n;
  }
}

// ---------------- t_emb ----------------
__global__ void k_temb(const int* __restrict__ t_pos, float* __restrict__ temb){
  int tid = threadIdx.x;
  if (tid >= B_*T_) return;
  int b = tid / T_, t = tid % T_;
  int p0 = t_pos[(b*T_+t)*2+0], p1 = t_pos[(b*T_+t)*2+1];
  float tp = (float)((p0 <= 4) ? p1 : 23 + p1);
  float c0 = -logf(10000.f)/32.f;
  for (int j = 0; j < 32; ++j){
    float a = tp * expf(c0 * (float)j);
    temb[(b*T_+t)*64 + j]      = cosf(a);
    temb[(b*T_+t)*64 + 32 + j] = sinf(a);
  }
}

// ---------------- core[b] ----------------
__global__ __launch_bounds__(256) void k_core(const float* __restrict__ temb,
                                              const float* __restrict__ core_W,
                                              const float* __restrict__ core_b,
                                              float* __restrict__ core_f){
  int idx = blockIdx.x*256 + threadIdx.x;
  if (idx >= B_*4096) return;
  int b = idx >> 12, c = idx & 4095;
  const float* te = temb + (b*T_ + 11)*64;
  float a = core_b[c];
  for (int h = 0; h < 64; ++h) a += te[h] * core_W[h*4096 + c];
  core_f[idx] = a;
}

// ---------------- tmp1[b] ----------------
__global__ __launch_bounds__(256) void k_tmp1(const int* __restrict__ ind,
                                              const float* __restrict__ nv_p1,
                                              const float* __restrict__ nv_pk,
                                              float* __restrict__ tmp1){
  int idx = blockIdx.x*256 + threadIdx.x;
  if (idx >= B_*4096) return;
  int b = idx >> 12, c = idx & 4095;
  int i0 = ind[(b*T_+1)*2+0], i1 = ind[(b*T_+1)*2+1];
  int row = (i0 <= 4) ? i1 : 23 + i1;
  const float* te = nv_p1 + row*64;
  float a = 0.f;
  for (int h = 0; h < 64; ++h) a += te[h] * nv_pk[h*4096 + c];
  tmp1[idx] = a;
}

// ---------------- fused per-expert TCN, 8 rows/block ----------------
// XCD-locality swizzle: grid.x = slot (k*2+path), padded to 24 so that
// dispatch index % 8 == slot % 8 -> each expert's weights cached in ONE XCD L2.
// grid.y = 250 chunk slots; chunk-stride loop handles any expert size.
__global__ __launch_bounds__(256) void k_tcn(
    const float* __restrict__ x,
    const float* __restrict__ fcx_W, const float* __restrict__ fcx_b,
    const float* __restrict__ temb,
    const int* __restrict__ node_list, const int* __restrict__ off,
    const float* __restrict__ WinN, const float* __restrict__ binN,
    const float* __restrict__ WfN,  const float* __restrict__ bfN,
    const float* __restrict__ WgN,  const float* __restrict__ bgN,
    const float* __restrict__ WoutN,const float* __restrict__ boutN,
    const float* __restrict__ WinP, const float* __restrict__ binP,
    const float* __restrict__ WfP,  const float* __restrict__ bfP,
    const float* __restrict__ WgP,  const float* __restrict__ bgP,
    const float* __restrict__ WoutP,const float* __restrict__ boutP,
    float* __restrict__ out_unb, float* __restrict__ out_hpr)
{
  int slot = blockIdx.x;
  if (slot >= 2*K_) return;
  int k = slot >> 1;
  int path = slot & 1;               // 0 = N (t0=1 -> unbias), 1 = P (t0=0 -> h_prev)
  int cnt = off[k+1] - off[k];
  int rows = cnt * 16;

  const float* Win  = (path ? WinP  : WinN)  + k*16384;
  const float* bin  = (path ? binP  : binN)  + k*128;
  const float* Wf   = (path ? WfP   : WfN)   + k*4*16384;
  const float* bf_  = (path ? bfP   : bfN)   + k*2*128;
  const float* Wg   = (path ? WgP   : WgN)   + k*4*16384;
  const float* bg_  = (path ? bgP   : bgN)   + k*2*128;
  const float* Wout = (path ? WoutP : WoutN) + k*8192;
  const float* bout = (path ? boutP : boutN) + k*64;
  float* outb = path ? out_hpr : out_unb;
  int t0 = path ? 0 : 1;

  __shared__ __align__(16) float sIn[4096];   // input only
  __shared__ __align__(16) float sH0[4096];   // h0 only
  __shared__ __align__(16) float sH1[2048];   // h1 only
  __shared__ __align__(16) float sH2[1024];   // h2 only
  __shared__ int rowBN[8];
  __shared__ int rowB[8];

  int tid = threadIdx.x;

  for (int chunk = blockIdx.y; chunk*8 < rows; chunk += 250){
    int r0 = chunk * 8;

    if (tid < 8){
      int r = r0 + tid;
      if (r < rows){
        int node = node_list[off[k] + (r >> 4)];
        int b = r & 15;
        rowBN[tid] = b*N_ + node;
        rowB[tid]  = b;
      } else { rowBN[tid] = -1; rowB[tid] = 0; }
    }
    __syncthreads();

    // Stage 0: build input tile
    for (int i = 0; i < 8; ++i){
      int rb = rowBN[i], b = rowB[i];
      for (int c2 = tid; c2 < 512; c2 += 256){
        int t = (c2 >> 7) + t0, c = c2 & 127;
        float v = 0.f;
        if (rb >= 0){
          if (c < 64){
            const float* xp = x + (rb*T_ + t)*2;
            v = xp[0]*fcx_W[c] + xp[1]*fcx_W[64+c] + fcx_b[c];
          } else {
            v = temb[(b*T_ + t)*64 + (c-64)];
          }
        }
        sIn[i*512 + c2] = v;
      }
    }
    __syncthreads();

    // Stage 1: h0 = xin @ Win + bin. 2 cols x 8 rt rows per thread.
    {
      int oc = (tid & 63)*2;
      int jg = (tid >> 6)*8;
      float a0[8], a1[8];
      #pragma unroll
      for (int j=0;j<8;++j){ a0[j]=0.f; a1[j]=0.f; }
      for (int c = 0; c < 128; c += 4){
        float2 w0 = *(const float2*)(Win + (c+0)*128 + oc);
        float2 w1 = *(const float2*)(Win + (c+1)*128 + oc);
        float2 w2 = *(const float2*)(Win + (c+2)*128 + oc);
        float2 w3 = *(const float2*)(Win + (c+3)*128 + oc);
        #pragma unroll
        for (int j=0;j<8;++j){
          float4 xv = *(const float4*)&sIn[(jg+j)*128 + c];
          a0[j] += xv.x*w0.x + xv.y*w1.x + xv.z*w2.x + xv.w*w3.x;
          a1[j] += xv.x*w0.y + xv.y*w1.y + xv.z*w2.y + xv.w*w3.y;
        }
      }
      float b0v = bin[oc], b1v = bin[oc+1];
      #pragma unroll
      for (int j=0;j<8;++j){
        sH0[(jg+j)*128 + oc]   = a0[j] + b0v;
        sH0[(jg+j)*128 + oc+1] = a1[j] + b1v;
      }
    }
    __syncthreads();

    // Stage 2: block0 (d=1), fused f+g, reads sH0, writes sH1.
    {
      int o = tid & 127;
      int jg = (tid >> 7)*8;
      float af[8], ag[8];
      #pragma unroll
      for (int j=0;j<8;++j){ af[j]=0.f; ag[j]=0.f; }
      for (int c = 0; c < 128; c += 4){
        float f00=Wf[(c+0)*128+o], f01=Wf[(c+1)*128+o], f02=Wf[(c+2)*128+o], f03=Wf[(c+3)*128+o];
        float f10=Wf[16384+(c+0)*128+o], f11=Wf[16384+(c+1)*128+o], f12=Wf[16384+(c+2)*128+o], f13=Wf[16384+(c+3)*128+o];
        float g00=Wg[(c+0)*128+o], g01=Wg[(c+1)*128+o], g02=Wg[(c+2)*128+o], g03=Wg[(c+3)*128+o];
        float g10=Wg[16384+(c+0)*128+o], g11=Wg[16384+(c+1)*128+o], g12=Wg[16384+(c+2)*128+o], g13=Wg[16384+(c+3)*128+o];
        #pragma unroll
        for (int jj=0;jj<8;++jj){
          int j = jg + jj;
          int i = j >> 1, ti = j & 1;
          float4 xa = *(const float4*)&sH0[(i*4+ti*2  )*128 + c];
          float4 xb = *(const float4*)&sH0[(i*4+ti*2+1)*128 + c];
          af[jj] += xa.x*f00 + xa.y*f01 + xa.z*f02 + xa.w*f03
                  + xb.x*f10 + xb.y*f11 + xb.z*f12 + xb.w*f13;
          ag[jj] += xa.x*g00 + xa.y*g01 + xa.z*g02 + xa.w*g03
                  + xb.x*g10 + xb.y*g11 + xb.z*g12 + xb.w*g13;
        }
      }
      float bfv = bf_[o], bgv = bg_[o];
      #pragma unroll
      for (int jj=0;jj<8;++jj){
        int j = jg + jj;
        int i = j >> 1, ti = j & 1;
        float f = tanhf(af[jj] + bfv);
        float g = 1.f/(1.f + expf(-(ag[jj] + bgv)));
        sH1[j*128 + o] = f*g + sH0[(i*4 + ti*2 + 1)*128 + o];
      }
    }
    __syncthreads();

    // Stage 3: block1 (d=2), fused f+g, reads sH1, writes sH2.
    {
      int o = tid & 127;
      int ig = (tid >> 7)*4;
      const float* Wf1 = Wf + 2*16384;
      const float* Wg1 = Wg + 2*16384;
      float af[4], ag[4];
      #pragma unroll
      for (int i=0;i<4;++i){ af[i]=0.f; ag[i]=0.f; }
      for (int c = 0; c < 128; c += 4){
        float f00=Wf1[(c+0)*128+o], f01=Wf1[(c+1)*128+o], f02=Wf1[(c+2)*128+o], f03=Wf1[(c+3)*128+o];
        float f10=Wf1[16384+(c+0)*128+o], f11=Wf1[16384+(c+1)*128+o], f12=Wf1[16384+(c+2)*128+o], f13=Wf1[16384+(c+3)*128+o];
        float g00=Wg1[(c+0)*128+o], g01=Wg1[(c+1)*128+o], g02=Wg1[(c+2)*128+o], g03=Wg1[(c+3)*128+o];
        float g10=Wg1[16384+(c+0)*128+o], g11=Wg1[16384+(c+1)*128+o], g12=Wg1[16384+(c+2)*128+o], g13=Wg1[16384+(c+3)*128+o];
        #pragma unroll
        for (int ii=0;ii<4;++ii){
          int i = ig + ii;
          float4 xa = *(const float4*)&sH1[(i*2+0)*128 + c];
          float4 xb = *(const float4*)&sH1[(i*2+1)*128 + c];
          af[ii] += xa.x*f00 + xa.y*f01 + xa.z*f02 + xa.w*f03
                  + xb.x*f10 + xb.y*f11 + xb.z*f12 + xb.w*f13;
          ag[ii] += xa.x*g00 + xa.y*g01 + xa.z*g02 + xa.w*g03
                  + xb.x*g10 + xb.y*g11 + xb.z*g12 + xb.w*g13;
        }
      }
      float bfv = bf_[128+o], bgv = bg_[128+o];
      #pragma unroll
      for (int ii=0;ii<4;++ii){
        int i = ig + ii;
        float f = tanhf(af[ii] + bfv);
        float g = 1.f/(1.f + expf(-(ag[ii] + bgv)));
        sH2[i*128 + o] = f*g + sH1[(i*2+1)*128 + o];
      }
    }
    __syncthreads();

    // Stage 4: out = h2 @ Wout + bout (128 -> 64)
    {
      int o6 = tid & 63, grp = tid >> 6;
      #pragma unroll
      for (int ii=0; ii<2; ++ii){
        int i = grp*2 + ii;
        float acc = 0.f;
        for (int c = 0; c < 128; c += 4){
          float w0=Wout[(c+0)*64+o6], w1=Wout[(c+1)*64+o6],
                w2=Wout[(c+2)*64+o6], w3=Wout[(c+3)*64+o6];
          float4 xv = *(const float4*)&sH2[i*128 + c];
          acc += xv.x*w0 + xv.y*w1 + xv.z*w2 + xv.w*w3;
        }
        if (rowBN[i] >= 0) outb[rowBN[i]*64 + o6] = acc + bout[o6];
      }
    }
    __syncthreads();   // protect rowBN/sH2 before next loop iteration
  }
}

// ---------------- batchnorm ----------------
__global__ __launch_bounds__(256) void k_bnstats(const float* __restrict__ unb,
                                                 const float* __restrict__ hpr,
                                                 float* __restrict__ stats){
  int bid = blockIdx.x;
  int tensor = bid >> 6, c = bid & 63;
  const float* buf = tensor ? hpr : unb;
  float s1 = 0.f, s2 = 0.f;
  for (int r = threadIdx.x; r < NROWS; r += 256){
    float v = buf[r*64 + c];
    s1 += v; s2 += v*v;
  }
  __shared__ float r1[256], r2[256];
  r1[threadIdx.x]=s1; r2[threadIdx.x]=s2;
  __syncthreads();
  for (int s=128; s>0; s>>=1){
    if (threadIdx.x < s){ r1[threadIdx.x]+=r1[threadIdx.x+s]; r2[threadIdx.x]+=r2[threadIdx.x+s]; }
    __syncthreads();
  }
  if (threadIdx.x==0){
    float mean = r1[0]/(float)NROWS;
    float var  = r2[0]/(float)NROWS - mean*mean;
    stats[tensor*128 + c]      = mean;
    stats[tensor*128 + 64 + c] = rsqrtf(var + 1e-5f);
  }
}

__global__ __launch_bounds__(256) void k_bnapply(float* __restrict__ unb, float* __restrict__ hpr,
                                                 const float* __restrict__ stats,
                                                 const float* __restrict__ g1, const float* __restrict__ be1,
                                                 const float* __restrict__ gP, const float* __restrict__ beP){
  int idx = blockIdx.x*256 + threadIdx.x;
  if (idx >= 2*NROWS*64) return;
  int tensor = idx >= NROWS*64;
  int local = idx - tensor*NROWS*64;
  int c = local & 63;
  float* buf = tensor ? hpr : unb;
  float mean = stats[tensor*128+c], rstd = stats[tensor*128+64+c];
  float g = tensor ? gP[c] : g1[c];
  float bb = tensor ? beP[c] : be1[c];
  buf[local] = g * (buf[local]-mean) * rstd + bb;
}

// ---------------- fused adjacency build + apply ----------------
// Templated (distinct kernel names in rocprof). Register double-buffered
// prefetch of Keys/X chunks: global loads issued pre-compute, ds_write
// post-compute -> vmcnt drain overlaps LDS compute. One barrier per chunk.
template<int AMODE, int RELU, int FINAL, int ADD>
__global__ __launch_bounds__(256) void k_attn(
    const float* __restrict__ geo,
    const float* __restrict__ Qf, const float* __restrict__ Qb,
    const float* __restrict__ M,
    const float* __restrict__ Keysf, const float* __restrict__ Keysb,
    const float* __restrict__ X,
    const float* __restrict__ X0, const float* __restrict__ Z1,
    const float* __restrict__ Wg, const float* __restrict__ bg,
    float* __restrict__ cur, float* __restrict__ Y)
{
  __shared__ float vbuf[16][65];
  __shared__ float mb[2][64][65];
  __shared__ float sbuf[16][513];
  __shared__ float red[16][17];
  __shared__ float rowm[16], rowinv[16];

  int b = blockIdx.y, n0 = blockIdx.x*16;
  int tid = threadIdx.x;
  int nl = tid >> 4, ml = tid & 15;
  int n = n0 + nl;
  float rr[16];

  if (AMODE == 0){
    for (int idx = tid; idx < 16*512; idx += 256){
      int r = idx >> 9, m = idx & 511;
      int nn = n0 + r;
      sbuf[r][m] = (nn < N_ && m < N_) ? geo[nn*N_+m] : 0.f;
    }
    __syncthreads();
  } else {
    for (int idx = tid; idx < 1024; idx += 256){
      int r = idx >> 6, kk = idx & 63;
      int nn = n0 + r;
      float q = 0.f;
      if (nn < N_) q = (AMODE == 1) ? Qf[(b*N_+nn)*64+kk] : Qb[nn*64+kk];
      vbuf[r][kk] = q;
    }
    for (int idx = tid; idx < 4096; idx += 256){
      int kk = idx >> 6, c = idx & 63;
      mb[0][kk][c] = M[b*4096 + idx];
    }
    __syncthreads();
    float v4[4] = {0.f,0.f,0.f,0.f};
    for (int kk = 0; kk < 64; ++kk){
      float q = vbuf[nl][kk];
      #pragma unroll
      for (int c = 0; c < 4; ++c) v4[c] += q * mb[0][kk][ml*4+c];
    }
    __syncthreads();
    #pragma unroll
    for (int c = 0; c < 4; ++c) vbuf[nl][ml*4+c] = v4[c];

    // scores: double-buffered key streaming
    #pragma unroll
    for (int ii=0; ii<16; ++ii){
      int idx = tid + ii*256;
      int mm = idx >> 6, kk = idx & 63;
      rr[ii] = (AMODE == 1) ? Keysf[(b*N_+mm)*64+kk] : Keysb[mm*64+kk];  // chunk 0: mm<64<N_
    }
    #pragma unroll
    for (int ii=0; ii<16; ++ii){
      int idx = tid + ii*256;
      mb[0][idx >> 6][idx & 63] = rr[ii];
    }
    __syncthreads();
    for (int ci = 0; ci < 8; ++ci){
      int m0 = ci*64;
      int cb = ci & 1, nb = (ci+1) & 1;
      if (ci < 7){
        #pragma unroll
        for (int ii=0; ii<16; ++ii){
          int idx = tid + ii*256;
          int mm = idx >> 6, kk = idx & 63;
          int m = m0 + 64 + mm;
          rr[ii] = 0.f;
          if (m < N_) rr[ii] = (AMODE == 1) ? Keysf[(b*N_+m)*64+kk] : Keysb[m*64+kk];
        }
      }
      #pragma unroll
      for (int mi = 0; mi < 4; ++mi){
        int mloc = ml + 16*mi;
        float a = 0.f;
        for (int kk = 0; kk < 64; ++kk) a += vbuf[nl][kk]*mb[cb][mloc][kk];
        sbuf[nl][m0+mloc] = a;
      }
      if (ci < 7){
        #pragma unroll
        for (int ii=0; ii<16; ++ii){
          int idx = tid + ii*256;
          mb[nb][idx >> 6][idx & 63] = rr[ii];
        }
      }
      __syncthreads();
    }
    // row softmax
    float lmax = -1e30f;
    for (int m = ml; m < N_; m += 16){
      float v = sbuf[nl][m];
      if (RELU) v = fmaxf(v, 0.f);
      lmax = fmaxf(lmax, v);
    }
    red[nl][ml] = lmax;
    __syncthreads();
    if (ml == 0){
      float mx = red[nl][0];
      for (int j=1;j<16;++j) mx = fmaxf(mx, red[nl][j]);
      rowm[nl] = mx;
    }
    __syncthreads();
    float mx = rowm[nl];
    float lsum = 0.f;
    for (int m = ml; m < N_; m += 16){
      float v = sbuf[nl][m];
      if (RELU) v = fmaxf(v, 0.f);
      lsum += expf(v - mx);
    }
    red[nl][ml] = lsum;
    __syncthreads();
    if (ml == 0){
      float s = 0.f;
      for (int j=0;j<16;++j) s += red[nl][j];
      rowinv[nl] = 1.f/s;
    }
    __syncthreads();
    float inv = rowinv[nl];
    for (int m = ml; m < 512; m += 16){
      float p = 0.f;
      if (m < N_){
        float v = sbuf[nl][m];
        if (RELU) v = fmaxf(v, 0.f);
        p = expf(v - mx)*inv;
      }
      sbuf[nl][m] = p;
    }
    __syncthreads();
  }

  // apply: Y_tile = A_tile @ X[b], double-buffered X streaming
  float acc4[4] = {0.f,0.f,0.f,0.f};
  #pragma unroll
  for (int ii=0; ii<16; ++ii){
    int idx = tid + ii*256;
    int mm = idx >> 6, kk = idx & 63;
    rr[ii] = X[(b*N_+mm)*64+kk];    // chunk 0: mm<64<N_
  }
  #pragma unroll
  for (int ii=0; ii<16; ++ii){
    int idx = tid + ii*256;
    mb[0][idx >> 6][idx & 63] = rr[ii];
  }
  __syncthreads();
  for (int ci = 0; ci < 8; ++ci){
    int m0 = ci*64;
    int cb = ci & 1, nb = (ci+1) & 1;
    if (ci < 7){
      #pragma unroll
      for (int ii=0; ii<16; ++ii){
        int idx = tid + ii*256;
        int mm = idx >> 6, kk = idx & 63;
        int m = m0 + 64 + mm;
        rr[ii] = (m < N_) ? X[(b*N_+m)*64+kk] : 0.f;
      }
    }
    for (int mm = 0; mm < 64; ++mm){
      float p = sbuf[nl][m0+mm];
      #pragma unroll
      for (int c = 0; c < 4; ++c) acc4[c] += p * mb[cb][mm][ml*4+c];
    }
    if (ci < 7){
      #pragma unroll
      for (int ii=0; ii<16; ++ii){
        int idx = tid + ii*256;
        mb[nb][idx >> 6][idx & 63] = rr[ii];
      }
    }
    __syncthreads();
  }

  if (!FINAL){
    if (n < N_){
      #pragma unroll
      for (int c = 0; c < 4; ++c) Y[(b*N_+n)*64 + ml*4+c] = acc4[c];
    }
    return;
  }

  // epilogue: cur (+)= (X0 + Z1 + Y) @ Wg + bg
  {
    int row = b*N_ + n;
    #pragma unroll
    for (int c = 0; c < 4; ++c){
      float s = 0.f;
      if (n < N_) s = acc4[c] + X0[row*64 + ml*4+c] + Z1[row*64 + ml*4+c];
      vbuf[nl][ml*4+c] = s;
    }
    for (int idx = tid; idx < 4096; idx += 256){
      int kk = idx >> 6, c = idx & 63;
      mb[0][kk][c] = Wg[idx];
    }
    __syncthreads();
    float o4[4] = {0.f,0.f,0.f,0.f};
    for (int kk = 0; kk < 64; ++kk){
      float s = vbuf[nl][kk];
      #pragma unroll
      for (int c = 0; c < 4; ++c) o4[c] += s * mb[0][kk][ml*4+c];
    }
    if (n < N_){
      #pragma unroll
      for (int c = 0; c < 4; ++c){
        float val = o4[c] + bg[ml*4+c];
        if (ADD) cur[row*64 + ml*4+c] += val;
        else     cur[row*64 + ml*4+c]  = val;
      }
    }
  }
}

// ---------------- output head: 4 rows/block, 2 barriers ----------------
__global__ __launch_bounds__(128) void k_out(const float* __restrict__ cur,
                                             const float* __restrict__ W1, const float* __restrict__ bb1,
                                             const float* __restrict__ W2, const float* __restrict__ bb2,
                                             float* __restrict__ out){
  __shared__ float ch[4][64];
  __shared__ float hid[4*1200];   // [r][t][f]
  int tid = threadIdx.x;
  int rbase = blockIdx.x*4;
  for (int idx = tid; idx < 256; idx += 128){
    int r = idx >> 6, h = idx & 63;
    ch[r][h] = cur[(rbase+r)*64 + h];
  }
  __syncthreads();
  for (int job = tid; job < 1200; job += 128){
    int t = job / 100, f = job - t*100;
    float a0 = bb1[t*100+f], a1 = a0, a2 = a0, a3 = a0;
    for (int h = 0; h < 64; ++h){
      float w = W1[(t*64+h)*100 + f];
      a0 += ch[0][h]*w; a1 += ch[1][h]*w; a2 += ch[2][h]*w; a3 += ch[3][h]*w;
    }
    hid[0*1200+job] = (a0 > 0.f) ? a0 : expm1f(a0);
    hid[1*1200+job] = (a1 > 0.f) ? a1 : expm1f(a1);
    hid[2*1200+job] = (a2 > 0.f) ? a2 : expm1f(a2);
    hid[3*1200+job] = (a3 > 0.f) ? a3 : expm1f(a3);
  }
  __syncthreads();
  if (tid < 96){
    int r = tid / 24, rem = tid % 24;
    int t = rem >> 1, o = rem & 1;
    float a = bb2[t*2+o];
    const float* hp = hid + r*1200 + t*100;
    for (int f = 0; f < 100; ++f) a += hp[f] * W2[(t*100+f)*2+o];
    out[(rbase+r)*24 + t*2+o] = a;
  }
}

// ---------------- launch ----------------
extern "C" void kernel_launch(void* const* d_in, const int* in_sizes, int n_in,
                              void* d_out, int out_size, void* d_ws, size_t ws_size,
                              hipStream_t stream)
{
  const float* x        = (const float*)d_in[0];
  const float* geo      = (const float*)d_in[2];
  const float* fcx_W    = (const float*)d_in[3];
  const float* fcx_b    = (const float*)d_in[4];
  const float* env_cb   = (const float*)d_in[5];
  const float* nodes_cb = (const float*)d_in[6];
  const float* w_v      = (const float*)d_in[7];
  const float* w_k      = (const float*)d_in[8];
  const float* w_q      = (const float*)d_in[9];
  const float* core_W   = (const float*)d_in[10];
  const float* core_b   = (const float*)d_in[11];
  const float* tN_Win   = (const float*)d_in[12];
  const float* tN_bin   = (const float*)d_in[13];
  const float* tN_Wf    = (const float*)d_in[14];
  const float* tN_bf    = (const float*)d_in[15];
  const float* tN_Wg    = (const float*)d_in[16];
  const float* tN_bg    = (const float*)d_in[17];
  const float* tN_Wout  = (const float*)d_in[18];
  const float* tN_bout  = (const float*)d_in[19];
  const float* tP_Win   = (const float*)d_in[20];
  const float* tP_bin   = (const float*)d_in[21];
  const float* tP_Wf    = (const float*)d_in[22];
  const float* tP_bf    = (const float*)d_in[23];
  const float* tP_Wg    = (const float*)d_in[24];
  const float* tP_bg    = (const float*)d_in[25];
  const float* tP_Wout  = (const float*)d_in[26];
  const float* tP_bout  = (const float*)d_in[27];
  const float* bn1_g    = (const float*)d_in[28];
  const float* bn1_b    = (const float*)d_in[29];
  const float* bnP_g    = (const float*)d_in[30];
  const float* bnP_b    = (const float*)d_in[31];
  const float* gcn1_W   = (const float*)d_in[32];
  const float* gcn1_b   = (const float*)d_in[33];
  const float* gcn2_W   = (const float*)d_in[34];
  const float* gcn2_b   = (const float*)d_in[35];
  const float* gcnp_W   = (const float*)d_in[36];
  const float* gcnp_b   = (const float*)d_in[37];
  const float* nv_p1    = (const float*)d_in[38];
  const float* nv_p2    = (const float*)d_in[39];
  const float* nv_p3    = (const float*)d_in[40];
  const float* nv_pk    = (const float*)d_in[41];
  const float* out_W1   = (const float*)d_in[42];
  const float* out_b1   = (const float*)d_in[43];
  const float* out_W2   = (const float*)d_in[44];
  const float* out_b2   = (const float*)d_in[45];
  const int*   t_pos    = (const int*)d_in[46];
  const int*   ind      = (const int*)d_in[47];

  // Workspace: 4096 B header + 2,223,616 floats = 8,898,560 B (~8.49 MiB)
  int* node_list = (int*)d_ws;
  int* off       = node_list + 512;
  float* F = (float*)((char*)d_ws + 4096);
  float* temb   = F + 0;
  float* core_f = F + 12288;
  float* tmp1   = F + 77824;
  float* stats  = F + 143360;
  float* matq   = F + 143616;
  float* unb    = F + 175616;
  float* hpr    = F + 687616;
  float* cur    = F + 1199616;
  float* zt1    = F + 1711616;

  k_matq <<<dim3(125), dim3(256), 0, stream>>>(nodes_cb, w_q, matq);
  k_route<<<dim3(1),   dim3(256), 0, stream>>>(env_cb, w_v, w_k, matq, node_list, off);
  k_temb <<<dim3(1),   dim3(192), 0, stream>>>(t_pos, temb);
  k_core <<<dim3(256), dim3(256), 0, stream>>>(temb, core_W, core_b, core_f);
  k_tcn  <<<dim3(24, 250), dim3(256), 0, stream>>>(x, fcx_W, fcx_b, temb, node_list, off,
      tN_Win, tN_bin, tN_Wf, tN_bf, tN_Wg, tN_bg, tN_Wout, tN_bout,
      tP_Win, tP_bin, tP_Wf, tP_bf, tP_Wg, tP_bg, tP_Wout, tP_bout,
      unb, hpr);
  k_bnstats<<<dim3(128), dim3(256), 0, stream>>>(unb, hpr, stats);
  k_bnapply<<<dim3(4000),dim3(256), 0, stream>>>(unb, hpr, stats, bn1_g, bn1_b, bnP_g, bnP_b);

  dim3 ag(32, 16);
  // gcn1: geo adjacency on h_prev
  k_attn<0,0,0,0><<<ag, 256, 0, stream>>>(geo, nullptr,nullptr,nullptr, nullptr,nullptr,
                                 hpr, nullptr,nullptr, nullptr,nullptr, nullptr, zt1);
  k_attn<0,0,1,0><<<ag, 256, 0, stream>>>(geo, nullptr,nullptr,nullptr, nullptr,nullptr,
                                 zt1, hpr, zt1, gcn1_W, gcn1_b, cur, nullptr);
  // gcn2: causal adjacency softmax(unb @ core[b] @ hpr^T) on unbias
  k_attn<1,0,0,0><<<ag, 256, 0, stream>>>(nullptr, unb,nullptr, core_f, hpr,nullptr,
                                 unb, nullptr,nullptr, nullptr,nullptr, nullptr, zt1);
  k_attn<1,0,1,1><<<ag, 256, 0, stream>>>(nullptr, unb,nullptr, core_f, hpr,nullptr,
                                 zt1, unb, zt1, gcn2_W, gcn2_b, cur, nullptr);
  // gcnp: adaptive adjacency softmax(relu(nv_p3 @ (nv_p2 @ (te @ nv_pk)))) on unbias
  k_tmp1<<<dim3(256), dim3(256), 0, stream>>>(ind, nv_p1, nv_pk, tmp1);
  k_attn<2,1,0,0><<<ag, 256, 0, stream>>>(nullptr, nullptr,nv_p2, tmp1, nullptr,nv_p3,
                                 unb, nullptr,nullptr, nullptr,nullptr, nullptr, zt1);
  k_attn<2,1,1,1><<<ag, 256, 0, stream>>>(nullptr, nullptr,nv_p2, tmp1, nullptr,nv_p3,
                                 zt1, unb, zt1, gcnp_W, gcnp_b, cur, nullptr);
  // head
  k_out<<<dim3(2000), dim3(128), 0, stream>>>(cur, out_W1, out_b1, out_W2, out_b2, (float*)d_out);
}

// Round 9
// 1344.677 us; speedup vs baseline: 1.3949x; 1.3218x over previous
//
#include <hip/hip_runtime.h>
#include <hip/hip_bf16.h>
#include <math.h>

#define B_ 16
#define N_ 500
#define T_ 12
#define K_ 10
#define NROWS (B_*N_)   // 8000

// ---------------- threefry / gumbel (jax.random.key(42)) ----------------
__device__ __forceinline__ unsigned rotl32(unsigned v, int r){ return (v<<r)|(v>>(32-r)); }

__device__ __forceinline__ void threefry2x32(unsigned k0, unsigned k1,
                                             unsigned c0, unsigned c1,
                                             unsigned &o0, unsigned &o1){
  unsigned ks2 = k0 ^ k1 ^ 0x1BD11BDAu;
  unsigned x0 = c0 + k0, x1 = c1 + k1;
#define TF_R(r) { x0 += x1; x1 = rotl32(x1,(r)); x1 ^= x0; }
  TF_R(13) TF_R(15) TF_R(26) TF_R(6)
  x0 += k1;  x1 += ks2 + 1u;
  TF_R(17) TF_R(29) TF_R(16) TF_R(24)
  x0 += ks2; x1 += k0 + 2u;
  TF_R(13) TF_R(15) TF_R(26) TF_R(6)
  x0 += k0;  x1 += k1 + 3u;
  TF_R(17) TF_R(29) TF_R(16) TF_R(24)
  x0 += k1;  x1 += ks2 + 4u;
  TF_R(13) TF_R(15) TF_R(26) TF_R(6)
  x0 += ks2; x1 += k0 + 5u;
#undef TF_R
  o0 = x0; o1 = x1;
}

// Partitionable threefry (JAX >= 0.4.30): bits[i] = x0 ^ x1 of threefry(key,(0,i)).
// VERIFIED bit-exact vs harness (round 5 pass).
__device__ __forceinline__ float gumbel_at(unsigned idx){
  unsigned b0, b1;
  threefry2x32(0u, 42u, 0u, idx, b0, b1);
  unsigned bits = b0 ^ b1;
  float u = __uint_as_float((bits >> 9) | 0x3f800000u) - 1.0f;  // [0,1)
  u = fmaxf(u, 1.17549435e-38f);
  return -logf(-logf(u));
}

// ---------------- matq = nodes_cb @ w_q ----------------
__global__ __launch_bounds__(256) void k_matq(const float* __restrict__ nodes_cb,
                                              const float* __restrict__ w_q,
                                              float* __restrict__ matq){
  int idx = blockIdx.x*256 + threadIdx.x;
  if (idx >= N_*64) return;
  int n = idx >> 6, d = idx & 63;
  float a = 0.f;
  for (int c = 0; c < 64; ++c) a += nodes_cb[n*64+c] * w_q[c*64+d];
  matq[idx] = a;
}

// ---------------- routing ----------------
__global__ __launch_bounds__(256) void k_route(const float* __restrict__ env_cb,
                                               const float* __restrict__ w_v,
                                               const float* __restrict__ w_k,
                                               const float* __restrict__ matq,
                                               int* __restrict__ node_list,
                                               int* __restrict__ off){
  __shared__ float smk[K_*64];
  __shared__ float smv[K_*K_];
  __shared__ int sroute[N_];
  int tid = threadIdx.x;
  for (int idx = tid; idx < K_*64; idx += 256){
    int kk = idx >> 6, d = idx & 63;
    float a = 0.f;
    for (int c = 0; c < 64; ++c) a += env_cb[kk*64+c] * w_k[c*64+d];
    smk[idx] = a;
  }
  for (int idx = tid; idx < K_*K_; idx += 256){
    int kk = idx / K_, j = idx % K_;
    float a = 0.f;
    for (int c = 0; c < 64; ++c) a += env_cb[kk*64+c] * w_v[c*K_+j];
    smv[idx] = a;
  }
  __syncthreads();
  for (int n = tid; n < N_; n += 256){
    float s[K_];
    float mx = -1e30f;
    for (int j = 0; j < K_; ++j){
      float a = 0.f;
      for (int d = 0; d < 64; ++d) a += matq[n*64+d]*smk[j*64+d];
      s[j] = a * 0.125f;
      mx = fmaxf(mx, s[j]);
    }
    float sum = 0.f;
    for (int j = 0; j < K_; ++j){ s[j] = expf(s[j]-mx); sum += s[j]; }
    float inv = 1.f/sum;
    int best = 0; float bestv = -1e30f;
    for (int j2 = 0; j2 < K_; ++j2){
      float lg = 0.f;
      for (int j = 0; j < K_; ++j) lg += s[j]*inv*smv[j*K_+j2];
      float tot = lg + gumbel_at((unsigned)(n*K_+j2));
      if (tot > bestv){ bestv = tot; best = j2; }
    }
    sroute[n] = best;
  }
  __syncthreads();
  if (tid == 0){
    int cnt[K_]; for (int j=0;j<K_;++j) cnt[j]=0;
    for (int n=0;n<N_;++n) cnt[sroute[n]]++;
    int acc=0;
    for (int j=0;j<K_;++j){ off[j]=acc; acc+=cnt[j]; }
    off[K_]=acc;
    int pos[K_]; for (int j=0;j<K_;++j) pos[j]=off[j];
    for (int n=0;n<N_;++n) node_list[pos[sroute[n]]++] = n;
  }
}

// ---------------- t_emb ----------------
__global__ void k_temb(const int* __restrict__ t_pos, float* __restrict__ temb){
  int tid = threadIdx.x;
  if (tid >= B_*T_) return;
  int b = tid / T_, t = tid % T_;
  int p0 = t_pos[(b*T_+t)*2+0], p1 = t_pos[(b*T_+t)*2+1];
  float tp = (float)((p0 <= 4) ? p1 : 23 + p1);
  float c0 = -logf(10000.f)/32.f;
  for (int j = 0; j < 32; ++j){
    float a = tp * expf(c0 * (float)j);
    temb[(b*T_+t)*64 + j]      = cosf(a);
    temb[(b*T_+t)*64 + 32 + j] = sinf(a);
  }
}

// ---------------- core[b] ----------------
__global__ __launch_bounds__(256) void k_core(const float* __restrict__ temb,
                                              const float* __restrict__ core_W,
                                              const float* __restrict__ core_b,
                                              float* __restrict__ core_f){
  int idx = blockIdx.x*256 + threadIdx.x;
  if (idx >= B_*4096) return;
  int b = idx >> 12, c = idx & 4095;
  const float* te = temb + (b*T_ + 11)*64;
  float a = core_b[c];
  for (int h = 0; h < 64; ++h) a += te[h] * core_W[h*4096 + c];
  core_f[idx] = a;
}

// ---------------- tmp1[b] ----------------
__global__ __launch_bounds__(256) void k_tmp1(const int* __restrict__ ind,
                                              const float* __restrict__ nv_p1,
                                              const float* __restrict__ nv_pk,
                                              float* __restrict__ tmp1){
  int idx = blockIdx.x*256 + threadIdx.x;
  if (idx >= B_*4096) return;
  int b = idx >> 12, c = idx & 4095;
  int i0 = ind[(b*T_+1)*2+0], i1 = ind[(b*T_+1)*2+1];
  int row = (i0 <= 4) ? i1 : 23 + i1;
  const float* te = nv_p1 + row*64;
  float a = 0.f;
  for (int h = 0; h < 64; ++h) a += te[h] * nv_pk[h*4096 + c];
  tmp1[idx] = a;
}

// ---------------- fused per-expert TCN, 8 rows/block, ONE chunk per block ----------------
// XCD-locality swizzle: grid.x = slot (k*2+path) padded to 24; 24 % 8 == 0 so
// XCD = (x + 24y) % 8 = x % 8 -> each expert's weights cached in ONE XCD L2.
// No chunk loop (round-8 regression: loop state pushed VGPR 128->188, occupancy 21->8%).
__global__ __launch_bounds__(256) void k_tcn(
    const float* __restrict__ x,
    const float* __restrict__ fcx_W, const float* __restrict__ fcx_b,
    const float* __restrict__ temb,
    const int* __restrict__ node_list, const int* __restrict__ off,
    const float* __restrict__ WinN, const float* __restrict__ binN,
    const float* __restrict__ WfN,  const float* __restrict__ bfN,
    const float* __restrict__ WgN,  const float* __restrict__ bgN,
    const float* __restrict__ WoutN,const float* __restrict__ boutN,
    const float* __restrict__ WinP, const float* __restrict__ binP,
    const float* __restrict__ WfP,  const float* __restrict__ bfP,
    const float* __restrict__ WgP,  const float* __restrict__ bgP,
    const float* __restrict__ WoutP,const float* __restrict__ boutP,
    float* __restrict__ out_unb, float* __restrict__ out_hpr)
{
  int slot = blockIdx.x;
  if (slot >= 2*K_) return;
  int k = slot >> 1;
  int path = slot & 1;               // 0 = N (t0=1 -> unbias), 1 = P (t0=0 -> h_prev)
  int cnt = off[k+1] - off[k];
  int rows = cnt * 16;
  int r0 = blockIdx.y * 8;
  if (r0 >= rows) return;

  const float* Win  = (path ? WinP  : WinN)  + k*16384;
  const float* bin  = (path ? binP  : binN)  + k*128;
  const float* Wf   = (path ? WfP   : WfN)   + k*4*16384;
  const float* bf_  = (path ? bfP   : bfN)   + k*2*128;
  const float* Wg   = (path ? WgP   : WgN)   + k*4*16384;
  const float* bg_  = (path ? bgP   : bgN)   + k*2*128;
  const float* Wout = (path ? WoutP : WoutN) + k*8192;
  const float* bout = (path ? boutP : boutN) + k*64;
  float* outb = path ? out_hpr : out_unb;
  int t0 = path ? 0 : 1;

  __shared__ __align__(16) float sIn[4096];   // input only
  __shared__ __align__(16) float sH0[4096];   // h0 only
  __shared__ __align__(16) float sH1[2048];   // h1 only
  __shared__ __align__(16) float sH2[1024];   // h2 only
  __shared__ int rowBN[8];
  __shared__ int rowB[8];

  int tid = threadIdx.x;
  if (tid < 8){
    int r = r0 + tid;
    if (r < rows){
      int node = node_list[off[k] + (r >> 4)];
      int b = r & 15;
      rowBN[tid] = b*N_ + node;
      rowB[tid]  = b;
    } else { rowBN[tid] = -1; rowB[tid] = 0; }
  }
  __syncthreads();

  // Stage 0: build input tile
  for (int i = 0; i < 8; ++i){
    int rb = rowBN[i], b = rowB[i];
    for (int c2 = tid; c2 < 512; c2 += 256){
      int t = (c2 >> 7) + t0, c = c2 & 127;
      float v = 0.f;
      if (rb >= 0){
        if (c < 64){
          const float* xp = x + (rb*T_ + t)*2;
          v = xp[0]*fcx_W[c] + xp[1]*fcx_W[64+c] + fcx_b[c];
        } else {
          v = temb[(b*T_ + t)*64 + (c-64)];
        }
      }
      sIn[i*512 + c2] = v;
    }
  }
  __syncthreads();

  // Stage 1: h0 = xin @ Win + bin. 2 cols x 8 rt rows per thread.
  {
    int oc = (tid & 63)*2;
    int jg = (tid >> 6)*8;
    float a0[8], a1[8];
    #pragma unroll
    for (int j=0;j<8;++j){ a0[j]=0.f; a1[j]=0.f; }
    for (int c = 0; c < 128; c += 4){
      float2 w0 = *(const float2*)(Win + (c+0)*128 + oc);
      float2 w1 = *(const float2*)(Win + (c+1)*128 + oc);
      float2 w2 = *(const float2*)(Win + (c+2)*128 + oc);
      float2 w3 = *(const float2*)(Win + (c+3)*128 + oc);
      #pragma unroll
      for (int j=0;j<8;++j){
        float4 xv = *(const float4*)&sIn[(jg+j)*128 + c];
        a0[j] += xv.x*w0.x + xv.y*w1.x + xv.z*w2.x + xv.w*w3.x;
        a1[j] += xv.x*w0.y + xv.y*w1.y + xv.z*w2.y + xv.w*w3.y;
      }
    }
    float b0v = bin[oc], b1v = bin[oc+1];
    #pragma unroll
    for (int j=0;j<8;++j){
      sH0[(jg+j)*128 + oc]   = a0[j] + b0v;
      sH0[(jg+j)*128 + oc+1] = a1[j] + b1v;
    }
  }
  __syncthreads();

  // Stage 2: block0 (d=1), fused f+g, reads sH0, writes sH1.
  {
    int o = tid & 127;
    int jg = (tid >> 7)*8;
    float af[8], ag[8];
    #pragma unroll
    for (int j=0;j<8;++j){ af[j]=0.f; ag[j]=0.f; }
    for (int c = 0; c < 128; c += 4){
      float f00=Wf[(c+0)*128+o], f01=Wf[(c+1)*128+o], f02=Wf[(c+2)*128+o], f03=Wf[(c+3)*128+o];
      float f10=Wf[16384+(c+0)*128+o], f11=Wf[16384+(c+1)*128+o], f12=Wf[16384+(c+2)*128+o], f13=Wf[16384+(c+3)*128+o];
      float g00=Wg[(c+0)*128+o], g01=Wg[(c+1)*128+o], g02=Wg[(c+2)*128+o], g03=Wg[(c+3)*128+o];
      float g10=Wg[16384+(c+0)*128+o], g11=Wg[16384+(c+1)*128+o], g12=Wg[16384+(c+2)*128+o], g13=Wg[16384+(c+3)*128+o];
      #pragma unroll
      for (int jj=0;jj<8;++jj){
        int j = jg + jj;
        int i = j >> 1, ti = j & 1;
        float4 xa = *(const float4*)&sH0[(i*4+ti*2  )*128 + c];
        float4 xb = *(const float4*)&sH0[(i*4+ti*2+1)*128 + c];
        af[jj] += xa.x*f00 + xa.y*f01 + xa.z*f02 + xa.w*f03
                + xb.x*f10 + xb.y*f11 + xb.z*f12 + xb.w*f13;
        ag[jj] += xa.x*g00 + xa.y*g01 + xa.z*g02 + xa.w*g03
                + xb.x*g10 + xb.y*g11 + xb.z*g12 + xb.w*g13;
      }
    }
    float bfv = bf_[o], bgv = bg_[o];
    #pragma unroll
    for (int jj=0;jj<8;++jj){
      int j = jg + jj;
      int i = j >> 1, ti = j & 1;
      float f = tanhf(af[jj] + bfv);
      float g = 1.f/(1.f + expf(-(ag[jj] + bgv)));
      sH1[j*128 + o] = f*g + sH0[(i*4 + ti*2 + 1)*128 + o];
    }
  }
  __syncthreads();

  // Stage 3: block1 (d=2), fused f+g, reads sH1, writes sH2.
  {
    int o = tid & 127;
    int ig = (tid >> 7)*4;
    const float* Wf1 = Wf + 2*16384;
    const float* Wg1 = Wg + 2*16384;
    float af[4], ag[4];
    #pragma unroll
    for (int i=0;i<4;++i){ af[i]=0.f; ag[i]=0.f; }
    for (int c = 0; c < 128; c += 4){
      float f00=Wf1[(c+0)*128+o], f01=Wf1[(c+1)*128+o], f02=Wf1[(c+2)*128+o], f03=Wf1[(c+3)*128+o];
      float f10=Wf1[16384+(c+0)*128+o], f11=Wf1[16384+(c+1)*128+o], f12=Wf1[16384+(c+2)*128+o], f13=Wf1[16384+(c+3)*128+o];
      float g00=Wg1[(c+0)*128+o], g01=Wg1[(c+1)*128+o], g02=Wg1[(c+2)*128+o], g03=Wg1[(c+3)*128+o];
      float g10=Wg1[16384+(c+0)*128+o], g11=Wg1[16384+(c+1)*128+o], g12=Wg1[16384+(c+2)*128+o], g13=Wg1[16384+(c+3)*128+o];
      #pragma unroll
      for (int ii=0;ii<4;++ii){
        int i = ig + ii;
        float4 xa = *(const float4*)&sH1[(i*2+0)*128 + c];
        float4 xb = *(const float4*)&sH1[(i*2+1)*128 + c];
        af[ii] += xa.x*f00 + xa.y*f01 + xa.z*f02 + xa.w*f03
                + xb.x*f10 + xb.y*f11 + xb.z*f12 + xb.w*f13;
        ag[ii] += xa.x*g00 + xa.y*g01 + xa.z*g02 + xa.w*g03
                + xb.x*g10 + xb.y*g11 + xb.z*g12 + xb.w*g13;
      }
    }
    float bfv = bf_[128+o], bgv = bg_[128+o];
    #pragma unroll
    for (int ii=0;ii<4;++ii){
      int i = ig + ii;
      float f = tanhf(af[ii] + bfv);
      float g = 1.f/(1.f + expf(-(ag[ii] + bgv)));
      sH2[i*128 + o] = f*g + sH1[(i*2+1)*128 + o];
    }
  }
  __syncthreads();

  // Stage 4: out = h2 @ Wout + bout (128 -> 64)
  {
    int o6 = tid & 63, grp = tid >> 6;
    #pragma unroll
    for (int ii=0; ii<2; ++ii){
      int i = grp*2 + ii;
      float acc = 0.f;
      for (int c = 0; c < 128; c += 4){
        float w0=Wout[(c+0)*64+o6], w1=Wout[(c+1)*64+o6],
              w2=Wout[(c+2)*64+o6], w3=Wout[(c+3)*64+o6];
        float4 xv = *(const float4*)&sH2[i*128 + c];
        acc += xv.x*w0 + xv.y*w1 + xv.z*w2 + xv.w*w3;
      }
      if (rowBN[i] >= 0) outb[rowBN[i]*64 + o6] = acc + bout[o6];
    }
  }
}

// ---------------- batchnorm ----------------
__global__ __launch_bounds__(256) void k_bnstats(const float* __restrict__ unb,
                                                 const float* __restrict__ hpr,
                                                 float* __restrict__ stats){
  int bid = blockIdx.x;
  int tensor = bid >> 6, c = bid & 63;
  const float* buf = tensor ? hpr : unb;
  float s1 = 0.f, s2 = 0.f;
  for (int r = threadIdx.x; r < NROWS; r += 256){
    float v = buf[r*64 + c];
    s1 += v; s2 += v*v;
  }
  __shared__ float r1[256], r2[256];
  r1[threadIdx.x]=s1; r2[threadIdx.x]=s2;
  __syncthreads();
  for (int s=128; s>0; s>>=1){
    if (threadIdx.x < s){ r1[threadIdx.x]+=r1[threadIdx.x+s]; r2[threadIdx.x]+=r2[threadIdx.x+s]; }
    __syncthreads();
  }
  if (threadIdx.x==0){
    float mean = r1[0]/(float)NROWS;
    float var  = r2[0]/(float)NROWS - mean*mean;
    stats[tensor*128 + c]      = mean;
    stats[tensor*128 + 64 + c] = rsqrtf(var + 1e-5f);
  }
}

__global__ __launch_bounds__(256) void k_bnapply(float* __restrict__ unb, float* __restrict__ hpr,
                                                 const float* __restrict__ stats,
                                                 const float* __restrict__ g1, const float* __restrict__ be1,
                                                 const float* __restrict__ gP, const float* __restrict__ beP){
  int idx = blockIdx.x*256 + threadIdx.x;
  if (idx >= 2*NROWS*64) return;
  int tensor = idx >= NROWS*64;
  int local = idx - tensor*NROWS*64;
  int c = local & 63;
  float* buf = tensor ? hpr : unb;
  float mean = stats[tensor*128+c], rstd = stats[tensor*128+64+c];
  float g = tensor ? gP[c] : g1[c];
  float bb = tensor ? beP[c] : be1[c];
  buf[local] = g * (buf[local]-mean) * rstd + bb;
}

// ---------------- fused adjacency build + apply ----------------
// Register double-buffered prefetch of Keys/X chunks (round-8 win, kept verbatim).
template<int AMODE, int RELU, int FINAL, int ADD>
__global__ __launch_bounds__(256) void k_attn(
    const float* __restrict__ geo,
    const float* __restrict__ Qf, const float* __restrict__ Qb,
    const float* __restrict__ M,
    const float* __restrict__ Keysf, const float* __restrict__ Keysb,
    const float* __restrict__ X,
    const float* __restrict__ X0, const float* __restrict__ Z1,
    const float* __restrict__ Wg, const float* __restrict__ bg,
    float* __restrict__ cur, float* __restrict__ Y)
{
  __shared__ float vbuf[16][65];
  __shared__ float mb[2][64][65];
  __shared__ float sbuf[16][513];
  __shared__ float red[16][17];
  __shared__ float rowm[16], rowinv[16];

  int b = blockIdx.y, n0 = blockIdx.x*16;
  int tid = threadIdx.x;
  int nl = tid >> 4, ml = tid & 15;
  int n = n0 + nl;
  float rr[16];

  if (AMODE == 0){
    for (int idx = tid; idx < 16*512; idx += 256){
      int r = idx >> 9, m = idx & 511;
      int nn = n0 + r;
      sbuf[r][m] = (nn < N_ && m < N_) ? geo[nn*N_+m] : 0.f;
    }
    __syncthreads();
  } else {
    for (int idx = tid; idx < 1024; idx += 256){
      int r = idx >> 6, kk = idx & 63;
      int nn = n0 + r;
      float q = 0.f;
      if (nn < N_) q = (AMODE == 1) ? Qf[(b*N_+nn)*64+kk] : Qb[nn*64+kk];
      vbuf[r][kk] = q;
    }
    for (int idx = tid; idx < 4096; idx += 256){
      int kk = idx >> 6, c = idx & 63;
      mb[0][kk][c] = M[b*4096 + idx];
    }
    __syncthreads();
    float v4[4] = {0.f,0.f,0.f,0.f};
    for (int kk = 0; kk < 64; ++kk){
      float q = vbuf[nl][kk];
      #pragma unroll
      for (int c = 0; c < 4; ++c) v4[c] += q * mb[0][kk][ml*4+c];
    }
    __syncthreads();
    #pragma unroll
    for (int c = 0; c < 4; ++c) vbuf[nl][ml*4+c] = v4[c];

    // scores: double-buffered key streaming
    #pragma unroll
    for (int ii=0; ii<16; ++ii){
      int idx = tid + ii*256;
      int mm = idx >> 6, kk = idx & 63;
      rr[ii] = (AMODE == 1) ? Keysf[(b*N_+mm)*64+kk] : Keysb[mm*64+kk];  // chunk 0: mm<64<N_
    }
    #pragma unroll
    for (int ii=0; ii<16; ++ii){
      int idx = tid + ii*256;
      mb[0][idx >> 6][idx & 63] = rr[ii];
    }
    __syncthreads();
    for (int ci = 0; ci < 8; ++ci){
      int m0 = ci*64;
      int cb = ci & 1, nb = (ci+1) & 1;
      if (ci < 7){
        #pragma unroll
        for (int ii=0; ii<16; ++ii){
          int idx = tid + ii*256;
          int mm = idx >> 6, kk = idx & 63;
          int m = m0 + 64 + mm;
          rr[ii] = 0.f;
          if (m < N_) rr[ii] = (AMODE == 1) ? Keysf[(b*N_+m)*64+kk] : Keysb[m*64+kk];
        }
      }
      #pragma unroll
      for (int mi = 0; mi < 4; ++mi){
        int mloc = ml + 16*mi;
        float a = 0.f;
        for (int kk = 0; kk < 64; ++kk) a += vbuf[nl][kk]*mb[cb][mloc][kk];
        sbuf[nl][m0+mloc] = a;
      }
      if (ci < 7){
        #pragma unroll
        for (int ii=0; ii<16; ++ii){
          int idx = tid + ii*256;
          mb[nb][idx >> 6][idx & 63] = rr[ii];
        }
      }
      __syncthreads();
    }
    // row softmax
    float lmax = -1e30f;
    for (int m = ml; m < N_; m += 16){
      float v = sbuf[nl][m];
      if (RELU) v = fmaxf(v, 0.f);
      lmax = fmaxf(lmax, v);
    }
    red[nl][ml] = lmax;
    __syncthreads();
    if (ml == 0){
      float mx = red[nl][0];
      for (int j=1;j<16;++j) mx = fmaxf(mx, red[nl][j]);
      rowm[nl] = mx;
    }
    __syncthreads();
    float mx = rowm[nl];
    float lsum = 0.f;
    for (int m = ml; m < N_; m += 16){
      float v = sbuf[nl][m];
      if (RELU) v = fmaxf(v, 0.f);
      lsum += expf(v - mx);
    }
    red[nl][ml] = lsum;
    __syncthreads();
    if (ml == 0){
      float s = 0.f;
      for (int j=0;j<16;++j) s += red[nl][j];
      rowinv[nl] = 1.f/s;
    }
    __syncthreads();
    float inv = rowinv[nl];
    for (int m = ml; m < 512; m += 16){
      float p = 0.f;
      if (m < N_){
        float v = sbuf[nl][m];
        if (RELU) v = fmaxf(v, 0.f);
        p = expf(v - mx)*inv;
      }
      sbuf[nl][m] = p;
    }
    __syncthreads();
  }

  // apply: Y_tile = A_tile @ X[b], double-buffered X streaming
  float acc4[4] = {0.f,0.f,0.f,0.f};
  #pragma unroll
  for (int ii=0; ii<16; ++ii){
    int idx = tid + ii*256;
    int mm = idx >> 6, kk = idx & 63;
    rr[ii] = X[(b*N_+mm)*64+kk];    // chunk 0: mm<64<N_
  }
  #pragma unroll
  for (int ii=0; ii<16; ++ii){
    int idx = tid + ii*256;
    mb[0][idx >> 6][idx & 63] = rr[ii];
  }
  __syncthreads();
  for (int ci = 0; ci < 8; ++ci){
    int m0 = ci*64;
    int cb = ci & 1, nb = (ci+1) & 1;
    if (ci < 7){
      #pragma unroll
      for (int ii=0; ii<16; ++ii){
        int idx = tid + ii*256;
        int mm = idx >> 6, kk = idx & 63;
        int m = m0 + 64 + mm;
        rr[ii] = (m < N_) ? X[(b*N_+m)*64+kk] : 0.f;
      }
    }
    for (int mm = 0; mm < 64; ++mm){
      float p = sbuf[nl][m0+mm];
      #pragma unroll
      for (int c = 0; c < 4; ++c) acc4[c] += p * mb[cb][mm][ml*4+c];
    }
    if (ci < 7){
      #pragma unroll
      for (int ii=0; ii<16; ++ii){
        int idx = tid + ii*256;
        mb[nb][idx >> 6][idx & 63] = rr[ii];
      }
    }
    __syncthreads();
  }

  if (!FINAL){
    if (n < N_){
      #pragma unroll
      for (int c = 0; c < 4; ++c) Y[(b*N_+n)*64 + ml*4+c] = acc4[c];
    }
    return;
  }

  // epilogue: cur (+)= (X0 + Z1 + Y) @ Wg + bg
  {
    int row = b*N_ + n;
    #pragma unroll
    for (int c = 0; c < 4; ++c){
      float s = 0.f;
      if (n < N_) s = acc4[c] + X0[row*64 + ml*4+c] + Z1[row*64 + ml*4+c];
      vbuf[nl][ml*4+c] = s;
    }
    for (int idx = tid; idx < 4096; idx += 256){
      int kk = idx >> 6, c = idx & 63;
      mb[0][kk][c] = Wg[idx];
    }
    __syncthreads();
    float o4[4] = {0.f,0.f,0.f,0.f};
    for (int kk = 0; kk < 64; ++kk){
      float s = vbuf[nl][kk];
      #pragma unroll
      for (int c = 0; c < 4; ++c) o4[c] += s * mb[0][kk][ml*4+c];
    }
    if (n < N_){
      #pragma unroll
      for (int c = 0; c < 4; ++c){
        float val = o4[c] + bg[ml*4+c];
        if (ADD) cur[row*64 + ml*4+c] += val;
        else     cur[row*64 + ml*4+c]  = val;
      }
    }
  }
}

// ---------------- output head: 4 rows/block, 2 barriers ----------------
__global__ __launch_bounds__(128) void k_out(const float* __restrict__ cur,
                                             const float* __restrict__ W1, const float* __restrict__ bb1,
                                             const float* __restrict__ W2, const float* __restrict__ bb2,
                                             float* __restrict__ out){
  __shared__ float ch[4][64];
  __shared__ float hid[4*1200];   // [r][t][f]
  int tid = threadIdx.x;
  int rbase = blockIdx.x*4;
  for (int idx = tid; idx < 256; idx += 128){
    int r = idx >> 6, h = idx & 63;
    ch[r][h] = cur[(rbase+r)*64 + h];
  }
  __syncthreads();
  for (int job = tid; job < 1200; job += 128){
    int t = job / 100, f = job - t*100;
    float a0 = bb1[t*100+f], a1 = a0, a2 = a0, a3 = a0;
    for (int h = 0; h < 64; ++h){
      float w = W1[(t*64+h)*100 + f];
      a0 += ch[0][h]*w; a1 += ch[1][h]*w; a2 += ch[2][h]*w; a3 += ch[3][h]*w;
    }
    hid[0*1200+job] = (a0 > 0.f) ? a0 : expm1f(a0);
    hid[1*1200+job] = (a1 > 0.f) ? a1 : expm1f(a1);
    hid[2*1200+job] = (a2 > 0.f) ? a2 : expm1f(a2);
    hid[3*1200+job] = (a3 > 0.f) ? a3 : expm1f(a3);
  }
  __syncthreads();
  if (tid < 96){
    int r = tid / 24, rem = tid % 24;
    int t = rem >> 1, o = rem & 1;
    float a = bb2[t*2+o];
    const float* hp = hid + r*1200 + t*100;
    for (int f = 0; f < 100; ++f) a += hp[f] * W2[(t*100+f)*2+o];
    out[(rbase+r)*24 + t*2+o] = a;
  }
}

// ---------------- launch ----------------
extern "C" void kernel_launch(void* const* d_in, const int* in_sizes, int n_in,
                              void* d_out, int out_size, void* d_ws, size_t ws_size,
                              hipStream_t stream)
{
  const float* x        = (const float*)d_in[0];
  const float* geo      = (const float*)d_in[2];
  const float* fcx_W    = (const float*)d_in[3];
  const float* fcx_b    = (const float*)d_in[4];
  const float* env_cb   = (const float*)d_in[5];
  const float* nodes_cb = (const float*)d_in[6];
  const float* w_v      = (const float*)d_in[7];
  const float* w_k      = (const float*)d_in[8];
  const float* w_q      = (const float*)d_in[9];
  const float* core_W   = (const float*)d_in[10];
  const float* core_b   = (const float*)d_in[11];
  const float* tN_Win   = (const float*)d_in[12];
  const float* tN_bin   = (const float*)d_in[13];
  const float* tN_Wf    = (const float*)d_in[14];
  const float* tN_bf    = (const float*)d_in[15];
  const float* tN_Wg    = (const float*)d_in[16];
  const float* tN_bg    = (const float*)d_in[17];
  const float* tN_Wout  = (const float*)d_in[18];
  const float* tN_bout  = (const float*)d_in[19];
  const float* tP_Win   = (const float*)d_in[20];
  const float* tP_bin   = (const float*)d_in[21];
  const float* tP_Wf    = (const float*)d_in[22];
  const float* tP_bf    = (const float*)d_in[23];
  const float* tP_Wg    = (const float*)d_in[24];
  const float* tP_bg    = (const float*)d_in[25];
  const float* tP_Wout  = (const float*)d_in[26];
  const float* tP_bout  = (const float*)d_in[27];
  const float* bn1_g    = (const float*)d_in[28];
  const float* bn1_b    = (const float*)d_in[29];
  const float* bnP_g    = (const float*)d_in[30];
  const float* bnP_b    = (const float*)d_in[31];
  const float* gcn1_W   = (const float*)d_in[32];
  const float* gcn1_b   = (const float*)d_in[33];
  const float* gcn2_W   = (const float*)d_in[34];
  const float* gcn2_b   = (const float*)d_in[35];
  const float* gcnp_W   = (const float*)d_in[36];
  const float* gcnp_b   = (const float*)d_in[37];
  const float* nv_p1    = (const float*)d_in[38];
  const float* nv_p2    = (const float*)d_in[39];
  const float* nv_p3    = (const float*)d_in[40];
  const float* nv_pk    = (const float*)d_in[41];
  const float* out_W1   = (const float*)d_in[42];
  const float* out_b1   = (const float*)d_in[43];
  const float* out_W2   = (const float*)d_in[44];
  const float* out_b2   = (const float*)d_in[45];
  const int*   t_pos    = (const int*)d_in[46];
  const int*   ind      = (const int*)d_in[47];

  // Workspace: 4096 B header + 2,223,616 floats = 8,898,560 B (~8.49 MiB)
  int* node_list = (int*)d_ws;
  int* off       = node_list + 512;
  float* F = (float*)((char*)d_ws + 4096);
  float* temb   = F + 0;
  float* core_f = F + 12288;
  float* tmp1   = F + 77824;
  float* stats  = F + 143360;
  float* matq   = F + 143616;
  float* unb    = F + 175616;
  float* hpr    = F + 687616;
  float* cur    = F + 1199616;
  float* zt1    = F + 1711616;

  k_matq <<<dim3(125), dim3(256), 0, stream>>>(nodes_cb, w_q, matq);
  k_route<<<dim3(1),   dim3(256), 0, stream>>>(env_cb, w_v, w_k, matq, node_list, off);
  k_temb <<<dim3(1),   dim3(192), 0, stream>>>(t_pos, temb);
  k_core <<<dim3(256), dim3(256), 0, stream>>>(temb, core_W, core_b, core_f);
  k_tcn  <<<dim3(24, 250), dim3(256), 0, stream>>>(x, fcx_W, fcx_b, temb, node_list, off,
      tN_Win, tN_bin, tN_Wf, tN_bf, tN_Wg, tN_bg, tN_Wout, tN_bout,
      tP_Win, tP_bin, tP_Wf, tP_bf, tP_Wg, tP_bg, tP_Wout, tP_bout,
      unb, hpr);
  k_bnstats<<<dim3(128), dim3(256), 0, stream>>>(unb, hpr, stats);
  k_bnapply<<<dim3(4000),dim3(256), 0, stream>>>(unb, hpr, stats, bn1_g, bn1_b, bnP_g, bnP_b);

  dim3 ag(32, 16);
  // gcn1: geo adjacency on h_prev
  k_attn<0,0,0,0><<<ag, 256, 0, stream>>>(geo, nullptr,nullptr,nullptr, nullptr,nullptr,
                                 hpr, nullptr,nullptr, nullptr,nullptr, nullptr, zt1);
  k_attn<0,0,1,0><<<ag, 256, 0, stream>>>(geo, nullptr,nullptr,nullptr, nullptr,nullptr,
                                 zt1, hpr, zt1, gcn1_W, gcn1_b, cur, nullptr);
  // gcn2: causal adjacency softmax(unb @ core[b] @ hpr^T) on unbias
  k_attn<1,0,0,0><<<ag, 256, 0, stream>>>(nullptr, unb,nullptr, core_f, hpr,nullptr,
                                 unb, nullptr,nullptr, nullptr,nullptr, nullptr, zt1);
  k_attn<1,0,1,1><<<ag, 256, 0, stream>>>(nullptr, unb,nullptr, core_f, hpr,nullptr,
                                 zt1, unb, zt1, gcn2_W, gcn2_b, cur, nullptr);
  // gcnp: adaptive adjacency softmax(relu(nv_p3 @ (nv_p2 @ (te @ nv_pk)))) on unbias
  k_tmp1<<<dim3(256), dim3(256), 0, stream>>>(ind, nv_p1, nv_pk, tmp1);
  k_attn<2,1,0,0><<<ag, 256, 0, stream>>>(nullptr, nullptr,nv_p2, tmp1, nullptr,nv_p3,
                                 unb, nullptr,nullptr, nullptr,nullptr, nullptr, zt1);
  k_attn<2,1,1,1><<<ag, 256, 0, stream>>>(nullptr, nullptr,nv_p2, tmp1, nullptr,nv_p3,
                                 zt1, unb, zt1, gcnp_W, gcnp_b, cur, nullptr);
  // head
  k_out<<<dim3(2000), dim3(128), 0, stream>>>(cur, out_W1, out_b1, out_W2, out_b2, (float*)d_out);
}

// Round 10
// 1017.163 us; speedup vs baseline: 1.8440x; 1.3220x over previous
//
#include <hip/hip_runtime.h>
#include <hip/hip_bf16.h>
#include <math.h>

#define B_ 16
#define N_ 500
#define T_ 12
#define K_ 10
#define NROWS (B_*N_)   // 8000
#define TROWS 6         // k_tcn rows per block (6 -> 33.8 KB LDS -> 4 blocks/CU)

// ---------------- threefry / gumbel (jax.random.key(42)) ----------------
__device__ __forceinline__ unsigned rotl32(unsigned v, int r){ return (v<<r)|(v>>(32-r)); }

__device__ __forceinline__ void threefry2x32(unsigned k0, unsigned k1,
                                             unsigned c0, unsigned c1,
                                             unsigned &o0, unsigned &o1){
  unsigned ks2 = k0 ^ k1 ^ 0x1BD11BDAu;
  unsigned x0 = c0 + k0, x1 = c1 + k1;
#define TF_R(r) { x0 += x1; x1 = rotl32(x1,(r)); x1 ^= x0; }
  TF_R(13) TF_R(15) TF_R(26) TF_R(6)
  x0 += k1;  x1 += ks2 + 1u;
  TF_R(17) TF_R(29) TF_R(16) TF_R(24)
  x0 += ks2; x1 += k0 + 2u;
  TF_R(13) TF_R(15) TF_R(26) TF_R(6)
  x0 += k0;  x1 += k1 + 3u;
  TF_R(17) TF_R(29) TF_R(16) TF_R(24)
  x0 += k1;  x1 += ks2 + 4u;
  TF_R(13) TF_R(15) TF_R(26) TF_R(6)
  x0 += ks2; x1 += k0 + 5u;
#undef TF_R
  o0 = x0; o1 = x1;
}

// Partitionable threefry (JAX >= 0.4.30): bits[i] = x0 ^ x1 of threefry(key,(0,i)).
// VERIFIED bit-exact vs harness (round 5 pass).
__device__ __forceinline__ float gumbel_at(unsigned idx){
  unsigned b0, b1;
  threefry2x32(0u, 42u, 0u, idx, b0, b1);
  unsigned bits = b0 ^ b1;
  float u = __uint_as_float((bits >> 9) | 0x3f800000u) - 1.0f;  // [0,1)
  u = fmaxf(u, 1.17549435e-38f);
  return -logf(-logf(u));
}

// ---------------- matq = nodes_cb @ w_q ----------------
__global__ __launch_bounds__(256) void k_matq(const float* __restrict__ nodes_cb,
                                              const float* __restrict__ w_q,
                                              float* __restrict__ matq){
  int idx = blockIdx.x*256 + threadIdx.x;
  if (idx >= N_*64) return;
  int n = idx >> 6, d = idx & 63;
  float a = 0.f;
  for (int c = 0; c < 64; ++c) a += nodes_cb[n*64+c] * w_q[c*64+d];
  matq[idx] = a;
}

// ---------------- routing ----------------
__global__ __launch_bounds__(256) void k_route(const float* __restrict__ env_cb,
                                               const float* __restrict__ w_v,
                                               const float* __restrict__ w_k,
                                               const float* __restrict__ matq,
                                               int* __restrict__ node_list,
                                               int* __restrict__ off){
  __shared__ float smk[K_*64];
  __shared__ float smv[K_*K_];
  __shared__ int sroute[N_];
  int tid = threadIdx.x;
  for (int idx = tid; idx < K_*64; idx += 256){
    int kk = idx >> 6, d = idx & 63;
    float a = 0.f;
    for (int c = 0; c < 64; ++c) a += env_cb[kk*64+c] * w_k[c*64+d];
    smk[idx] = a;
  }
  for (int idx = tid; idx < K_*K_; idx += 256){
    int kk = idx / K_, j = idx % K_;
    float a = 0.f;
    for (int c = 0; c < 64; ++c) a += env_cb[kk*64+c] * w_v[c*K_+j];
    smv[idx] = a;
  }
  __syncthreads();
  for (int n = tid; n < N_; n += 256){
    float s[K_];
    float mx = -1e30f;
    for (int j = 0; j < K_; ++j){
      float a = 0.f;
      for (int d = 0; d < 64; ++d) a += matq[n*64+d]*smk[j*64+d];
      s[j] = a * 0.125f;
      mx = fmaxf(mx, s[j]);
    }
    float sum = 0.f;
    for (int j = 0; j < K_; ++j){ s[j] = expf(s[j]-mx); sum += s[j]; }
    float inv = 1.f/sum;
    int best = 0; float bestv = -1e30f;
    for (int j2 = 0; j2 < K_; ++j2){
      float lg = 0.f;
      for (int j = 0; j < K_; ++j) lg += s[j]*inv*smv[j*K_+j2];
      float tot = lg + gumbel_at((unsigned)(n*K_+j2));
      if (tot > bestv){ bestv = tot; best = j2; }
    }
    sroute[n] = best;
  }
  __syncthreads();
  if (tid == 0){
    int cnt[K_]; for (int j=0;j<K_;++j) cnt[j]=0;
    for (int n=0;n<N_;++n) cnt[sroute[n]]++;
    int acc=0;
    for (int j=0;j<K_;++j){ off[j]=acc; acc+=cnt[j]; }
    off[K_]=acc;
    int pos[K_]; for (int j=0;j<K_;++j) pos[j]=off[j];
    for (int n=0;n<N_;++n) node_list[pos[sroute[n]]++] = n;
  }
}

// ---------------- t_emb ----------------
__global__ void k_temb(const int* __restrict__ t_pos, float* __restrict__ temb){
  int tid = threadIdx.x;
  if (tid >= B_*T_) return;
  int b = tid / T_, t = tid % T_;
  int p0 = t_pos[(b*T_+t)*2+0], p1 = t_pos[(b*T_+t)*2+1];
  float tp = (float)((p0 <= 4) ? p1 : 23 + p1);
  float c0 = -logf(10000.f)/32.f;
  for (int j = 0; j < 32; ++j){
    float a = tp * expf(c0 * (float)j);
    temb[(b*T_+t)*64 + j]      = cosf(a);
    temb[(b*T_+t)*64 + 32 + j] = sinf(a);
  }
}

// ---------------- core[b] ----------------
__global__ __launch_bounds__(256) void k_core(const float* __restrict__ temb,
                                              const float* __restrict__ core_W,
                                              const float* __restrict__ core_b,
                                              float* __restrict__ core_f){
  int idx = blockIdx.x*256 + threadIdx.x;
  if (idx >= B_*4096) return;
  int b = idx >> 12, c = idx & 4095;
  const float* te = temb + (b*T_ + 11)*64;
  float a = core_b[c];
  for (int h = 0; h < 64; ++h) a += te[h] * core_W[h*4096 + c];
  core_f[idx] = a;
}

// ---------------- tmp1[b] ----------------
__global__ __launch_bounds__(256) void k_tmp1(const int* __restrict__ ind,
                                              const float* __restrict__ nv_p1,
                                              const float* __restrict__ nv_pk,
                                              float* __restrict__ tmp1){
  int idx = blockIdx.x*256 + threadIdx.x;
  if (idx >= B_*4096) return;
  int b = idx >> 12, c = idx & 4095;
  int i0 = ind[(b*T_+1)*2+0], i1 = ind[(b*T_+1)*2+1];
  int row = (i0 <= 4) ? i1 : 23 + i1;
  const float* te = nv_p1 + row*64;
  float a = 0.f;
  for (int h = 0; h < 64; ++h) a += te[h] * nv_pk[h*4096 + c];
  tmp1[idx] = a;
}

// ---------------- fused per-expert TCN, 6 rows/block, one chunk/block ----------------
// Balanced 2-XCD locality: grid (20, 334), slot = blockIdx.x. Linear id = x + 20y
// -> XCD = (x + 4*(y&1)) % 8: each expert split over exactly 2 XCDs (even/odd y);
// every XCD carries 5 half-slots (balanced, unlike round 9's 3-vs-2 with x pad 24).
// 6 rows/block: LDS 33.8 KB -> 4 blocks/CU (was 8 rows, 45.5 KB, 3 blocks/CU).
__global__ __launch_bounds__(256) void k_tcn(
    const float* __restrict__ x,
    const float* __restrict__ fcx_W, const float* __restrict__ fcx_b,
    const float* __restrict__ temb,
    const int* __restrict__ node_list, const int* __restrict__ off,
    const float* __restrict__ WinN, const float* __restrict__ binN,
    const float* __restrict__ WfN,  const float* __restrict__ bfN,
    const float* __restrict__ WgN,  const float* __restrict__ bgN,
    const float* __restrict__ WoutN,const float* __restrict__ boutN,
    const float* __restrict__ WinP, const float* __restrict__ binP,
    const float* __restrict__ WfP,  const float* __restrict__ bfP,
    const float* __restrict__ WgP,  const float* __restrict__ bgP,
    const float* __restrict__ WoutP,const float* __restrict__ boutP,
    float* __restrict__ out_unb, float* __restrict__ out_hpr)
{
  int slot = blockIdx.x;
  int k = slot >> 1;
  int path = slot & 1;               // 0 = N (t0=1 -> unbias), 1 = P (t0=0 -> h_prev)
  int cnt = off[k+1] - off[k];
  int rows = cnt * 16;
  int r0 = blockIdx.y * TROWS;
  if (r0 >= rows) return;

  const float* Win  = (path ? WinP  : WinN)  + k*16384;
  const float* bin  = (path ? binP  : binN)  + k*128;
  const float* Wf   = (path ? WfP   : WfN)   + k*4*16384;
  const float* bf_  = (path ? bfP   : bfN)   + k*2*128;
  const float* Wg   = (path ? WgP   : WgN)   + k*4*16384;
  const float* bg_  = (path ? bgP   : bgN)   + k*2*128;
  const float* Wout = (path ? WoutP : WoutN) + k*8192;
  const float* bout = (path ? boutP : boutN) + k*64;
  float* outb = path ? out_hpr : out_unb;
  int t0 = path ? 0 : 1;

  __shared__ __align__(16) float sIn[TROWS*512];   // input only
  __shared__ __align__(16) float sH0[TROWS*512];   // h0 only  (24 rt x 128)
  __shared__ __align__(16) float sH1[TROWS*256];   // h1 only  (12 x 128)
  __shared__ __align__(16) float sH2[TROWS*128];   // h2 only  (6 x 128)
  __shared__ int rowBN[TROWS];
  __shared__ int rowB[TROWS];

  int tid = threadIdx.x;
  if (tid < TROWS){
    int r = r0 + tid;
    if (r < rows){
      int node = node_list[off[k] + (r >> 4)];
      int b = r & 15;
      rowBN[tid] = b*N_ + node;
      rowB[tid]  = b;
    } else { rowBN[tid] = -1; rowB[tid] = 0; }
  }
  __syncthreads();

  // Stage 0: build input tile
  for (int i = 0; i < TROWS; ++i){
    int rb = rowBN[i], b = rowB[i];
    for (int c2 = tid; c2 < 512; c2 += 256){
      int t = (c2 >> 7) + t0, c = c2 & 127;
      float v = 0.f;
      if (rb >= 0){
        if (c < 64){
          const float* xp = x + (rb*T_ + t)*2;
          v = xp[0]*fcx_W[c] + xp[1]*fcx_W[64+c] + fcx_b[c];
        } else {
          v = temb[(b*T_ + t)*64 + (c-64)];
        }
      }
      sIn[i*512 + c2] = v;
    }
  }
  __syncthreads();

  // Stage 1: h0 = xin @ Win + bin. 2 cols x 6 rt rows per thread (24 rt total).
  {
    int oc = (tid & 63)*2;
    int jg = (tid >> 6)*6;
    float a0[6], a1[6];
    #pragma unroll
    for (int j=0;j<6;++j){ a0[j]=0.f; a1[j]=0.f; }
    for (int c = 0; c < 128; c += 4){
      float2 w0 = *(const float2*)(Win + (c+0)*128 + oc);
      float2 w1 = *(const float2*)(Win + (c+1)*128 + oc);
      float2 w2 = *(const float2*)(Win + (c+2)*128 + oc);
      float2 w3 = *(const float2*)(Win + (c+3)*128 + oc);
      #pragma unroll
      for (int j=0;j<6;++j){
        float4 xv = *(const float4*)&sIn[(jg+j)*128 + c];
        a0[j] += xv.x*w0.x + xv.y*w1.x + xv.z*w2.x + xv.w*w3.x;
        a1[j] += xv.x*w0.y + xv.y*w1.y + xv.z*w2.y + xv.w*w3.y;
      }
    }
    float b0v = bin[oc], b1v = bin[oc+1];
    #pragma unroll
    for (int j=0;j<6;++j){
      sH0[(jg+j)*128 + oc]   = a0[j] + b0v;
      sH0[(jg+j)*128 + oc+1] = a1[j] + b1v;
    }
  }
  __syncthreads();

  // Stage 2: block0 (d=1), fused f+g, 6 j per thread (12 total), sH0 -> sH1.
  {
    int o = tid & 127;
    int jg = (tid >> 7)*6;
    float af[6], ag[6];
    #pragma unroll
    for (int j=0;j<6;++j){ af[j]=0.f; ag[j]=0.f; }
    for (int c = 0; c < 128; c += 4){
      float f00=Wf[(c+0)*128+o], f01=Wf[(c+1)*128+o], f02=Wf[(c+2)*128+o], f03=Wf[(c+3)*128+o];
      float f10=Wf[16384+(c+0)*128+o], f11=Wf[16384+(c+1)*128+o], f12=Wf[16384+(c+2)*128+o], f13=Wf[16384+(c+3)*128+o];
      float g00=Wg[(c+0)*128+o], g01=Wg[(c+1)*128+o], g02=Wg[(c+2)*128+o], g03=Wg[(c+3)*128+o];
      float g10=Wg[16384+(c+0)*128+o], g11=Wg[16384+(c+1)*128+o], g12=Wg[16384+(c+2)*128+o], g13=Wg[16384+(c+3)*128+o];
      #pragma unroll
      for (int jj=0;jj<6;++jj){
        int j = jg + jj;
        int i = j >> 1, ti = j & 1;
        float4 xa = *(const float4*)&sH0[(i*4+ti*2  )*128 + c];
        float4 xb = *(const float4*)&sH0[(i*4+ti*2+1)*128 + c];
        af[jj] += xa.x*f00 + xa.y*f01 + xa.z*f02 + xa.w*f03
                + xb.x*f10 + xb.y*f11 + xb.z*f12 + xb.w*f13;
        ag[jj] += xa.x*g00 + xa.y*g01 + xa.z*g02 + xa.w*g03
                + xb.x*g10 + xb.y*g11 + xb.z*g12 + xb.w*g13;
      }
    }
    float bfv = bf_[o], bgv = bg_[o];
    #pragma unroll
    for (int jj=0;jj<6;++jj){
      int j = jg + jj;
      int i = j >> 1, ti = j & 1;
      float f = tanhf(af[jj] + bfv);
      float g = 1.f/(1.f + expf(-(ag[jj] + bgv)));
      sH1[j*128 + o] = f*g + sH0[(i*4 + ti*2 + 1)*128 + o];
    }
  }
  __syncthreads();

  // Stage 3: block1 (d=2), fused f+g, 3 i per thread (6 total), sH1 -> sH2.
  {
    int o = tid & 127;
    int ig = (tid >> 7)*3;
    const float* Wf1 = Wf + 2*16384;
    const float* Wg1 = Wg + 2*16384;
    float af[3], ag[3];
    #pragma unroll
    for (int i=0;i<3;++i){ af[i]=0.f; ag[i]=0.f; }
    for (int c = 0; c < 128; c += 4){
      float f00=Wf1[(c+0)*128+o], f01=Wf1[(c+1)*128+o], f02=Wf1[(c+2)*128+o], f03=Wf1[(c+3)*128+o];
      float f10=Wf1[16384+(c+0)*128+o], f11=Wf1[16384+(c+1)*128+o], f12=Wf1[16384+(c+2)*128+o], f13=Wf1[16384+(c+3)*128+o];
      float g00=Wg1[(c+0)*128+o], g01=Wg1[(c+1)*128+o], g02=Wg1[(c+2)*128+o], g03=Wg1[(c+3)*128+o];
      float g10=Wg1[16384+(c+0)*128+o], g11=Wg1[16384+(c+1)*128+o], g12=Wg1[16384+(c+2)*128+o], g13=Wg1[16384+(c+3)*128+o];
      #pragma unroll
      for (int ii=0;ii<3;++ii){
        int i = ig + ii;
        float4 xa = *(const float4*)&sH1[(i*2+0)*128 + c];
        float4 xb = *(const float4*)&sH1[(i*2+1)*128 + c];
        af[ii] += xa.x*f00 + xa.y*f01 + xa.z*f02 + xa.w*f03
                + xb.x*f10 + xb.y*f11 + xb.z*f12 + xb.w*f13;
        ag[ii] += xa.x*g00 + xa.y*g01 + xa.z*g02 + xa.w*g03
                + xb.x*g10 + xb.y*g11 + xb.z*g12 + xb.w*g13;
      }
    }
    float bfv = bf_[128+o], bgv = bg_[128+o];
    #pragma unroll
    for (int ii=0;ii<3;++ii){
      int i = ig + ii;
      float f = tanhf(af[ii] + bfv);
      float g = 1.f/(1.f + expf(-(ag[ii] + bgv)));
      sH2[i*128 + o] = f*g + sH1[(i*2+1)*128 + o];
    }
  }
  __syncthreads();

  // Stage 4: out = h2 @ Wout + bout (128 -> 64)
  {
    int o6 = tid & 63, grp = tid >> 6;
    #pragma unroll
    for (int ii=0; ii<2; ++ii){
      int i = grp*2 + ii;
      if (i >= TROWS) continue;
      float acc = 0.f;
      for (int c = 0; c < 128; c += 4){
        float w0=Wout[(c+0)*64+o6], w1=Wout[(c+1)*64+o6],
              w2=Wout[(c+2)*64+o6], w3=Wout[(c+3)*64+o6];
        float4 xv = *(const float4*)&sH2[i*128 + c];
        acc += xv.x*w0 + xv.y*w1 + xv.z*w2 + xv.w*w3;
      }
      if (rowBN[i] >= 0) outb[rowBN[i]*64 + o6] = acc + bout[o6];
    }
  }
}

// ---------------- batchnorm ----------------
__global__ __launch_bounds__(256) void k_bnstats(const float* __restrict__ unb,
                                                 const float* __restrict__ hpr,
                                                 float* __restrict__ stats){
  int bid = blockIdx.x;
  int tensor = bid >> 6, c = bid & 63;
  const float* buf = tensor ? hpr : unb;
  float s1 = 0.f, s2 = 0.f;
  for (int r = threadIdx.x; r < NROWS; r += 256){
    float v = buf[r*64 + c];
    s1 += v; s2 += v*v;
  }
  __shared__ float r1[256], r2[256];
  r1[threadIdx.x]=s1; r2[threadIdx.x]=s2;
  __syncthreads();
  for (int s=128; s>0; s>>=1){
    if (threadIdx.x < s){ r1[threadIdx.x]+=r1[threadIdx.x+s]; r2[threadIdx.x]+=r2[threadIdx.x+s]; }
    __syncthreads();
  }
  if (threadIdx.x==0){
    float mean = r1[0]/(float)NROWS;
    float var  = r2[0]/(float)NROWS - mean*mean;
    stats[tensor*128 + c]      = mean;
    stats[tensor*128 + 64 + c] = rsqrtf(var + 1e-5f);
  }
}

__global__ __launch_bounds__(256) void k_bnapply(float* __restrict__ unb, float* __restrict__ hpr,
                                                 const float* __restrict__ stats,
                                                 const float* __restrict__ g1, const float* __restrict__ be1,
                                                 const float* __restrict__ gP, const float* __restrict__ beP){
  int idx = blockIdx.x*256 + threadIdx.x;
  if (idx >= 2*NROWS*64) return;
  int tensor = idx >= NROWS*64;
  int local = idx - tensor*NROWS*64;
  int c = local & 63;
  float* buf = tensor ? hpr : unb;
  float mean = stats[tensor*128+c], rstd = stats[tensor*128+64+c];
  float g = tensor ? gP[c] : g1[c];
  float bb = tensor ? beP[c] : be1[c];
  buf[local] = g * (buf[local]-mean) * rstd + bb;
}

// ---------------- fused adjacency build + apply ----------------
// Round-8-proven barrier skeleton + register double-buffered prefetch.
// This round: float4 LDS vectorization of the 4 inner loops (padded [68]/[516],
// 16B-aligned; ml/ml+8 2-way bank aliasing is free). FP accum order preserved.
template<int AMODE, int RELU, int FINAL, int ADD>
__global__ __launch_bounds__(256) void k_attn(
    const float* __restrict__ geo,
    const float* __restrict__ Qf, const float* __restrict__ Qb,
    const float* __restrict__ M,
    const float* __restrict__ Keysf, const float* __restrict__ Keysb,
    const float* __restrict__ X,
    const float* __restrict__ X0, const float* __restrict__ Z1,
    const float* __restrict__ Wg, const float* __restrict__ bg,
    float* __restrict__ cur, float* __restrict__ Y)
{
  __shared__ __align__(16) float vbuf[16][68];
  __shared__ __align__(16) float mb[2][64][68];
  __shared__ __align__(16) float sbuf[16][516];
  __shared__ float red[16][17];
  __shared__ float rowm[16], rowinv[16];

  int b = blockIdx.y, n0 = blockIdx.x*16;
  int tid = threadIdx.x;
  int nl = tid >> 4, ml = tid & 15;
  int n = n0 + nl;
  float rr[16];

  if (AMODE == 0){
    for (int idx = tid; idx < 16*512; idx += 256){
      int r = idx >> 9, m = idx & 511;
      int nn = n0 + r;
      sbuf[r][m] = (nn < N_ && m < N_) ? geo[nn*N_+m] : 0.f;
    }
    __syncthreads();
  } else {
    for (int idx = tid; idx < 1024; idx += 256){
      int r = idx >> 6, kk = idx & 63;
      int nn = n0 + r;
      float q = 0.f;
      if (nn < N_) q = (AMODE == 1) ? Qf[(b*N_+nn)*64+kk] : Qb[nn*64+kk];
      vbuf[r][kk] = q;
    }
    for (int idx = tid; idx < 4096; idx += 256){
      int kk = idx >> 6, c = idx & 63;
      mb[0][kk][c] = M[b*4096 + idx];
    }
    __syncthreads();
    // V = Q @ M  (b32 broadcast + b128)
    float4 v4 = {0.f,0.f,0.f,0.f};
    for (int kk = 0; kk < 64; ++kk){
      float q = vbuf[nl][kk];
      float4 m4 = *(const float4*)&mb[0][kk][ml*4];
      v4.x += q*m4.x; v4.y += q*m4.y; v4.z += q*m4.z; v4.w += q*m4.w;
    }
    __syncthreads();
    *(float4*)&vbuf[nl][ml*4] = v4;

    // scores: double-buffered key streaming, float4 inner
    #pragma unroll
    for (int ii=0; ii<16; ++ii){
      int idx = tid + ii*256;
      int mm = idx >> 6, kk = idx & 63;
      rr[ii] = (AMODE == 1) ? Keysf[(b*N_+mm)*64+kk] : Keysb[mm*64+kk];  // chunk 0: mm<64<N_
    }
    #pragma unroll
    for (int ii=0; ii<16; ++ii){
      int idx = tid + ii*256;
      mb[0][idx >> 6][idx & 63] = rr[ii];
    }
    __syncthreads();
    for (int ci = 0; ci < 8; ++ci){
      int m0 = ci*64;
      int cb = ci & 1, nb = (ci+1) & 1;
      if (ci < 7){
        #pragma unroll
        for (int ii=0; ii<16; ++ii){
          int idx = tid + ii*256;
          int mm = idx >> 6, kk = idx & 63;
          int m = m0 + 64 + mm;
          rr[ii] = 0.f;
          if (m < N_) rr[ii] = (AMODE == 1) ? Keysf[(b*N_+m)*64+kk] : Keysb[m*64+kk];
        }
      }
      {
        float s0=0.f, s1=0.f, s2=0.f, s3=0.f;
        for (int kk = 0; kk < 64; kk += 4){
          float4 qv  = *(const float4*)&vbuf[nl][kk];
          float4 k0v = *(const float4*)&mb[cb][ml   ][kk];
          float4 k1v = *(const float4*)&mb[cb][ml+16][kk];
          float4 k2v = *(const float4*)&mb[cb][ml+32][kk];
          float4 k3v = *(const float4*)&mb[cb][ml+48][kk];
          s0 += qv.x*k0v.x + qv.y*k0v.y + qv.z*k0v.z + qv.w*k0v.w;
          s1 += qv.x*k1v.x + qv.y*k1v.y + qv.z*k1v.z + qv.w*k1v.w;
          s2 += qv.x*k2v.x + qv.y*k2v.y + qv.z*k2v.z + qv.w*k2v.w;
          s3 += qv.x*k3v.x + qv.y*k3v.y + qv.z*k3v.z + qv.w*k3v.w;
        }
        sbuf[nl][m0+ml   ] = s0;
        sbuf[nl][m0+ml+16] = s1;
        sbuf[nl][m0+ml+32] = s2;
        sbuf[nl][m0+ml+48] = s3;
      }
      if (ci < 7){
        #pragma unroll
        for (int ii=0; ii<16; ++ii){
          int idx = tid + ii*256;
          mb[nb][idx >> 6][idx & 63] = rr[ii];
        }
      }
      __syncthreads();
    }
    // row softmax
    float lmax = -1e30f;
    for (int m = ml; m < N_; m += 16){
      float v = sbuf[nl][m];
      if (RELU) v = fmaxf(v, 0.f);
      lmax = fmaxf(lmax, v);
    }
    red[nl][ml] = lmax;
    __syncthreads();
    if (ml == 0){
      float mx = red[nl][0];
      for (int j=1;j<16;++j) mx = fmaxf(mx, red[nl][j]);
      rowm[nl] = mx;
    }
    __syncthreads();
    float mx = rowm[nl];
    float lsum = 0.f;
    for (int m = ml; m < N_; m += 16){
      float v = sbuf[nl][m];
      if (RELU) v = fmaxf(v, 0.f);
      lsum += expf(v - mx);
    }
    red[nl][ml] = lsum;
    __syncthreads();
    if (ml == 0){
      float s = 0.f;
      for (int j=0;j<16;++j) s += red[nl][j];
      rowinv[nl] = 1.f/s;
    }
    __syncthreads();
    float inv = rowinv[nl];
    for (int m = ml; m < 512; m += 16){
      float p = 0.f;
      if (m < N_){
        float v = sbuf[nl][m];
        if (RELU) v = fmaxf(v, 0.f);
        p = expf(v - mx)*inv;
      }
      sbuf[nl][m] = p;
    }
    __syncthreads();
  }

  // apply: Y_tile = A_tile @ X[b], double-buffered X streaming, float4 inner
  float4 acc4 = {0.f,0.f,0.f,0.f};
  #pragma unroll
  for (int ii=0; ii<16; ++ii){
    int idx = tid + ii*256;
    int mm = idx >> 6, kk = idx & 63;
    rr[ii] = X[(b*N_+mm)*64+kk];    // chunk 0: mm<64<N_
  }
  #pragma unroll
  for (int ii=0; ii<16; ++ii){
    int idx = tid + ii*256;
    mb[0][idx >> 6][idx & 63] = rr[ii];
  }
  __syncthreads();
  for (int ci = 0; ci < 8; ++ci){
    int m0 = ci*64;
    int cb = ci & 1, nb = (ci+1) & 1;
    if (ci < 7){
      #pragma unroll
      for (int ii=0; ii<16; ++ii){
        int idx = tid + ii*256;
        int mm = idx >> 6, kk = idx & 63;
        int m = m0 + 64 + mm;
        rr[ii] = (m < N_) ? X[(b*N_+m)*64+kk] : 0.f;
      }
    }
    for (int mm = 0; mm < 64; mm += 4){
      float4 pv  = *(const float4*)&sbuf[nl][m0+mm];
      float4 x0v = *(const float4*)&mb[cb][mm+0][ml*4];
      float4 x1v = *(const float4*)&mb[cb][mm+1][ml*4];
      float4 x2v = *(const float4*)&mb[cb][mm+2][ml*4];
      float4 x3v = *(const float4*)&mb[cb][mm+3][ml*4];
      acc4.x += pv.x*x0v.x + pv.y*x1v.x + pv.z*x2v.x + pv.w*x3v.x;
      acc4.y += pv.x*x0v.y + pv.y*x1v.y + pv.z*x2v.y + pv.w*x3v.y;
      acc4.z += pv.x*x0v.z + pv.y*x1v.z + pv.z*x2v.z + pv.w*x3v.z;
      acc4.w += pv.x*x0v.w + pv.y*x1v.w + pv.z*x2v.w + pv.w*x3v.w;
    }
    if (ci < 7){
      #pragma unroll
      for (int ii=0; ii<16; ++ii){
        int idx = tid + ii*256;
        mb[nb][idx >> 6][idx & 63] = rr[ii];
      }
    }
    __syncthreads();
  }

  if (!FINAL){
    if (n < N_) *(float4*)&Y[(b*N_+n)*64 + ml*4] = acc4;
    return;
  }

  // epilogue: cur (+)= (X0 + Z1 + Y) @ Wg + bg
  {
    int row = b*N_ + n;
    float4 sv = {0.f,0.f,0.f,0.f};
    if (n < N_){
      float4 x0v = *(const float4*)&X0[row*64 + ml*4];
      float4 z1v = *(const float4*)&Z1[row*64 + ml*4];
      sv.x = acc4.x + x0v.x + z1v.x;
      sv.y = acc4.y + x0v.y + z1v.y;
      sv.z = acc4.z + x0v.z + z1v.z;
      sv.w = acc4.w + x0v.w + z1v.w;
    }
    *(float4*)&vbuf[nl][ml*4] = sv;
    for (int idx = tid; idx < 4096; idx += 256){
      int kk = idx >> 6, c = idx & 63;
      mb[0][kk][c] = Wg[idx];
    }
    __syncthreads();
    float4 o4 = {0.f,0.f,0.f,0.f};
    for (int kk = 0; kk < 64; ++kk){
      float s = vbuf[nl][kk];
      float4 w4 = *(const float4*)&mb[0][kk][ml*4];
      o4.x += s*w4.x; o4.y += s*w4.y; o4.z += s*w4.z; o4.w += s*w4.w;
    }
    if (n < N_){
      float4 bv = *(const float4*)&bg[ml*4];
      float4 val;
      val.x = o4.x + bv.x; val.y = o4.y + bv.y;
      val.z = o4.z + bv.z; val.w = o4.w + bv.w;
      if (ADD){
        float4 old = *(const float4*)&cur[row*64 + ml*4];
        val.x += old.x; val.y += old.y; val.z += old.z; val.w += old.w;
      }
      *(float4*)&cur[row*64 + ml*4] = val;
    }
  }
}

// ---------------- output head: 4 rows/block, 2 barriers ----------------
__global__ __launch_bounds__(128) void k_out(const float* __restrict__ cur,
                                             const float* __restrict__ W1, const float* __restrict__ bb1,
                                             const float* __restrict__ W2, const float* __restrict__ bb2,
                                             float* __restrict__ out){
  __shared__ float ch[4][64];
  __shared__ float hid[4*1200];   // [r][t][f]
  int tid = threadIdx.x;
  int rbase = blockIdx.x*4;
  for (int idx = tid; idx < 256; idx += 128){
    int r = idx >> 6, h = idx & 63;
    ch[r][h] = cur[(rbase+r)*64 + h];
  }
  __syncthreads();
  for (int job = tid; job < 1200; job += 128){
    int t = job / 100, f = job - t*100;
    float a0 = bb1[t*100+f], a1 = a0, a2 = a0, a3 = a0;
    for (int h = 0; h < 64; ++h){
      float w = W1[(t*64+h)*100 + f];
      a0 += ch[0][h]*w; a1 += ch[1][h]*w; a2 += ch[2][h]*w; a3 += ch[3][h]*w;
    }
    hid[0*1200+job] = (a0 > 0.f) ? a0 : expm1f(a0);
    hid[1*1200+job] = (a1 > 0.f) ? a1 : expm1f(a1);
    hid[2*1200+job] = (a2 > 0.f) ? a2 : expm1f(a2);
    hid[3*1200+job] = (a3 > 0.f) ? a3 : expm1f(a3);
  }
  __syncthreads();
  if (tid < 96){
    int r = tid / 24, rem = tid % 24;
    int t = rem >> 1, o = rem & 1;
    float a = bb2[t*2+o];
    const float* hp = hid + r*1200 + t*100;
    for (int f = 0; f < 100; ++f) a += hp[f] * W2[(t*100+f)*2+o];
    out[(rbase+r)*24 + t*2+o] = a;
  }
}

// ---------------- launch ----------------
extern "C" void kernel_launch(void* const* d_in, const int* in_sizes, int n_in,
                              void* d_out, int out_size, void* d_ws, size_t ws_size,
                              hipStream_t stream)
{
  const float* x        = (const float*)d_in[0];
  const float* geo      = (const float*)d_in[2];
  const float* fcx_W    = (const float*)d_in[3];
  const float* fcx_b    = (const float*)d_in[4];
  const float* env_cb   = (const float*)d_in[5];
  const float* nodes_cb = (const float*)d_in[6];
  const float* w_v      = (const float*)d_in[7];
  const float* w_k      = (const float*)d_in[8];
  const float* w_q      = (const float*)d_in[9];
  const float* core_W   = (const float*)d_in[10];
  const float* core_b   = (const float*)d_in[11];
  const float* tN_Win   = (const float*)d_in[12];
  const float* tN_bin   = (const float*)d_in[13];
  const float* tN_Wf    = (const float*)d_in[14];
  const float* tN_bf    = (const float*)d_in[15];
  const float* tN_Wg    = (const float*)d_in[16];
  const float* tN_bg    = (const float*)d_in[17];
  const float* tN_Wout  = (const float*)d_in[18];
  const float* tN_bout  = (const float*)d_in[19];
  const float* tP_Win   = (const float*)d_in[20];
  const float* tP_bin   = (const float*)d_in[21];
  const float* tP_Wf    = (const float*)d_in[22];
  const float* tP_bf    = (const float*)d_in[23];
  const float* tP_Wg    = (const float*)d_in[24];
  const float* tP_bg    = (const float*)d_in[25];
  const float* tP_Wout  = (const float*)d_in[26];
  const float* tP_bout  = (const float*)d_in[27];
  const float* bn1_g    = (const float*)d_in[28];
  const float* bn1_b    = (const float*)d_in[29];
  const float* bnP_g    = (const float*)d_in[30];
  const float* bnP_b    = (const float*)d_in[31];
  const float* gcn1_W   = (const float*)d_in[32];
  const float* gcn1_b   = (const float*)d_in[33];
  const float* gcn2_W   = (const float*)d_in[34];
  const float* gcn2_b   = (const float*)d_in[35];
  const float* gcnp_W   = (const float*)d_in[36];
  const float* gcnp_b   = (const float*)d_in[37];
  const float* nv_p1    = (const float*)d_in[38];
  const float* nv_p2    = (const float*)d_in[39];
  const float* nv_p3    = (const float*)d_in[40];
  const float* nv_pk    = (const float*)d_in[41];
  const float* out_W1   = (const float*)d_in[42];
  const float* out_b1   = (const float*)d_in[43];
  const float* out_W2   = (const float*)d_in[44];
  const float* out_b2   = (const float*)d_in[45];
  const int*   t_pos    = (const int*)d_in[46];
  const int*   ind      = (const int*)d_in[47];

  // Workspace: 4096 B header + 2,223,616 floats = 8,898,560 B (~8.49 MiB)
  int* node_list = (int*)d_ws;
  int* off       = node_list + 512;
  float* F = (float*)((char*)d_ws + 4096);
  float* temb   = F + 0;
  float* core_f = F + 12288;
  float* tmp1   = F + 77824;
  float* stats  = F + 143360;
  float* matq   = F + 143616;
  float* unb    = F + 175616;
  float* hpr    = F + 687616;
  float* cur    = F + 1199616;
  float* zt1    = F + 1711616;

  k_matq <<<dim3(125), dim3(256), 0, stream>>>(nodes_cb, w_q, matq);
  k_route<<<dim3(1),   dim3(256), 0, stream>>>(env_cb, w_v, w_k, matq, node_list, off);
  k_temb <<<dim3(1),   dim3(192), 0, stream>>>(t_pos, temb);
  k_core <<<dim3(256), dim3(256), 0, stream>>>(temb, core_W, core_b, core_f);
  k_tcn  <<<dim3(20, 334), dim3(256), 0, stream>>>(x, fcx_W, fcx_b, temb, node_list, off,
      tN_Win, tN_bin, tN_Wf, tN_bf, tN_Wg, tN_bg, tN_Wout, tN_bout,
      tP_Win, tP_bin, tP_Wf, tP_bf, tP_Wg, tP_bg, tP_Wout, tP_bout,
      unb, hpr);
  k_bnstats<<<dim3(128), dim3(256), 0, stream>>>(unb, hpr, stats);
  k_bnapply<<<dim3(4000),dim3(256), 0, stream>>>(unb, hpr, stats, bn1_g, bn1_b, bnP_g, bnP_b);

  dim3 ag(32, 16);
  // gcn1: geo adjacency on h_prev
  k_attn<0,0,0,0><<<ag, 256, 0, stream>>>(geo, nullptr,nullptr,nullptr, nullptr,nullptr,
                                 hpr, nullptr,nullptr, nullptr,nullptr, nullptr, zt1);
  k_attn<0,0,1,0><<<ag, 256, 0, stream>>>(geo, nullptr,nullptr,nullptr, nullptr,nullptr,
                                 zt1, hpr, zt1, gcn1_W, gcn1_b, cur, nullptr);
  // gcn2: causal adjacency softmax(unb @ core[b] @ hpr^T) on unbias
  k_attn<1,0,0,0><<<ag, 256, 0, stream>>>(nullptr, unb,nullptr, core_f, hpr,nullptr,
                                 unb, nullptr,nullptr, nullptr,nullptr, nullptr, zt1);
  k_attn<1,0,1,1><<<ag, 256, 0, stream>>>(nullptr, unb,nullptr, core_f, hpr,nullptr,
                                 zt1, unb, zt1, gcn2_W, gcn2_b, cur, nullptr);
  // gcnp: adaptive adjacency softmax(relu(nv_p3 @ (nv_p2 @ (te @ nv_pk)))) on unbias
  k_tmp1<<<dim3(256), dim3(256), 0, stream>>>(ind, nv_p1, nv_pk, tmp1);
  k_attn<2,1,0,0><<<ag, 256, 0, stream>>>(nullptr, nullptr,nv_p2, tmp1, nullptr,nv_p3,
                                 unb, nullptr,nullptr, nullptr,nullptr, nullptr, zt1);
  k_attn<2,1,1,1><<<ag, 256, 0, stream>>>(nullptr, nullptr,nv_p2, tmp1, nullptr,nv_p3,
                                 zt1, unb, zt1, gcnp_W, gcnp_b, cur, nullptr);
  // head
  k_out<<<dim3(2000), dim3(128), 0, stream>>>(cur, out_W1, out_b1, out_W2, out_b2, (float*)d_out);
}

// Round 11
// 969.572 us; speedup vs baseline: 1.9346x; 1.0491x over previous
//
#include <hip/hip_runtime.h>
#include <hip/hip_bf16.h>
#include <math.h>

#define B_ 16
#define N_ 500
#define T_ 12
#define K_ 10
#define NROWS (B_*N_)   // 8000
#define TROWS 6         // k_tcn rows per block

// ---------------- threefry / gumbel (jax.random.key(42)) ----------------
__device__ __forceinline__ unsigned rotl32(unsigned v, int r){ return (v<<r)|(v>>(32-r)); }

__device__ __forceinline__ void threefry2x32(unsigned k0, unsigned k1,
                                             unsigned c0, unsigned c1,
                                             unsigned &o0, unsigned &o1){
  unsigned ks2 = k0 ^ k1 ^ 0x1BD11BDAu;
  unsigned x0 = c0 + k0, x1 = c1 + k1;
#define TF_R(r) { x0 += x1; x1 = rotl32(x1,(r)); x1 ^= x0; }
  TF_R(13) TF_R(15) TF_R(26) TF_R(6)
  x0 += k1;  x1 += ks2 + 1u;
  TF_R(17) TF_R(29) TF_R(16) TF_R(24)
  x0 += ks2; x1 += k0 + 2u;
  TF_R(13) TF_R(15) TF_R(26) TF_R(6)
  x0 += k0;  x1 += k1 + 3u;
  TF_R(17) TF_R(29) TF_R(16) TF_R(24)
  x0 += k1;  x1 += ks2 + 4u;
  TF_R(13) TF_R(15) TF_R(26) TF_R(6)
  x0 += ks2; x1 += k0 + 5u;
#undef TF_R
  o0 = x0; o1 = x1;
}

// Partitionable threefry (JAX >= 0.4.30): bits[i] = x0 ^ x1 of threefry(key,(0,i)).
// VERIFIED bit-exact vs harness (round 5 pass).
__device__ __forceinline__ float gumbel_at(unsigned idx){
  unsigned b0, b1;
  threefry2x32(0u, 42u, 0u, idx, b0, b1);
  unsigned bits = b0 ^ b1;
  float u = __uint_as_float((bits >> 9) | 0x3f800000u) - 1.0f;  // [0,1)
  u = fmaxf(u, 1.17549435e-38f);
  return -logf(-logf(u));
}

// ---------------- matq = nodes_cb @ w_q ----------------
__global__ __launch_bounds__(256) void k_matq(const float* __restrict__ nodes_cb,
                                              const float* __restrict__ w_q,
                                              float* __restrict__ matq){
  int idx = blockIdx.x*256 + threadIdx.x;
  if (idx >= N_*64) return;
  int n = idx >> 6, d = idx & 63;
  float a = 0.f;
  for (int c = 0; c < 64; ++c) a += nodes_cb[n*64+c] * w_q[c*64+d];
  matq[idx] = a;
}

// ---------------- routing ----------------
__global__ __launch_bounds__(256) void k_route(const float* __restrict__ env_cb,
                                               const float* __restrict__ w_v,
                                               const float* __restrict__ w_k,
                                               const float* __restrict__ matq,
                                               int* __restrict__ node_list,
                                               int* __restrict__ off){
  __shared__ float smk[K_*64];
  __shared__ float smv[K_*K_];
  __shared__ int sroute[N_];
  int tid = threadIdx.x;
  for (int idx = tid; idx < K_*64; idx += 256){
    int kk = idx >> 6, d = idx & 63;
    float a = 0.f;
    for (int c = 0; c < 64; ++c) a += env_cb[kk*64+c] * w_k[c*64+d];
    smk[idx] = a;
  }
  for (int idx = tid; idx < K_*K_; idx += 256){
    int kk = idx / K_, j = idx % K_;
    float a = 0.f;
    for (int c = 0; c < 64; ++c) a += env_cb[kk*64+c] * w_v[c*K_+j];
    smv[idx] = a;
  }
  __syncthreads();
  for (int n = tid; n < N_; n += 256){
    float s[K_];
    float mx = -1e30f;
    for (int j = 0; j < K_; ++j){
      float a = 0.f;
      for (int d = 0; d < 64; ++d) a += matq[n*64+d]*smk[j*64+d];
      s[j] = a * 0.125f;
      mx = fmaxf(mx, s[j]);
    }
    float sum = 0.f;
    for (int j = 0; j < K_; ++j){ s[j] = expf(s[j]-mx); sum += s[j]; }
    float inv = 1.f/sum;
    int best = 0; float bestv = -1e30f;
    for (int j2 = 0; j2 < K_; ++j2){
      float lg = 0.f;
      for (int j = 0; j < K_; ++j) lg += s[j]*inv*smv[j*K_+j2];
      float tot = lg + gumbel_at((unsigned)(n*K_+j2));
      if (tot > bestv){ bestv = tot; best = j2; }
    }
    sroute[n] = best;
  }
  __syncthreads();
  if (tid == 0){
    int cnt[K_]; for (int j=0;j<K_;++j) cnt[j]=0;
    for (int n=0;n<N_;++n) cnt[sroute[n]]++;
    int acc=0;
    for (int j=0;j<K_;++j){ off[j]=acc; acc+=cnt[j]; }
    off[K_]=acc;
    int pos[K_]; for (int j=0;j<K_;++j) pos[j]=off[j];
    for (int n=0;n<N_;++n) node_list[pos[sroute[n]]++] = n;
  }
}

// ---------------- t_emb ----------------
__global__ void k_temb(const int* __restrict__ t_pos, float* __restrict__ temb){
  int tid = threadIdx.x;
  if (tid >= B_*T_) return;
  int b = tid / T_, t = tid % T_;
  int p0 = t_pos[(b*T_+t)*2+0], p1 = t_pos[(b*T_+t)*2+1];
  float tp = (float)((p0 <= 4) ? p1 : 23 + p1);
  float c0 = -logf(10000.f)/32.f;
  for (int j = 0; j < 32; ++j){
    float a = tp * expf(c0 * (float)j);
    temb[(b*T_+t)*64 + j]      = cosf(a);
    temb[(b*T_+t)*64 + 32 + j] = sinf(a);
  }
}

// ---------------- core[b] ----------------
__global__ __launch_bounds__(256) void k_core(const float* __restrict__ temb,
                                              const float* __restrict__ core_W,
                                              const float* __restrict__ core_b,
                                              float* __restrict__ core_f){
  int idx = blockIdx.x*256 + threadIdx.x;
  if (idx >= B_*4096) return;
  int b = idx >> 12, c = idx & 4095;
  const float* te = temb + (b*T_ + 11)*64;
  float a = core_b[c];
  for (int h = 0; h < 64; ++h) a += te[h] * core_W[h*4096 + c];
  core_f[idx] = a;
}

// ---------------- tmp1[b] ----------------
__global__ __launch_bounds__(256) void k_tmp1(const int* __restrict__ ind,
                                              const float* __restrict__ nv_p1,
                                              const float* __restrict__ nv_pk,
                                              float* __restrict__ tmp1){
  int idx = blockIdx.x*256 + threadIdx.x;
  if (idx >= B_*4096) return;
  int b = idx >> 12, c = idx & 4095;
  int i0 = ind[(b*T_+1)*2+0], i1 = ind[(b*T_+1)*2+1];
  int row = (i0 <= 4) ? i1 : 23 + i1;
  const float* te = nv_p1 + row*64;
  float a = 0.f;
  for (int h = 0; h < 64; ++h) a += te[h] * nv_pk[h*4096 + c];
  tmp1[idx] = a;
}

// ---------------- fused per-expert TCN (round-10 proven, byte-identical) ----------------
__global__ __launch_bounds__(256) void k_tcn(
    const float* __restrict__ x,
    const float* __restrict__ fcx_W, const float* __restrict__ fcx_b,
    const float* __restrict__ temb,
    const int* __restrict__ node_list, const int* __restrict__ off,
    const float* __restrict__ WinN, const float* __restrict__ binN,
    const float* __restrict__ WfN,  const float* __restrict__ bfN,
    const float* __restrict__ WgN,  const float* __restrict__ bgN,
    const float* __restrict__ WoutN,const float* __restrict__ boutN,
    const float* __restrict__ WinP, const float* __restrict__ binP,
    const float* __restrict__ WfP,  const float* __restrict__ bfP,
    const float* __restrict__ WgP,  const float* __restrict__ bgP,
    const float* __restrict__ WoutP,const float* __restrict__ boutP,
    float* __restrict__ out_unb, float* __restrict__ out_hpr)
{
  int slot = blockIdx.x;
  int k = slot >> 1;
  int path = slot & 1;
  int cnt = off[k+1] - off[k];
  int rows = cnt * 16;
  int r0 = blockIdx.y * TROWS;
  if (r0 >= rows) return;

  const float* Win  = (path ? WinP  : WinN)  + k*16384;
  const float* bin  = (path ? binP  : binN)  + k*128;
  const float* Wf   = (path ? WfP   : WfN)   + k*4*16384;
  const float* bf_  = (path ? bfP   : bfN)   + k*2*128;
  const float* Wg   = (path ? WgP   : WgN)   + k*4*16384;
  const float* bg_  = (path ? bgP   : bgN)   + k*2*128;
  const float* Wout = (path ? WoutP : WoutN) + k*8192;
  const float* bout = (path ? boutP : boutN) + k*64;
  float* outb = path ? out_hpr : out_unb;
  int t0 = path ? 0 : 1;

  __shared__ __align__(16) float sIn[TROWS*512];
  __shared__ __align__(16) float sH0[TROWS*512];
  __shared__ __align__(16) float sH1[TROWS*256];
  __shared__ __align__(16) float sH2[TROWS*128];
  __shared__ int rowBN[TROWS];
  __shared__ int rowB[TROWS];

  int tid = threadIdx.x;
  if (tid < TROWS){
    int r = r0 + tid;
    if (r < rows){
      int node = node_list[off[k] + (r >> 4)];
      int b = r & 15;
      rowBN[tid] = b*N_ + node;
      rowB[tid]  = b;
    } else { rowBN[tid] = -1; rowB[tid] = 0; }
  }
  __syncthreads();

  for (int i = 0; i < TROWS; ++i){
    int rb = rowBN[i], b = rowB[i];
    for (int c2 = tid; c2 < 512; c2 += 256){
      int t = (c2 >> 7) + t0, c = c2 & 127;
      float v = 0.f;
      if (rb >= 0){
        if (c < 64){
          const float* xp = x + (rb*T_ + t)*2;
          v = xp[0]*fcx_W[c] + xp[1]*fcx_W[64+c] + fcx_b[c];
        } else {
          v = temb[(b*T_ + t)*64 + (c-64)];
        }
      }
      sIn[i*512 + c2] = v;
    }
  }
  __syncthreads();

  {
    int oc = (tid & 63)*2;
    int jg = (tid >> 6)*6;
    float a0[6], a1[6];
    #pragma unroll
    for (int j=0;j<6;++j){ a0[j]=0.f; a1[j]=0.f; }
    for (int c = 0; c < 128; c += 4){
      float2 w0 = *(const float2*)(Win + (c+0)*128 + oc);
      float2 w1 = *(const float2*)(Win + (c+1)*128 + oc);
      float2 w2 = *(const float2*)(Win + (c+2)*128 + oc);
      float2 w3 = *(const float2*)(Win + (c+3)*128 + oc);
      #pragma unroll
      for (int j=0;j<6;++j){
        float4 xv = *(const float4*)&sIn[(jg+j)*128 + c];
        a0[j] += xv.x*w0.x + xv.y*w1.x + xv.z*w2.x + xv.w*w3.x;
        a1[j] += xv.x*w0.y + xv.y*w1.y + xv.z*w2.y + xv.w*w3.y;
      }
    }
    float b0v = bin[oc], b1v = bin[oc+1];
    #pragma unroll
    for (int j=0;j<6;++j){
      sH0[(jg+j)*128 + oc]   = a0[j] + b0v;
      sH0[(jg+j)*128 + oc+1] = a1[j] + b1v;
    }
  }
  __syncthreads();

  {
    int o = tid & 127;
    int jg = (tid >> 7)*6;
    float af[6], ag[6];
    #pragma unroll
    for (int j=0;j<6;++j){ af[j]=0.f; ag[j]=0.f; }
    for (int c = 0; c < 128; c += 4){
      float f00=Wf[(c+0)*128+o], f01=Wf[(c+1)*128+o], f02=Wf[(c+2)*128+o], f03=Wf[(c+3)*128+o];
      float f10=Wf[16384+(c+0)*128+o], f11=Wf[16384+(c+1)*128+o], f12=Wf[16384+(c+2)*128+o], f13=Wf[16384+(c+3)*128+o];
      float g00=Wg[(c+0)*128+o], g01=Wg[(c+1)*128+o], g02=Wg[(c+2)*128+o], g03=Wg[(c+3)*128+o];
      float g10=Wg[16384+(c+0)*128+o], g11=Wg[16384+(c+1)*128+o], g12=Wg[16384+(c+2)*128+o], g13=Wg[16384+(c+3)*128+o];
      #pragma unroll
      for (int jj=0;jj<6;++jj){
        int j = jg + jj;
        int i = j >> 1, ti = j & 1;
        float4 xa = *(const float4*)&sH0[(i*4+ti*2  )*128 + c];
        float4 xb = *(const float4*)&sH0[(i*4+ti*2+1)*128 + c];
        af[jj] += xa.x*f00 + xa.y*f01 + xa.z*f02 + xa.w*f03
                + xb.x*f10 + xb.y*f11 + xb.z*f12 + xb.w*f13;
        ag[jj] += xa.x*g00 + xa.y*g01 + xa.z*g02 + xa.w*g03
                + xb.x*g10 + xb.y*g11 + xb.z*g12 + xb.w*g13;
      }
    }
    float bfv = bf_[o], bgv = bg_[o];
    #pragma unroll
    for (int jj=0;jj<6;++jj){
      int j = jg + jj;
      int i = j >> 1, ti = j & 1;
      float f = tanhf(af[jj] + bfv);
      float g = 1.f/(1.f + expf(-(ag[jj] + bgv)));
      sH1[j*128 + o] = f*g + sH0[(i*4 + ti*2 + 1)*128 + o];
    }
  }
  __syncthreads();

  {
    int o = tid & 127;
    int ig = (tid >> 7)*3;
    const float* Wf1 = Wf + 2*16384;
    const float* Wg1 = Wg + 2*16384;
    float af[3], ag[3];
    #pragma unroll
    for (int i=0;i<3;++i){ af[i]=0.f; ag[i]=0.f; }
    for (int c = 0; c < 128; c += 4){
      float f00=Wf1[(c+0)*128+o], f01=Wf1[(c+1)*128+o], f02=Wf1[(c+2)*128+o], f03=Wf1[(c+3)*128+o];
      float f10=Wf1[16384+(c+0)*128+o], f11=Wf1[16384+(c+1)*128+o], f12=Wf1[16384+(c+2)*128+o], f13=Wf1[16384+(c+3)*128+o];
      float g00=Wg1[(c+0)*128+o], g01=Wg1[(c+1)*128+o], g02=Wg1[(c+2)*128+o], g03=Wg1[(c+3)*128+o];
      float g10=Wg1[16384+(c+0)*128+o], g11=Wg1[16384+(c+1)*128+o], g12=Wg1[16384+(c+2)*128+o], g13=Wg1[16384+(c+3)*128+o];
      #pragma unroll
      for (int ii=0;ii<3;++ii){
        int i = ig + ii;
        float4 xa = *(const float4*)&sH1[(i*2+0)*128 + c];
        float4 xb = *(const float4*)&sH1[(i*2+1)*128 + c];
        af[ii] += xa.x*f00 + xa.y*f01 + xa.z*f02 + xa.w*f03
                + xb.x*f10 + xb.y*f11 + xb.z*f12 + xb.w*f13;
        ag[ii] += xa.x*g00 + xa.y*g01 + xa.z*g02 + xa.w*g03
                + xb.x*g10 + xb.y*g11 + xb.z*g12 + xb.w*g13;
      }
    }
    float bfv = bf_[128+o], bgv = bg_[128+o];
    #pragma unroll
    for (int ii=0;ii<3;++ii){
      int i = ig + ii;
      float f = tanhf(af[ii] + bfv);
      float g = 1.f/(1.f + expf(-(ag[ii] + bgv)));
      sH2[i*128 + o] = f*g + sH1[(i*2+1)*128 + o];
    }
  }
  __syncthreads();

  {
    int o6 = tid & 63, grp = tid >> 6;
    #pragma unroll
    for (int ii=0; ii<2; ++ii){
      int i = grp*2 + ii;
      if (i >= TROWS) continue;
      float acc = 0.f;
      for (int c = 0; c < 128; c += 4){
        float w0=Wout[(c+0)*64+o6], w1=Wout[(c+1)*64+o6],
              w2=Wout[(c+2)*64+o6], w3=Wout[(c+3)*64+o6];
        float4 xv = *(const float4*)&sH2[i*128 + c];
        acc += xv.x*w0 + xv.y*w1 + xv.z*w2 + xv.w*w3;
      }
      if (rowBN[i] >= 0) outb[rowBN[i]*64 + o6] = acc + bout[o6];
    }
  }
}

// ---------------- batchnorm ----------------
__global__ __launch_bounds__(256) void k_bnstats(const float* __restrict__ unb,
                                                 const float* __restrict__ hpr,
                                                 float* __restrict__ stats){
  int bid = blockIdx.x;
  int tensor = bid >> 6, c = bid & 63;
  const float* buf = tensor ? hpr : unb;
  float s1 = 0.f, s2 = 0.f;
  for (int r = threadIdx.x; r < NROWS; r += 256){
    float v = buf[r*64 + c];
    s1 += v; s2 += v*v;
  }
  __shared__ float r1[256], r2[256];
  r1[threadIdx.x]=s1; r2[threadIdx.x]=s2;
  __syncthreads();
  for (int s=128; s>0; s>>=1){
    if (threadIdx.x < s){ r1[threadIdx.x]+=r1[threadIdx.x+s]; r2[threadIdx.x]+=r2[threadIdx.x+s]; }
    __syncthreads();
  }
  if (threadIdx.x==0){
    float mean = r1[0]/(float)NROWS;
    float var  = r2[0]/(float)NROWS - mean*mean;
    stats[tensor*128 + c]      = mean;
    stats[tensor*128 + 64 + c] = rsqrtf(var + 1e-5f);
  }
}

__global__ __launch_bounds__(256) void k_bnapply(float* __restrict__ unb, float* __restrict__ hpr,
                                                 const float* __restrict__ stats,
                                                 const float* __restrict__ g1, const float* __restrict__ be1,
                                                 const float* __restrict__ gP, const float* __restrict__ beP){
  int idx = blockIdx.x*256 + threadIdx.x;
  if (idx >= 2*NROWS*64) return;
  int tensor = idx >= NROWS*64;
  int local = idx - tensor*NROWS*64;
  int c = local & 63;
  float* buf = tensor ? hpr : unb;
  float mean = stats[tensor*128+c], rstd = stats[tensor*128+64+c];
  float g = tensor ? gP[c] : g1[c];
  float bb = tensor ? beP[c] : be1[c];
  buf[local] = g * (buf[local]-mean) * rstd + bb;
}

// ---------------- flash-style fused adjacency build + apply ----------------
// 8 rows/block, 32 lanes/row (grid 64 x 16 = 1024 blocks). Online softmax:
// single 8-chunk pass streams Keys+X together; row max/sum via __shfl_xor
// (row lanes contiguous in-wave). No sbuf -> LDS 36.3 KB -> 4 blocks/CU.
// Register prefetch of next chunk; 3 barriers/chunk.
template<int AMODE, int RELU, int FINAL, int ADD>
__global__ __launch_bounds__(256) void k_attn(
    const float* __restrict__ geo,
    const float* __restrict__ Qf, const float* __restrict__ Qb,
    const float* __restrict__ M,
    const float* __restrict__ Keysf, const float* __restrict__ Keysb,
    const float* __restrict__ X,
    const float* __restrict__ X0, const float* __restrict__ Z1,
    const float* __restrict__ Wg, const float* __restrict__ bg,
    float* __restrict__ cur, float* __restrict__ Y)
{
  __shared__ __align__(16) float kbuf[64][65];   // Keys chunk / M / Wg
  __shared__ __align__(16) float xbuf[64][64];   // X chunk
  __shared__ __align__(16) float vbuf[8][64];    // Q@M rows (broadcast reads)
  __shared__ __align__(16) float pbuf[8][64];    // probs (AMODE!=0) / A-chunk (AMODE==0)

  int b = blockIdx.y, n0 = blockIdx.x*8;
  int tid = threadIdx.x;
  int nl = tid >> 5, ml = tid & 31;
  int n = n0 + nl;
  float rrK[16], rrX[16], rrA[2];

  if (AMODE != 0){
    // stage Q tile (temp in pbuf) and M (kbuf)
    for (int idx = tid; idx < 512; idx += 256){
      int r = idx >> 6, kk = idx & 63;
      int nn = n0 + r;
      float q = 0.f;
      if (nn < N_) q = (AMODE == 1) ? Qf[(b*N_+nn)*64+kk] : Qb[nn*64+kk];
      pbuf[r][kk] = q;
    }
    for (int idx = tid; idx < 4096; idx += 256)
      kbuf[idx>>6][idx&63] = M[b*4096 + idx];
    __syncthreads();
    // vbuf row = Q row @ M (2 cols per thread)
    float vx = 0.f, vy = 0.f;
    for (int kk = 0; kk < 64; ++kk){
      float q = pbuf[nl][kk];
      float2 m2 = *(const float2*)&kbuf[kk][ml*2];
      vx += q*m2.x; vy += q*m2.y;
    }
    __syncthreads();
    vbuf[nl][ml*2]   = vx;
    vbuf[nl][ml*2+1] = vy;
  }
  // stage chunk 0 (cols 0..63, all < N_)
  {
    if (AMODE != 0) __syncthreads();   // vbuf writes + kbuf free
    #pragma unroll
    for (int ii = 0; ii < 16; ++ii){
      int idx = tid + ii*256;
      int mm = idx >> 6, kk = idx & 63;
      if (AMODE != 0)
        kbuf[mm][kk] = (AMODE == 1) ? Keysf[(b*N_+mm)*64+kk] : Keysb[mm*64+kk];
      xbuf[mm][kk] = X[(b*N_+mm)*64+kk];
    }
    if (AMODE == 0){
      #pragma unroll
      for (int ii = 0; ii < 2; ++ii){
        int idx = tid + ii*256;
        int r = idx >> 6, mm = idx & 63;
        int nn = n0 + r;
        pbuf[r][mm] = (nn < N_) ? geo[nn*N_ + mm] : 0.f;
      }
    }
    __syncthreads();
  }

  float m_run = -1e30f, l_run = 0.f;
  float accx = 0.f, accy = 0.f;

  for (int ci = 0; ci < 8; ++ci){
    int m0 = ci*64;
    // prefetch next chunk into registers
    if (ci < 7){
      #pragma unroll
      for (int ii=0; ii<16; ++ii){
        int idx = tid + ii*256;
        int mm = idx >> 6, kk = idx & 63;
        int m = m0 + 64 + mm;
        if (AMODE != 0)
          rrK[ii] = (m < N_) ? ((AMODE == 1) ? Keysf[(b*N_+m)*64+kk] : Keysb[m*64+kk]) : 0.f;
        rrX[ii] = (m < N_) ? X[(b*N_+m)*64+kk] : 0.f;
      }
      if (AMODE == 0){
        #pragma unroll
        for (int ii=0; ii<2; ++ii){
          int idx = tid + ii*256;
          int r = idx >> 6, mm = idx & 63;
          int nn = n0 + r, m = m0 + 64 + mm;
          rrA[ii] = (nn < N_ && m < N_) ? geo[nn*N_ + m] : 0.f;
        }
      }
    }
    if (AMODE != 0){
      // scores for columns m0+ml, m0+ml+32
      float s0 = 0.f, s1 = 0.f;
      for (int kk = 0; kk < 64; kk += 4){
        float4 qv = *(const float4*)&vbuf[nl][kk];
        float4 k0 = *(const float4*)&kbuf[ml   ][kk];
        float4 k1 = *(const float4*)&kbuf[ml+32][kk];
        s0 += qv.x*k0.x + qv.y*k0.y + qv.z*k0.z + qv.w*k0.w;
        s1 += qv.x*k1.x + qv.y*k1.y + qv.z*k1.z + qv.w*k1.w;
      }
      float v0 = (m0 + ml      < N_) ? (RELU ? fmaxf(s0, 0.f) : s0) : -1e30f;
      float v1 = (m0 + ml + 32 < N_) ? (RELU ? fmaxf(s1, 0.f) : s1) : -1e30f;
      float cmax = fmaxf(v0, v1);
      #pragma unroll
      for (int msk = 1; msk < 32; msk <<= 1) cmax = fmaxf(cmax, __shfl_xor(cmax, msk, 32));
      float mnew = fmaxf(m_run, cmax);
      float scale = expf(m_run - mnew);
      float p0 = expf(v0 - mnew);
      float p1 = expf(v1 - mnew);
      float lc = p0 + p1;
      #pragma unroll
      for (int msk = 1; msk < 32; msk <<= 1) lc += __shfl_xor(lc, msk, 32);
      l_run = l_run*scale + lc;
      m_run = mnew;
      accx *= scale; accy *= scale;
      pbuf[nl][ml]    = p0;
      pbuf[nl][ml+32] = p1;
    }
    __syncthreads();   // pbuf visible; kbuf reads complete
    // apply: acc += pbuf[nl][:] . xbuf[:][ml*2 .. +1]
    for (int mm = 0; mm < 64; mm += 4){
      float4 pv = *(const float4*)&pbuf[nl][mm];
      float2 x0 = *(const float2*)&xbuf[mm+0][ml*2];
      float2 x1 = *(const float2*)&xbuf[mm+1][ml*2];
      float2 x2 = *(const float2*)&xbuf[mm+2][ml*2];
      float2 x3 = *(const float2*)&xbuf[mm+3][ml*2];
      accx += pv.x*x0.x + pv.y*x1.x + pv.z*x2.x + pv.w*x3.x;
      accy += pv.x*x0.y + pv.y*x1.y + pv.z*x2.y + pv.w*x3.y;
    }
    __syncthreads();   // xbuf (and pbuf for AMODE0) reads complete
    if (ci < 7){
      #pragma unroll
      for (int ii=0; ii<16; ++ii){
        int idx = tid + ii*256;
        int mm = idx >> 6, kk = idx & 63;
        if (AMODE != 0) kbuf[mm][kk] = rrK[ii];
        xbuf[mm][kk] = rrX[ii];
      }
      if (AMODE == 0){
        #pragma unroll
        for (int ii=0; ii<2; ++ii){
          int idx = tid + ii*256;
          pbuf[idx>>6][idx&63] = rrA[ii];
        }
      }
      __syncthreads();   // staged data visible
    }
  }
  if (AMODE != 0){
    float inv = 1.f / l_run;
    accx *= inv; accy *= inv;
  }

  if (!FINAL){
    if (n < N_){
      float2 o2; o2.x = accx; o2.y = accy;
      *(float2*)&Y[(b*N_+n)*64 + ml*2] = o2;
    }
    return;
  }

  // epilogue: cur (+)= (X0 + Z1 + Yacc) @ Wg + bg
  {
    int row = b*N_ + n;
    float svx = 0.f, svy = 0.f;
    if (n < N_){
      float2 x0v = *(const float2*)&X0[row*64 + ml*2];
      float2 z1v = *(const float2*)&Z1[row*64 + ml*2];
      svx = accx + x0v.x + z1v.x;
      svy = accy + x0v.y + z1v.y;
    }
    vbuf[nl][ml*2]   = svx;      // safe: all vbuf reads ended before last apply barrier
    vbuf[nl][ml*2+1] = svy;
    for (int idx = tid; idx < 4096; idx += 256)
      kbuf[idx>>6][idx&63] = Wg[idx];
    __syncthreads();
    float ox = 0.f, oy = 0.f;
    for (int kk = 0; kk < 64; ++kk){
      float s = vbuf[nl][kk];
      float2 w2 = *(const float2*)&kbuf[kk][ml*2];
      ox += s*w2.x; oy += s*w2.y;
    }
    if (n < N_){
      float2 bv = *(const float2*)&bg[ml*2];
      float vx = ox + bv.x, vy = oy + bv.y;
      if (ADD){
        float2 old = *(const float2*)&cur[row*64 + ml*2];
        vx += old.x; vy += old.y;
      }
      float2 o2; o2.x = vx; o2.y = vy;
      *(float2*)&cur[row*64 + ml*2] = o2;
    }
  }
}

// ---------------- output head: 4 rows/block, 2 barriers ----------------
__global__ __launch_bounds__(128) void k_out(const float* __restrict__ cur,
                                             const float* __restrict__ W1, const float* __restrict__ bb1,
                                             const float* __restrict__ W2, const float* __restrict__ bb2,
                                             float* __restrict__ out){
  __shared__ float ch[4][64];
  __shared__ float hid[4*1200];
  int tid = threadIdx.x;
  int rbase = blockIdx.x*4;
  for (int idx = tid; idx < 256; idx += 128){
    int r = idx >> 6, h = idx & 63;
    ch[r][h] = cur[(rbase+r)*64 + h];
  }
  __syncthreads();
  for (int job = tid; job < 1200; job += 128){
    int t = job / 100, f = job - t*100;
    float a0 = bb1[t*100+f], a1 = a0, a2 = a0, a3 = a0;
    for (int h = 0; h < 64; ++h){
      float w = W1[(t*64+h)*100 + f];
      a0 += ch[0][h]*w; a1 += ch[1][h]*w; a2 += ch[2][h]*w; a3 += ch[3][h]*w;
    }
    hid[0*1200+job] = (a0 > 0.f) ? a0 : expm1f(a0);
    hid[1*1200+job] = (a1 > 0.f) ? a1 : expm1f(a1);
    hid[2*1200+job] = (a2 > 0.f) ? a2 : expm1f(a2);
    hid[3*1200+job] = (a3 > 0.f) ? a3 : expm1f(a3);
  }
  __syncthreads();
  if (tid < 96){
    int r = tid / 24, rem = tid % 24;
    int t = rem >> 1, o = rem & 1;
    float a = bb2[t*2+o];
    const float* hp = hid + r*1200 + t*100;
    for (int f = 0; f < 100; ++f) a += hp[f] * W2[(t*100+f)*2+o];
    out[(rbase+r)*24 + t*2+o] = a;
  }
}

// ---------------- launch ----------------
extern "C" void kernel_launch(void* const* d_in, const int* in_sizes, int n_in,
                              void* d_out, int out_size, void* d_ws, size_t ws_size,
                              hipStream_t stream)
{
  const float* x        = (const float*)d_in[0];
  const float* geo      = (const float*)d_in[2];
  const float* fcx_W    = (const float*)d_in[3];
  const float* fcx_b    = (const float*)d_in[4];
  const float* env_cb   = (const float*)d_in[5];
  const float* nodes_cb = (const float*)d_in[6];
  const float* w_v      = (const float*)d_in[7];
  const float* w_k      = (const float*)d_in[8];
  const float* w_q      = (const float*)d_in[9];
  const float* core_W   = (const float*)d_in[10];
  const float* core_b   = (const float*)d_in[11];
  const float* tN_Win   = (const float*)d_in[12];
  const float* tN_bin   = (const float*)d_in[13];
  const float* tN_Wf    = (const float*)d_in[14];
  const float* tN_bf    = (const float*)d_in[15];
  const float* tN_Wg    = (const float*)d_in[16];
  const float* tN_bg    = (const float*)d_in[17];
  const float* tN_Wout  = (const float*)d_in[18];
  const float* tN_bout  = (const float*)d_in[19];
  const float* tP_Win   = (const float*)d_in[20];
  const float* tP_bin   = (const float*)d_in[21];
  const float* tP_Wf    = (const float*)d_in[22];
  const float* tP_bf    = (const float*)d_in[23];
  const float* tP_Wg    = (const float*)d_in[24];
  const float* tP_bg    = (const float*)d_in[25];
  const float* tP_Wout  = (const float*)d_in[26];
  const float* tP_bout  = (const float*)d_in[27];
  const float* bn1_g    = (const float*)d_in[28];
  const float* bn1_b    = (const float*)d_in[29];
  const float* bnP_g    = (const float*)d_in[30];
  const float* bnP_b    = (const float*)d_in[31];
  const float* gcn1_W   = (const float*)d_in[32];
  const float* gcn1_b   = (const float*)d_in[33];
  const float* gcn2_W   = (const float*)d_in[34];
  const float* gcn2_b   = (const float*)d_in[35];
  const float* gcnp_W   = (const float*)d_in[36];
  const float* gcnp_b   = (const float*)d_in[37];
  const float* nv_p1    = (const float*)d_in[38];
  const float* nv_p2    = (const float*)d_in[39];
  const float* nv_p3    = (const float*)d_in[40];
  const float* nv_pk    = (const float*)d_in[41];
  const float* out_W1   = (const float*)d_in[42];
  const float* out_b1   = (const float*)d_in[43];
  const float* out_W2   = (const float*)d_in[44];
  const float* out_b2   = (const float*)d_in[45];
  const int*   t_pos    = (const int*)d_in[46];
  const int*   ind      = (const int*)d_in[47];

  // Workspace: 4096 B header + 2,223,616 floats = 8,898,560 B (~8.49 MiB)
  int* node_list = (int*)d_ws;
  int* off       = node_list + 512;
  float* F = (float*)((char*)d_ws + 4096);
  float* temb   = F + 0;
  float* core_f = F + 12288;
  float* tmp1   = F + 77824;
  float* stats  = F + 143360;
  float* matq   = F + 143616;
  float* unb    = F + 175616;
  float* hpr    = F + 687616;
  float* cur    = F + 1199616;
  float* zt1    = F + 1711616;

  k_matq <<<dim3(125), dim3(256), 0, stream>>>(nodes_cb, w_q, matq);
  k_route<<<dim3(1),   dim3(256), 0, stream>>>(env_cb, w_v, w_k, matq, node_list, off);
  k_temb <<<dim3(1),   dim3(192), 0, stream>>>(t_pos, temb);
  k_core <<<dim3(256), dim3(256), 0, stream>>>(temb, core_W, core_b, core_f);
  k_tcn  <<<dim3(20, 334), dim3(256), 0, stream>>>(x, fcx_W, fcx_b, temb, node_list, off,
      tN_Win, tN_bin, tN_Wf, tN_bf, tN_Wg, tN_bg, tN_Wout, tN_bout,
      tP_Win, tP_bin, tP_Wf, tP_bf, tP_Wg, tP_bg, tP_Wout, tP_bout,
      unb, hpr);
  k_bnstats<<<dim3(128), dim3(256), 0, stream>>>(unb, hpr, stats);
  k_bnapply<<<dim3(4000),dim3(256), 0, stream>>>(unb, hpr, stats, bn1_g, bn1_b, bnP_g, bnP_b);

  dim3 ag(64, 16);
  // gcn1: geo adjacency on h_prev
  k_attn<0,0,0,0><<<ag, 256, 0, stream>>>(geo, nullptr,nullptr,nullptr, nullptr,nullptr,
                                 hpr, nullptr,nullptr, nullptr,nullptr, nullptr, zt1);
  k_attn<0,0,1,0><<<ag, 256, 0, stream>>>(geo, nullptr,nullptr,nullptr, nullptr,nullptr,
                                 zt1, hpr, zt1, gcn1_W, gcn1_b, cur, nullptr);
  // gcn2: causal adjacency softmax(unb @ core[b] @ hpr^T) on unbias
  k_attn<1,0,0,0><<<ag, 256, 0, stream>>>(nullptr, unb,nullptr, core_f, hpr,nullptr,
                                 unb, nullptr,nullptr, nullptr,nullptr, nullptr, zt1);
  k_attn<1,0,1,1><<<ag, 256, 0, stream>>>(nullptr, unb,nullptr, core_f, hpr,nullptr,
                                 zt1, unb, zt1, gcn2_W, gcn2_b, cur, nullptr);
  // gcnp: adaptive adjacency softmax(relu(nv_p3 @ (nv_p2 @ (te @ nv_pk)))) on unbias
  k_tmp1<<<dim3(256), dim3(256), 0, stream>>>(ind, nv_p1, nv_pk, tmp1);
  k_attn<2,1,0,0><<<ag, 256, 0, stream>>>(nullptr, nullptr,nv_p2, tmp1, nullptr,nv_p3,
                                 unb, nullptr,nullptr, nullptr,nullptr, nullptr, zt1);
  k_attn<2,1,1,1><<<ag, 256, 0, stream>>>(nullptr, nullptr,nv_p2, tmp1, nullptr,nv_p3,
                                 zt1, unb, zt1, gcnp_W, gcnp_b, cur, nullptr);
  // head
  k_out<<<dim3(2000), dim3(128), 0, stream>>>(cur, out_W1, out_b1, out_W2, out_b2, (float*)d_out);
}